// Round 1
// baseline (1154.943 us; speedup 1.0000x reference)
//
#include <hip/hip_runtime.h>

constexpr int NN   = 100000;
constexpr int EE   = 1600000;
constexpr int ETOT = EE + NN;
constexpr float SLOPE = 0.2f;

// ---------------- CSR build ----------------
__global__ void k_init_counts(int* cnt) {
    int i = blockIdx.x * blockDim.x + threadIdx.x;
    if (i < NN) cnt[i] = 1;  // self loop counted up front
}

__global__ void k_count(const int* __restrict__ ei, int* __restrict__ cnt) {
    int i = blockIdx.x * blockDim.x + threadIdx.x;
    if (i < EE) atomicAdd(&cnt[ei[EE + i]], 1);
}

__global__ void k_scan1(const int* __restrict__ in, int* __restrict__ out,
                        int* __restrict__ partials) {
    __shared__ int sd[256];
    int base = blockIdx.x * 1024;
    int t = threadIdx.x;
    int i = base + t * 4;
    int v0 = (i + 0 < NN) ? in[i + 0] : 0;
    int v1 = (i + 1 < NN) ? in[i + 1] : 0;
    int v2 = (i + 2 < NN) ? in[i + 2] : 0;
    int v3 = (i + 3 < NN) ? in[i + 3] : 0;
    int s = v0 + v1 + v2 + v3;
    sd[t] = s;
    __syncthreads();
    for (int off = 1; off < 256; off <<= 1) {
        int x = (t >= off) ? sd[t - off] : 0;
        __syncthreads();
        sd[t] += x;
        __syncthreads();
    }
    int run = sd[t] - s;  // exclusive prefix of thread sums
    if (i + 0 < NN) out[i + 0] = run; run += v0;
    if (i + 1 < NN) out[i + 1] = run; run += v1;
    if (i + 2 < NN) out[i + 2] = run; run += v2;
    if (i + 3 < NN) out[i + 3] = run;
    if (t == 255) partials[blockIdx.x] = sd[255];
}

__global__ void k_scan2(int* partials, int m) {
    __shared__ int sd[128];
    int t = threadIdx.x;
    int v = (t < m) ? partials[t] : 0;
    sd[t] = v;
    __syncthreads();
    for (int off = 1; off < 128; off <<= 1) {
        int x = (t >= off) ? sd[t - off] : 0;
        __syncthreads();
        sd[t] += x;
        __syncthreads();
    }
    if (t < m) partials[t] = sd[t] - v;
}

__global__ void k_scan3(int* out, const int* __restrict__ partials) {
    int i = blockIdx.x * blockDim.x + threadIdx.x;
    if (i < NN) out[i] += partials[i >> 10];
}

__global__ void k_copy_int(const int* __restrict__ in, int* __restrict__ out) {
    int i = blockIdx.x * blockDim.x + threadIdx.x;
    if (i < NN) out[i] = in[i];
}

__global__ void k_fill(const int* __restrict__ ei, int* __restrict__ cursor,
                       int* __restrict__ esrc) {
    int i = blockIdx.x * blockDim.x + threadIdx.x;
    if (i >= ETOT) return;
    int s, d;
    if (i < EE) { s = ei[i]; d = ei[EE + i]; }
    else        { s = i - EE; d = s; }
    int pos = atomicAdd(&cursor[d], 1);
    esrc[pos] = s;
}

// ---------------- fp32 tiled GEMM: C[M,NC] = A[M,K] @ B[K,NC] ----------------
template <int BM, int BN, int BK, int TM, int TN>
__global__ __launch_bounds__((BM / TM) * (BN / TN)) void k_sgemm(
    const float* __restrict__ A, const float* __restrict__ B,
    float* __restrict__ C, int M, int K, int NC) {
    constexpr int THREADS = (BM / TM) * (BN / TN);
    constexpr int TX = BN / TN;
    __shared__ __align__(16) float As[BK][BM + 4];
    __shared__ __align__(16) float Bs[BK][BN + 4];
    int tid = threadIdx.x;
    int tx = tid % TX, ty = tid / TX;
    int rowBase = blockIdx.x * BM;
    int colBase = blockIdx.y * BN;
    float acc[TM][TN];
#pragma unroll
    for (int i = 0; i < TM; i++)
#pragma unroll
        for (int j = 0; j < TN; j++) acc[i][j] = 0.f;

    constexpr int LA = (BM * BK) / (THREADS * 4);
    constexpr int LB = (BK * BN) / (THREADS * 4);
    for (int k0 = 0; k0 < K; k0 += BK) {
#pragma unroll
        for (int l = 0; l < LA; l++) {
            int idx = tid + l * THREADS;
            int m = idx / (BK / 4);
            int kk = (idx % (BK / 4)) * 4;
            float4 v = make_float4(0.f, 0.f, 0.f, 0.f);
            int gr = rowBase + m;
            if (gr < M) v = *(const float4*)(A + (size_t)gr * K + k0 + kk);
            As[kk + 0][m] = v.x; As[kk + 1][m] = v.y;
            As[kk + 2][m] = v.z; As[kk + 3][m] = v.w;
        }
#pragma unroll
        for (int l = 0; l < LB; l++) {
            int idx = tid + l * THREADS;
            int kk = idx / (BN / 4);
            int c = (idx % (BN / 4)) * 4;
            float4 v = *(const float4*)(B + (size_t)(k0 + kk) * NC + colBase + c);
            *(float4*)(&Bs[kk][c]) = v;
        }
        __syncthreads();
#pragma unroll
        for (int k = 0; k < BK; k++) {
            float a[TM], b[TN];
#pragma unroll
            for (int i = 0; i < TM; i++) a[i] = As[k][ty * TM + i];
#pragma unroll
            for (int j = 0; j < TN; j++) b[j] = Bs[k][tx * TN + j];
#pragma unroll
            for (int i = 0; i < TM; i++)
#pragma unroll
                for (int j = 0; j < TN; j++) acc[i][j] += a[i] * b[j];
        }
        __syncthreads();
    }
#pragma unroll
    for (int i = 0; i < TM; i++) {
        int gr = rowBase + ty * TM + i;
        if (gr < M) {
#pragma unroll
            for (int j = 0; j < TN; j += 4) {
                float4 v = make_float4(acc[i][j], acc[i][j + 1], acc[i][j + 2],
                                       acc[i][j + 3]);
                *(float4*)(C + (size_t)gr * NC + colBase + tx * TN + j) = v;
            }
        }
    }
}

// -------------- attention coefficients: a_s[n,h] = <h[n,h,:], as[h,:]> --------------
template <int H>
__global__ void k_att(const float* __restrict__ h, const float* __restrict__ as_,
                      const float* __restrict__ ad_, float* __restrict__ a_s,
                      float* __restrict__ a_d) {
    int i = blockIdx.x * blockDim.x + threadIdx.x;
    if (i >= NN * H) return;
    int n = i / H, hh = i % H;
    const float4* hp = (const float4*)(h + (size_t)n * (H * 32) + hh * 32);
    const float4* sp = (const float4*)(as_ + hh * 32);
    const float4* dp = (const float4*)(ad_ + hh * 32);
    float ss = 0.f, dd = 0.f;
#pragma unroll
    for (int j = 0; j < 8; j++) {
        float4 hv = hp[j], sv = sp[j], dv = dp[j];
        ss += hv.x * sv.x + hv.y * sv.y + hv.z * sv.z + hv.w * sv.w;
        dd += hv.x * dv.x + hv.y * dv.y + hv.z * dv.z + hv.w * dv.w;
    }
    a_s[i] = ss;
    a_d[i] = dd;
}

// -------- fused softmax + aggregate + bias + LayerNorm + ELU (H=4, C=32, 128ch) --------
__global__ __launch_bounds__(128) void k_aggregate_ln(
    const float* __restrict__ h, const float* __restrict__ a_src,
    const float* __restrict__ a_dst, const int* __restrict__ row_ptr,
    const int* __restrict__ esrc, const float* __restrict__ bias,
    const float* __restrict__ gamma, const float* __restrict__ beta,
    float* __restrict__ xout) {
    int n = blockIdx.x;
    int t = threadIdx.x;
    int start = row_ptr[n];
    int end = (n == NN - 1) ? ETOT : row_ptr[n + 1];

    __shared__ float s_ad[4];
    __shared__ float s_inv[4];
    __shared__ float4 red4[128];
    __shared__ float s_alpha[64 * 4];
    __shared__ int s_srcid[64];
    __shared__ float sred[128];

    if (t < 4) s_ad[t] = a_dst[(size_t)n * 4 + t];
    __syncthreads();
    float ad0 = s_ad[0], ad1 = s_ad[1], ad2 = s_ad[2], ad3 = s_ad[3];

    // phase A: softmax denominators per head
    float d0 = 0.f, d1 = 0.f, d2 = 0.f, d3 = 0.f;
    for (int k = start + t; k < end; k += 128) {
        int s = esrc[k];
        float4 a = ((const float4*)a_src)[s];
        float e0 = a.x + ad0; e0 = e0 > 0.f ? e0 : SLOPE * e0; d0 += __expf(e0);
        float e1 = a.y + ad1; e1 = e1 > 0.f ? e1 : SLOPE * e1; d1 += __expf(e1);
        float e2 = a.z + ad2; e2 = e2 > 0.f ? e2 : SLOPE * e2; d2 += __expf(e2);
        float e3 = a.w + ad3; e3 = e3 > 0.f ? e3 : SLOPE * e3; d3 += __expf(e3);
    }
    red4[t] = make_float4(d0, d1, d2, d3);
    __syncthreads();
    for (int off = 64; off > 0; off >>= 1) {
        if (t < off) {
            float4 a = red4[t], b = red4[t + off];
            red4[t] = make_float4(a.x + b.x, a.y + b.y, a.z + b.z, a.w + b.w);
        }
        __syncthreads();
    }
    if (t == 0) {
        float4 ds = red4[0];
        s_inv[0] = 1.f / (ds.x + 1e-16f);
        s_inv[1] = 1.f / (ds.y + 1e-16f);
        s_inv[2] = 1.f / (ds.z + 1e-16f);
        s_inv[3] = 1.f / (ds.w + 1e-16f);
    }
    __syncthreads();
    float inv0 = s_inv[0], inv1 = s_inv[1], inv2 = s_inv[2], inv3 = s_inv[3];

    // phase B: weighted aggregation, channel c = t
    float acc = 0.f;
    int myh = t >> 5;
    for (int base = start; base < end; base += 64) {
        int k = base + t;
        if (t < 64 && k < end) {
            int s = esrc[k];
            s_srcid[t] = s;
            float4 a = ((const float4*)a_src)[s];
            float e0 = a.x + ad0; e0 = e0 > 0.f ? e0 : SLOPE * e0;
            float e1 = a.y + ad1; e1 = e1 > 0.f ? e1 : SLOPE * e1;
            float e2 = a.z + ad2; e2 = e2 > 0.f ? e2 : SLOPE * e2;
            float e3 = a.w + ad3; e3 = e3 > 0.f ? e3 : SLOPE * e3;
            s_alpha[t * 4 + 0] = __expf(e0) * inv0;
            s_alpha[t * 4 + 1] = __expf(e1) * inv1;
            s_alpha[t * 4 + 2] = __expf(e2) * inv2;
            s_alpha[t * 4 + 3] = __expf(e3) * inv3;
        }
        __syncthreads();
        int cnt = min(64, end - base);
        for (int j = 0; j < cnt; j++) {
            int s = s_srcid[j];
            acc += h[(size_t)s * 128 + t] * s_alpha[j * 4 + myh];
        }
        __syncthreads();
    }

    // epilogue: bias + LayerNorm + ELU
    float y = acc + bias[t];
    sred[t] = y;
    __syncthreads();
    for (int off = 64; off > 0; off >>= 1) {
        if (t < off) sred[t] += sred[t + off];
        __syncthreads();
    }
    float mu = sred[0] * (1.f / 128.f);
    __syncthreads();
    float dv = y - mu;
    sred[t] = dv * dv;
    __syncthreads();
    for (int off = 64; off > 0; off >>= 1) {
        if (t < off) sred[t] += sred[t + off];
        __syncthreads();
    }
    float var = sred[0] * (1.f / 128.f);
    float xh = dv * rsqrtf(var + 1e-5f);
    float z = gamma[t] * xh + beta[t];
    xout[(size_t)n * 128 + t] = z > 0.f ? z : __expf(z) - 1.f;
}

// -------- final layer: H=1, C=32, no LN/ELU, writes d_out --------
__global__ __launch_bounds__(64) void k_agg_final(
    const float* __restrict__ hf, const float* __restrict__ a_src,
    const float* __restrict__ a_dst, const int* __restrict__ row_ptr,
    const int* __restrict__ esrc, const float* __restrict__ bf,
    float* __restrict__ out) {
    int n = blockIdx.x;
    int t = threadIdx.x;
    int start = row_ptr[n];
    int end = (n == NN - 1) ? ETOT : row_ptr[n + 1];
    float adn = a_dst[n];

    float d = 0.f;
    for (int k = start + t; k < end; k += 64) {
        int s = esrc[k];
        float e = a_src[s] + adn;
        e = e > 0.f ? e : SLOPE * e;
        d += __expf(e);
    }
    for (int m = 32; m > 0; m >>= 1) d += __shfl_xor(d, m);
    float inv = 1.f / (d + 1e-16f);

    __shared__ float s_alpha[64];
    __shared__ int s_src[64];
    float acc = 0.f;
    for (int base = start; base < end; base += 64) {
        int k = base + t;
        if (k < end) {
            int s = esrc[k];
            s_src[t] = s;
            float e = a_src[s] + adn;
            e = e > 0.f ? e : SLOPE * e;
            s_alpha[t] = __expf(e) * inv;
        }
        __syncthreads();
        int cnt = min(64, end - base);
        if (t < 32) {
            for (int j = 0; j < cnt; j++)
                acc += hf[(size_t)s_src[j] * 32 + t] * s_alpha[j];
        }
        __syncthreads();
    }
    if (t < 32) out[(size_t)n * 32 + t] = acc + bf[t];
}

// ---------------- launch ----------------
extern "C" void kernel_launch(void* const* d_in, const int* in_sizes, int n_in,
                              void* d_out, int out_size, void* d_ws,
                              size_t ws_size, hipStream_t stream) {
    const float* x  = (const float*)d_in[0];
    const int* ei   = (const int*)d_in[1];
    const float* W[3]  = {(const float*)d_in[2], (const float*)d_in[8],  (const float*)d_in[14]};
    const float* AS[3] = {(const float*)d_in[3], (const float*)d_in[9],  (const float*)d_in[15]};
    const float* AD[3] = {(const float*)d_in[4], (const float*)d_in[10], (const float*)d_in[16]};
    const float* Bb[3] = {(const float*)d_in[5], (const float*)d_in[11], (const float*)d_in[17]};
    const float* G[3]  = {(const float*)d_in[6], (const float*)d_in[12], (const float*)d_in[18]};
    const float* BE[3] = {(const float*)d_in[7], (const float*)d_in[13], (const float*)d_in[19]};
    const float* Wf  = (const float*)d_in[20];
    const float* asf = (const float*)d_in[21];
    const float* adf = (const float*)d_in[22];
    const float* bfp = (const float*)d_in[23];
    float* out = (float*)d_out;

    float* xbuf = (float*)d_ws;
    float* hbuf = xbuf + (size_t)NN * 128;
    float* a_s  = hbuf + (size_t)NN * 128;
    float* a_d  = a_s + (size_t)NN * 4;
    int* row_ptr  = (int*)(a_d + (size_t)NN * 4);
    int* cnt      = row_ptr + NN;
    int* esrc     = cnt + NN;
    int* partials = esrc + ETOT;

    int nbN = (NN + 255) / 256;
    k_init_counts<<<nbN, 256, 0, stream>>>(cnt);
    k_count<<<(EE + 255) / 256, 256, 0, stream>>>(ei, cnt);
    int nchunks = (NN + 1023) / 1024;
    k_scan1<<<nchunks, 256, 0, stream>>>(cnt, row_ptr, partials);
    k_scan2<<<1, 128, 0, stream>>>(partials, nchunks);
    k_scan3<<<nbN, 256, 0, stream>>>(row_ptr, partials);
    k_copy_int<<<nbN, 256, 0, stream>>>(row_ptr, cnt);  // cnt becomes cursor
    k_fill<<<(ETOT + 255) / 256, 256, 0, stream>>>(ei, cnt, esrc);

    const float* xin = x;
    int K = 64;
    for (int l = 0; l < 3; l++) {
        dim3 g((NN + 127) / 128, 1);
        k_sgemm<128, 128, 16, 8, 8><<<g, 256, 0, stream>>>(xin, W[l], hbuf, NN, K, 128);
        k_att<4><<<(NN * 4 + 255) / 256, 256, 0, stream>>>(hbuf, AS[l], AD[l], a_s, a_d);
        k_aggregate_ln<<<NN, 128, 0, stream>>>(hbuf, a_s, a_d, row_ptr, esrc,
                                               Bb[l], G[l], BE[l], xbuf);
        xin = xbuf;
        K = 128;
    }
    k_sgemm<64, 32, 16, 4, 4><<<dim3((NN + 63) / 64, 1), 128, 0, stream>>>(
        xbuf, Wf, hbuf, NN, 128, 32);
    k_att<1><<<(NN + 255) / 256, 256, 0, stream>>>(hbuf, asf, adf, a_s, a_d);
    k_agg_final<<<NN, 64, 0, stream>>>(hbuf, a_s, a_d, row_ptr, esrc, bfp, out);
}

// Round 2
// 1045.424 us; speedup vs baseline: 1.1048x; 1.1048x over previous
//
#include <hip/hip_runtime.h>

constexpr int NN   = 100000;
constexpr int EE   = 1600000;
constexpr int ETOT = EE + NN;
constexpr float SLOPE = 0.2f;
constexpr int MAXD = 96;   // degree cap for LDS edge cache (Poisson(16)+1, max~45)

// ---------------- CSR build ----------------
__global__ void k_init_counts(int* cnt) {
    int i = blockIdx.x * blockDim.x + threadIdx.x;
    if (i < NN) cnt[i] = 1;  // self loop counted up front
}

__global__ void k_count(const int* __restrict__ ei, int* __restrict__ cnt) {
    int i = blockIdx.x * blockDim.x + threadIdx.x;
    if (i < EE) atomicAdd(&cnt[ei[EE + i]], 1);
}

__global__ void k_scan1(const int* __restrict__ in, int* __restrict__ out,
                        int* __restrict__ partials) {
    __shared__ int sd[256];
    int base = blockIdx.x * 1024;
    int t = threadIdx.x;
    int i = base + t * 4;
    int v0 = (i + 0 < NN) ? in[i + 0] : 0;
    int v1 = (i + 1 < NN) ? in[i + 1] : 0;
    int v2 = (i + 2 < NN) ? in[i + 2] : 0;
    int v3 = (i + 3 < NN) ? in[i + 3] : 0;
    int s = v0 + v1 + v2 + v3;
    sd[t] = s;
    __syncthreads();
    for (int off = 1; off < 256; off <<= 1) {
        int x = (t >= off) ? sd[t - off] : 0;
        __syncthreads();
        sd[t] += x;
        __syncthreads();
    }
    int run = sd[t] - s;  // exclusive prefix of thread sums
    if (i + 0 < NN) out[i + 0] = run; run += v0;
    if (i + 1 < NN) out[i + 1] = run; run += v1;
    if (i + 2 < NN) out[i + 2] = run; run += v2;
    if (i + 3 < NN) out[i + 3] = run;
    if (t == 255) partials[blockIdx.x] = sd[255];
}

__global__ void k_scan2(int* partials, int m) {
    __shared__ int sd[128];
    int t = threadIdx.x;
    int v = (t < m) ? partials[t] : 0;
    sd[t] = v;
    __syncthreads();
    for (int off = 1; off < 128; off <<= 1) {
        int x = (t >= off) ? sd[t - off] : 0;
        __syncthreads();
        sd[t] += x;
        __syncthreads();
    }
    if (t < m) partials[t] = sd[t] - v;
}

__global__ void k_scan3(int* out, const int* __restrict__ partials) {
    int i = blockIdx.x * blockDim.x + threadIdx.x;
    if (i < NN) out[i] += partials[i >> 10];
}

__global__ void k_copy_int(const int* __restrict__ in, int* __restrict__ out) {
    int i = blockIdx.x * blockDim.x + threadIdx.x;
    if (i < NN) out[i] = in[i];
}

__global__ void k_fill(const int* __restrict__ ei, int* __restrict__ cursor,
                       int* __restrict__ esrc) {
    int i = blockIdx.x * blockDim.x + threadIdx.x;
    if (i >= ETOT) return;
    int s, d;
    if (i < EE) { s = ei[i]; d = ei[EE + i]; }
    else        { s = i - EE; d = s; }
    int pos = atomicAdd(&cursor[d], 1);
    esrc[pos] = s;
}

// ---------------- fp32 tiled GEMM: C[M,NC] = A[M,K] @ B[K,NC] ----------------
template <int BM, int BN, int BK, int TM, int TN>
__global__ __launch_bounds__((BM / TM) * (BN / TN)) void k_sgemm(
    const float* __restrict__ A, const float* __restrict__ B,
    float* __restrict__ C, int M, int K, int NC) {
    constexpr int THREADS = (BM / TM) * (BN / TN);
    constexpr int TX = BN / TN;
    __shared__ __align__(16) float As[BK][BM + 4];
    __shared__ __align__(16) float Bs[BK][BN + 4];
    int tid = threadIdx.x;
    int tx = tid % TX, ty = tid / TX;
    int rowBase = blockIdx.x * BM;
    int colBase = blockIdx.y * BN;
    float acc[TM][TN];
#pragma unroll
    for (int i = 0; i < TM; i++)
#pragma unroll
        for (int j = 0; j < TN; j++) acc[i][j] = 0.f;

    constexpr int LA = (BM * BK) / (THREADS * 4);
    constexpr int LB = (BK * BN) / (THREADS * 4);
    for (int k0 = 0; k0 < K; k0 += BK) {
#pragma unroll
        for (int l = 0; l < LA; l++) {
            int idx = tid + l * THREADS;
            int m = idx / (BK / 4);
            int kk = (idx % (BK / 4)) * 4;
            float4 v = make_float4(0.f, 0.f, 0.f, 0.f);
            int gr = rowBase + m;
            if (gr < M) v = *(const float4*)(A + (size_t)gr * K + k0 + kk);
            As[kk + 0][m] = v.x; As[kk + 1][m] = v.y;
            As[kk + 2][m] = v.z; As[kk + 3][m] = v.w;
        }
#pragma unroll
        for (int l = 0; l < LB; l++) {
            int idx = tid + l * THREADS;
            int kk = idx / (BN / 4);
            int c = (idx % (BN / 4)) * 4;
            float4 v = *(const float4*)(B + (size_t)(k0 + kk) * NC + colBase + c);
            *(float4*)(&Bs[kk][c]) = v;
        }
        __syncthreads();
#pragma unroll
        for (int k = 0; k < BK; k++) {
            float a[TM], b[TN];
#pragma unroll
            for (int i = 0; i < TM; i++) a[i] = As[k][ty * TM + i];
#pragma unroll
            for (int j = 0; j < TN; j++) b[j] = Bs[k][tx * TN + j];
#pragma unroll
            for (int i = 0; i < TM; i++)
#pragma unroll
                for (int j = 0; j < TN; j++) acc[i][j] += a[i] * b[j];
        }
        __syncthreads();
    }
#pragma unroll
    for (int i = 0; i < TM; i++) {
        int gr = rowBase + ty * TM + i;
        if (gr < M) {
#pragma unroll
            for (int j = 0; j < TN; j += 4) {
                float4 v = make_float4(acc[i][j], acc[i][j + 1], acc[i][j + 2],
                                       acc[i][j + 3]);
                *(float4*)(C + (size_t)gr * NC + colBase + tx * TN + j) = v;
            }
        }
    }
}

// -------------- attention coefficients: a_s[n,h] = <h[n,h,:], as[h,:]> --------------
template <int H>
__global__ void k_att(const float* __restrict__ h, const float* __restrict__ as_,
                      const float* __restrict__ ad_, float* __restrict__ a_s,
                      float* __restrict__ a_d) {
    int i = blockIdx.x * blockDim.x + threadIdx.x;
    if (i >= NN * H) return;
    int n = i / H, hh = i % H;
    const float4* hp = (const float4*)(h + (size_t)n * (H * 32) + hh * 32);
    const float4* sp = (const float4*)(as_ + hh * 32);
    const float4* dp = (const float4*)(ad_ + hh * 32);
    float ss = 0.f, dd = 0.f;
#pragma unroll
    for (int j = 0; j < 8; j++) {
        float4 hv = hp[j], sv = sp[j], dv = dp[j];
        ss += hv.x * sv.x + hv.y * sv.y + hv.z * sv.z + hv.w * sv.w;
        dd += hv.x * dv.x + hv.y * dv.y + hv.z * dv.z + hv.w * dv.w;
    }
    a_s[i] = ss;
    a_d[i] = dd;
}

// -------- fused softmax + aggregate + bias + LayerNorm + ELU (H=4, C=32, 128ch) --------
// block = 128 threads: phase A caches exp(e)+srcid in LDS (deg<=MAXD virtually always),
// phase B: 4 edge-groups x 32 channel-threads, float4 gathers of h.
__global__ __launch_bounds__(128) void k_aggregate_ln(
    const float* __restrict__ h, const float* __restrict__ a_src,
    const float* __restrict__ a_dst, const int* __restrict__ row_ptr,
    const int* __restrict__ esrc, const float* __restrict__ bias,
    const float* __restrict__ gamma, const float* __restrict__ beta,
    float* __restrict__ xout) {
    int n = blockIdx.x;
    int t = threadIdx.x;
    int start = row_ptr[n];
    int end = (n == NN - 1) ? ETOT : row_ptr[n + 1];
    int deg = end - start;

    __shared__ int   s_src[MAXD];
    __shared__ float s_exp[MAXD * 4];
    __shared__ float s_inv[4];
    __shared__ float4 wsum[2];
    __shared__ float4 part[128];

    float4 ad = ((const float4*)a_dst)[n];

    // phase A: exp(leaky(e)) per edge per head; cache in LDS; accumulate denominators
    float4 dsum = make_float4(0.f, 0.f, 0.f, 0.f);
    for (int k = start + t; k < end; k += 128) {
        int j = k - start;
        int s = esrc[k];
        float4 a = ((const float4*)a_src)[s];
        float e0 = a.x + ad.x; e0 = e0 > 0.f ? e0 : SLOPE * e0; float x0 = __expf(e0);
        float e1 = a.y + ad.y; e1 = e1 > 0.f ? e1 : SLOPE * e1; float x1 = __expf(e1);
        float e2 = a.z + ad.z; e2 = e2 > 0.f ? e2 : SLOPE * e2; float x2 = __expf(e2);
        float e3 = a.w + ad.w; e3 = e3 > 0.f ? e3 : SLOPE * e3; float x3 = __expf(e3);
        if (j < MAXD) {
            s_src[j] = s;
            s_exp[j * 4 + 0] = x0; s_exp[j * 4 + 1] = x1;
            s_exp[j * 4 + 2] = x2; s_exp[j * 4 + 3] = x3;
        }
        dsum.x += x0; dsum.y += x1; dsum.z += x2; dsum.w += x3;
    }
#pragma unroll
    for (int m = 1; m < 64; m <<= 1) {
        dsum.x += __shfl_xor(dsum.x, m);
        dsum.y += __shfl_xor(dsum.y, m);
        dsum.z += __shfl_xor(dsum.z, m);
        dsum.w += __shfl_xor(dsum.w, m);
    }
    if ((t & 63) == 0) wsum[t >> 6] = dsum;
    __syncthreads();
    if (t == 0) {
        float4 d2 = make_float4(wsum[0].x + wsum[1].x, wsum[0].y + wsum[1].y,
                                wsum[0].z + wsum[1].z, wsum[0].w + wsum[1].w);
        s_inv[0] = 1.f / (d2.x + 1e-16f);
        s_inv[1] = 1.f / (d2.y + 1e-16f);
        s_inv[2] = 1.f / (d2.z + 1e-16f);
        s_inv[3] = 1.f / (d2.w + 1e-16f);
    }
    __syncthreads();
    // prescale cached exps by 1/denom -> alpha
    int dd4 = (deg < MAXD ? deg : MAXD) * 4;
    for (int idx = t; idx < dd4; idx += 128) s_exp[idx] *= s_inv[idx & 3];
    __syncthreads();

    // phase B: weighted aggregation; group g handles edges j == g (mod 4)
    int g = t >> 5, c32 = t & 31, head = c32 >> 3;
    float4 acc = make_float4(0.f, 0.f, 0.f, 0.f);
    if (deg <= MAXD) {
        for (int j = g; j < deg; j += 4) {
            int s = s_src[j];
            float al = s_exp[j * 4 + head];
            float4 hv = ((const float4*)h)[(size_t)s * 32 + c32];
            acc.x += hv.x * al; acc.y += hv.y * al;
            acc.z += hv.z * al; acc.w += hv.w * al;
        }
    } else {  // cold fallback, ~never taken
        float invh = s_inv[head];
        float adh[4] = {ad.x, ad.y, ad.z, ad.w};
        for (int j = g; j < deg; j += 4) {
            int s = esrc[start + j];
            float4 a = ((const float4*)a_src)[s];
            float ah[4] = {a.x, a.y, a.z, a.w};
            float e = ah[head] + adh[head];
            e = e > 0.f ? e : SLOPE * e;
            float al = __expf(e) * invh;
            float4 hv = ((const float4*)h)[(size_t)s * 32 + c32];
            acc.x += hv.x * al; acc.y += hv.y * al;
            acc.z += hv.z * al; acc.w += hv.w * al;
        }
    }
    part[t] = acc;
    __syncthreads();

    // epilogue: threads 0..31 each own 4 consecutive channels
    if (t < 32) {
        float4 r = part[t];
        float4 r1 = part[t + 32], r2 = part[t + 64], r3 = part[t + 96];
        r.x += r1.x + r2.x + r3.x;
        r.y += r1.y + r2.y + r3.y;
        r.z += r1.z + r2.z + r3.z;
        r.w += r1.w + r2.w + r3.w;
        float4 b = ((const float4*)bias)[t];
        float4 y = make_float4(r.x + b.x, r.y + b.y, r.z + b.z, r.w + b.w);
        float sum = y.x + y.y + y.z + y.w;
#pragma unroll
        for (int m = 16; m > 0; m >>= 1) sum += __shfl_xor(sum, m);
        float mu = sum * (1.f / 128.f);
        float4 d = make_float4(y.x - mu, y.y - mu, y.z - mu, y.w - mu);
        float ss = d.x * d.x + d.y * d.y + d.z * d.z + d.w * d.w;
#pragma unroll
        for (int m = 16; m > 0; m >>= 1) ss += __shfl_xor(ss, m);
        float is = rsqrtf(ss * (1.f / 128.f) + 1e-5f);
        float4 gm = ((const float4*)gamma)[t];
        float4 bt = ((const float4*)beta)[t];
        float z0 = gm.x * (d.x * is) + bt.x;
        float z1 = gm.y * (d.y * is) + bt.y;
        float z2 = gm.z * (d.z * is) + bt.z;
        float z3 = gm.w * (d.w * is) + bt.w;
        float4 o;
        o.x = z0 > 0.f ? z0 : __expf(z0) - 1.f;
        o.y = z1 > 0.f ? z1 : __expf(z1) - 1.f;
        o.z = z2 > 0.f ? z2 : __expf(z2) - 1.f;
        o.w = z3 > 0.f ? z3 : __expf(z3) - 1.f;
        ((float4*)xout)[(size_t)n * 32 + t] = o;
    }
}

// -------- final layer: H=1, C=32, no LN/ELU, writes d_out --------
__global__ __launch_bounds__(64) void k_agg_final(
    const float* __restrict__ hf, const float* __restrict__ a_src,
    const float* __restrict__ a_dst, const int* __restrict__ row_ptr,
    const int* __restrict__ esrc, const float* __restrict__ bf,
    float* __restrict__ out) {
    int n = blockIdx.x;
    int t = threadIdx.x;
    int start = row_ptr[n];
    int end = (n == NN - 1) ? ETOT : row_ptr[n + 1];
    int deg = end - start;
    float adn = a_dst[n];

    __shared__ int   s_src[MAXD];
    __shared__ float s_exp[MAXD];
    __shared__ float4 part[64];

    float dsum = 0.f;
    for (int k = start + t; k < end; k += 64) {
        int j = k - start;
        int s = esrc[k];
        float e = a_src[s] + adn;
        e = e > 0.f ? e : SLOPE * e;
        float x = __expf(e);
        if (j < MAXD) { s_src[j] = s; s_exp[j] = x; }
        dsum += x;
    }
#pragma unroll
    for (int m = 1; m < 64; m <<= 1) dsum += __shfl_xor(dsum, m);
    float inv = 1.f / (dsum + 1e-16f);
    __syncthreads();
    int ddc = deg < MAXD ? deg : MAXD;
    for (int idx = t; idx < ddc; idx += 64) s_exp[idx] *= inv;
    __syncthreads();

    int g = t >> 3, c8 = t & 7;
    float4 acc = make_float4(0.f, 0.f, 0.f, 0.f);
    if (deg <= MAXD) {
        for (int j = g; j < deg; j += 8) {
            int s = s_src[j];
            float al = s_exp[j];
            float4 hv = ((const float4*)hf)[(size_t)s * 8 + c8];
            acc.x += hv.x * al; acc.y += hv.y * al;
            acc.z += hv.z * al; acc.w += hv.w * al;
        }
    } else {
        for (int j = g; j < deg; j += 8) {
            int s = esrc[start + j];
            float e = a_src[s] + adn;
            e = e > 0.f ? e : SLOPE * e;
            float al = __expf(e) * inv;
            float4 hv = ((const float4*)hf)[(size_t)s * 8 + c8];
            acc.x += hv.x * al; acc.y += hv.y * al;
            acc.z += hv.z * al; acc.w += hv.w * al;
        }
    }
    part[t] = acc;
    __syncthreads();
    if (t < 8) {
        float4 r = part[t];
#pragma unroll
        for (int k = 1; k < 8; k++) {
            float4 p = part[t + 8 * k];
            r.x += p.x; r.y += p.y; r.z += p.z; r.w += p.w;
        }
        float4 b4 = ((const float4*)bf)[t];
        float4 o = make_float4(r.x + b4.x, r.y + b4.y, r.z + b4.z, r.w + b4.w);
        ((float4*)out)[(size_t)n * 8 + t] = o;
    }
}

// ---------------- launch ----------------
extern "C" void kernel_launch(void* const* d_in, const int* in_sizes, int n_in,
                              void* d_out, int out_size, void* d_ws,
                              size_t ws_size, hipStream_t stream) {
    const float* x  = (const float*)d_in[0];
    const int* ei   = (const int*)d_in[1];
    const float* W[3]  = {(const float*)d_in[2], (const float*)d_in[8],  (const float*)d_in[14]};
    const float* AS[3] = {(const float*)d_in[3], (const float*)d_in[9],  (const float*)d_in[15]};
    const float* AD[3] = {(const float*)d_in[4], (const float*)d_in[10], (const float*)d_in[16]};
    const float* Bb[3] = {(const float*)d_in[5], (const float*)d_in[11], (const float*)d_in[17]};
    const float* G[3]  = {(const float*)d_in[6], (const float*)d_in[12], (const float*)d_in[18]};
    const float* BE[3] = {(const float*)d_in[7], (const float*)d_in[13], (const float*)d_in[19]};
    const float* Wf  = (const float*)d_in[20];
    const float* asf = (const float*)d_in[21];
    const float* adf = (const float*)d_in[22];
    const float* bfp = (const float*)d_in[23];
    float* out = (float*)d_out;

    float* xbuf = (float*)d_ws;
    float* hbuf = xbuf + (size_t)NN * 128;
    float* a_s  = hbuf + (size_t)NN * 128;
    float* a_d  = a_s + (size_t)NN * 4;
    int* row_ptr  = (int*)(a_d + (size_t)NN * 4);
    int* cnt      = row_ptr + NN;
    int* esrc     = cnt + NN;
    int* partials = esrc + ETOT;

    int nbN = (NN + 255) / 256;
    k_init_counts<<<nbN, 256, 0, stream>>>(cnt);
    k_count<<<(EE + 255) / 256, 256, 0, stream>>>(ei, cnt);
    int nchunks = (NN + 1023) / 1024;
    k_scan1<<<nchunks, 256, 0, stream>>>(cnt, row_ptr, partials);
    k_scan2<<<1, 128, 0, stream>>>(partials, nchunks);
    k_scan3<<<nbN, 256, 0, stream>>>(row_ptr, partials);
    k_copy_int<<<nbN, 256, 0, stream>>>(row_ptr, cnt);  // cnt becomes cursor
    k_fill<<<(ETOT + 255) / 256, 256, 0, stream>>>(ei, cnt, esrc);

    const float* xin = x;
    int K = 64;
    for (int l = 0; l < 3; l++) {
        dim3 g((NN + 127) / 128, 1);
        k_sgemm<128, 128, 16, 8, 8><<<g, 256, 0, stream>>>(xin, W[l], hbuf, NN, K, 128);
        k_att<4><<<(NN * 4 + 255) / 256, 256, 0, stream>>>(hbuf, AS[l], AD[l], a_s, a_d);
        k_aggregate_ln<<<NN, 128, 0, stream>>>(hbuf, a_s, a_d, row_ptr, esrc,
                                               Bb[l], G[l], BE[l], xbuf);
        xin = xbuf;
        K = 128;
    }
    k_sgemm<64, 32, 16, 4, 4><<<dim3((NN + 63) / 64, 1), 128, 0, stream>>>(
        xbuf, Wf, hbuf, NN, 128, 32);
    k_att<1><<<(NN + 255) / 256, 256, 0, stream>>>(hbuf, asf, adf, a_s, a_d);
    k_agg_final<<<NN, 64, 0, stream>>>(hbuf, a_s, a_d, row_ptr, esrc, bfp, out);
}

// Round 3
// 869.918 us; speedup vs baseline: 1.3276x; 1.2017x over previous
//
#include <hip/hip_runtime.h>
#include <hip/hip_bf16.h>

constexpr int NN   = 100000;
constexpr int EE   = 1600000;
constexpr int ETOT = EE + NN;
constexpr float SLOPE = 0.2f;
constexpr int MAXD = 96;   // degree cap for LDS edge cache (Poisson(16)+1, max~45)

__device__ __forceinline__ float bf_lo(unsigned u) { return __uint_as_float(u << 16); }
__device__ __forceinline__ float bf_hi(unsigned u) { return __uint_as_float(u & 0xffff0000u); }

// ---------------- CSR build ----------------
__global__ void k_init_counts(int* cnt) {
    int i = blockIdx.x * blockDim.x + threadIdx.x;
    if (i < NN) cnt[i] = 1;  // self loop counted up front
}

__global__ void k_count(const int* __restrict__ ei, int* __restrict__ cnt) {
    int i = blockIdx.x * blockDim.x + threadIdx.x;
    if (i < EE) atomicAdd(&cnt[ei[EE + i]], 1);
}

__global__ void k_scan1(const int* __restrict__ in, int* __restrict__ out,
                        int* __restrict__ partials) {
    __shared__ int sd[256];
    int base = blockIdx.x * 1024;
    int t = threadIdx.x;
    int i = base + t * 4;
    int v0 = (i + 0 < NN) ? in[i + 0] : 0;
    int v1 = (i + 1 < NN) ? in[i + 1] : 0;
    int v2 = (i + 2 < NN) ? in[i + 2] : 0;
    int v3 = (i + 3 < NN) ? in[i + 3] : 0;
    int s = v0 + v1 + v2 + v3;
    sd[t] = s;
    __syncthreads();
    for (int off = 1; off < 256; off <<= 1) {
        int x = (t >= off) ? sd[t - off] : 0;
        __syncthreads();
        sd[t] += x;
        __syncthreads();
    }
    int run = sd[t] - s;  // exclusive prefix of thread sums
    if (i + 0 < NN) out[i + 0] = run; run += v0;
    if (i + 1 < NN) out[i + 1] = run; run += v1;
    if (i + 2 < NN) out[i + 2] = run; run += v2;
    if (i + 3 < NN) out[i + 3] = run;
    if (t == 255) partials[blockIdx.x] = sd[255];
}

__global__ void k_scan2(int* partials, int m) {
    __shared__ int sd[128];
    int t = threadIdx.x;
    int v = (t < m) ? partials[t] : 0;
    sd[t] = v;
    __syncthreads();
    for (int off = 1; off < 128; off <<= 1) {
        int x = (t >= off) ? sd[t - off] : 0;
        __syncthreads();
        sd[t] += x;
        __syncthreads();
    }
    if (t < m) partials[t] = sd[t] - v;
}

__global__ void k_scan3(int* out, const int* __restrict__ partials) {
    int i = blockIdx.x * blockDim.x + threadIdx.x;
    if (i < NN) out[i] += partials[i >> 10];
}

__global__ void k_copy_int(const int* __restrict__ in, int* __restrict__ out) {
    int i = blockIdx.x * blockDim.x + threadIdx.x;
    if (i < NN) out[i] = in[i];
}

__global__ void k_fill(const int* __restrict__ ei, int* __restrict__ cursor,
                       int* __restrict__ esrc) {
    int i = blockIdx.x * blockDim.x + threadIdx.x;
    if (i >= ETOT) return;
    int s, d;
    if (i < EE) { s = ei[i]; d = ei[EE + i]; }
    else        { s = i - EE; d = s; }
    int pos = atomicAdd(&cursor[d], 1);
    esrc[pos] = s;
}

// ------- fp32 GEMM (full width in one col-block) + fused attention dots + bf16 h store -------
// C-tile stays in registers; epilogue computes a_s[n,h]=<h[n,h,:],as[h,:]> via shuffle
// reduction over the fp32 accumulators, stores h as bf16 only.
template <int BM, int BN, int BK, int TM, int TN, int H>
__global__ __launch_bounds__((BM / TM) * (BN / TN)) void k_gemm_att(
    const float* __restrict__ A, const float* __restrict__ B,
    const float* __restrict__ as_, const float* __restrict__ ad_,
    unsigned short* __restrict__ hb, float* __restrict__ a_s,
    float* __restrict__ a_d, int M, int K) {
    constexpr int THREADS = (BM / TM) * (BN / TN);
    constexpr int TX = BN / TN;
    __shared__ __align__(16) float As[BK][BM + 4];
    __shared__ __align__(16) float Bs[BK][BN + 4];
    int tid = threadIdx.x;
    int tx = tid % TX, ty = tid / TX;
    int rowBase = blockIdx.x * BM;
    float acc[TM][TN];
#pragma unroll
    for (int i = 0; i < TM; i++)
#pragma unroll
        for (int j = 0; j < TN; j++) acc[i][j] = 0.f;

    constexpr int LA = (BM * BK) / (THREADS * 4);
    constexpr int LB = (BK * BN) / (THREADS * 4);
    for (int k0 = 0; k0 < K; k0 += BK) {
#pragma unroll
        for (int l = 0; l < LA; l++) {
            int idx = tid + l * THREADS;
            int m = idx / (BK / 4);
            int kk = (idx % (BK / 4)) * 4;
            float4 v = make_float4(0.f, 0.f, 0.f, 0.f);
            int gr = rowBase + m;
            if (gr < M) v = *(const float4*)(A + (size_t)gr * K + k0 + kk);
            As[kk + 0][m] = v.x; As[kk + 1][m] = v.y;
            As[kk + 2][m] = v.z; As[kk + 3][m] = v.w;
        }
#pragma unroll
        for (int l = 0; l < LB; l++) {
            int idx = tid + l * THREADS;
            int kk = idx / (BN / 4);
            int c = (idx % (BN / 4)) * 4;
            float4 v = *(const float4*)(B + (size_t)(k0 + kk) * BN + c);
            *(float4*)(&Bs[kk][c]) = v;
        }
        __syncthreads();
#pragma unroll
        for (int k = 0; k < BK; k++) {
            float a[TM], b[TN];
#pragma unroll
            for (int i = 0; i < TM; i++) a[i] = As[k][ty * TM + i];
#pragma unroll
            for (int j = 0; j < TN; j++) b[j] = Bs[k][tx * TN + j];
#pragma unroll
            for (int i = 0; i < TM; i++)
#pragma unroll
                for (int j = 0; j < TN; j++) acc[i][j] += a[i] * b[j];
        }
        __syncthreads();
    }

    // epilogue: per-thread columns tx*TN..tx*TN+TN-1 lie within one head (C=32, TN|32)
    int head = (tx * TN) >> 5;
    int cc0 = (tx * TN) & 31;
    float sw[TN], dw[TN];
#pragma unroll
    for (int j = 0; j < TN; j++) {
        sw[j] = as_[head * 32 + cc0 + j];
        dw[j] = ad_[head * 32 + cc0 + j];
    }
    constexpr int LPH = 32 / TN;  // lanes covering one head's 32 channels
#pragma unroll
    for (int i = 0; i < TM; i++) {
        int gr = rowBase + ty * TM + i;
        float ps = 0.f, pd = 0.f;
#pragma unroll
        for (int j = 0; j < TN; j++) { ps += acc[i][j] * sw[j]; pd += acc[i][j] * dw[j]; }
#pragma unroll
        for (int m = 1; m < LPH; m <<= 1) {
            ps += __shfl_xor(ps, m);
            pd += __shfl_xor(pd, m);
        }
        if (gr < M) {
            if ((tx & (LPH - 1)) == 0) {
                a_s[(size_t)gr * H + head] = ps;
                a_d[(size_t)gr * H + head] = pd;
            }
            __hip_bfloat16 hv[TN];
#pragma unroll
            for (int j = 0; j < TN; j++) hv[j] = __float2bfloat16(acc[i][j]);
            if constexpr (TN == 8)
                *(uint4*)(hb + (size_t)gr * BN + tx * TN) = *(uint4*)hv;
            else
                *(uint2*)(hb + (size_t)gr * BN + tx * TN) = *(uint2*)hv;
        }
    }
}

// -------- fused softmax + aggregate(bf16 h) + bias + LayerNorm + ELU (H=4, 128ch) --------
__global__ __launch_bounds__(128) void k_aggregate_ln(
    const unsigned short* __restrict__ hb, const float* __restrict__ a_src,
    const float* __restrict__ a_dst, const int* __restrict__ row_ptr,
    const int* __restrict__ esrc, const float* __restrict__ bias,
    const float* __restrict__ gamma, const float* __restrict__ beta,
    float* __restrict__ xout) {
    int n = blockIdx.x;
    int t = threadIdx.x;
    int start = row_ptr[n];
    int end = (n == NN - 1) ? ETOT : row_ptr[n + 1];
    int deg = end - start;

    __shared__ int   s_src[MAXD];
    __shared__ float s_exp[MAXD * 4];
    __shared__ float s_inv[4];
    __shared__ float4 wsum[2];
    __shared__ float s_tmp[16][8];

    float4 ad = ((const float4*)a_dst)[n];

    // phase A: exp(leaky(e)) per edge per head; cache in LDS; accumulate denominators
    float4 dsum = make_float4(0.f, 0.f, 0.f, 0.f);
    for (int k = start + t; k < end; k += 128) {
        int j = k - start;
        int s = esrc[k];
        float4 a = ((const float4*)a_src)[s];
        float e0 = a.x + ad.x; e0 = e0 > 0.f ? e0 : SLOPE * e0; float x0 = __expf(e0);
        float e1 = a.y + ad.y; e1 = e1 > 0.f ? e1 : SLOPE * e1; float x1 = __expf(e1);
        float e2 = a.z + ad.z; e2 = e2 > 0.f ? e2 : SLOPE * e2; float x2 = __expf(e2);
        float e3 = a.w + ad.w; e3 = e3 > 0.f ? e3 : SLOPE * e3; float x3 = __expf(e3);
        if (j < MAXD) {
            s_src[j] = s;
            s_exp[j * 4 + 0] = x0; s_exp[j * 4 + 1] = x1;
            s_exp[j * 4 + 2] = x2; s_exp[j * 4 + 3] = x3;
        }
        dsum.x += x0; dsum.y += x1; dsum.z += x2; dsum.w += x3;
    }
#pragma unroll
    for (int m = 1; m < 64; m <<= 1) {
        dsum.x += __shfl_xor(dsum.x, m);
        dsum.y += __shfl_xor(dsum.y, m);
        dsum.z += __shfl_xor(dsum.z, m);
        dsum.w += __shfl_xor(dsum.w, m);
    }
    if ((t & 63) == 0) wsum[t >> 6] = dsum;
    __syncthreads();
    if (t == 0) {
        float4 d2 = make_float4(wsum[0].x + wsum[1].x, wsum[0].y + wsum[1].y,
                                wsum[0].z + wsum[1].z, wsum[0].w + wsum[1].w);
        s_inv[0] = 1.f / (d2.x + 1e-16f);
        s_inv[1] = 1.f / (d2.y + 1e-16f);
        s_inv[2] = 1.f / (d2.z + 1e-16f);
        s_inv[3] = 1.f / (d2.w + 1e-16f);
    }
    __syncthreads();
    int dd4 = (deg < MAXD ? deg : MAXD) * 4;
    for (int idx = t; idx < dd4; idx += 128) s_exp[idx] *= s_inv[idx & 3];
    __syncthreads();

    // phase B: 8 edge-groups x 16 channel-threads x 8 bf16 channels (uint4 loads)
    int g = t >> 4, c16 = t & 15, head = c16 >> 2;
    float acc[8];
#pragma unroll
    for (int k = 0; k < 8; k++) acc[k] = 0.f;
    if (deg <= MAXD) {
        for (int j = g; j < deg; j += 8) {
            int s = s_src[j];
            float al = s_exp[j * 4 + head];
            uint4 u = *(const uint4*)(hb + (size_t)s * 128 + c16 * 8);
            acc[0] += bf_lo(u.x) * al; acc[1] += bf_hi(u.x) * al;
            acc[2] += bf_lo(u.y) * al; acc[3] += bf_hi(u.y) * al;
            acc[4] += bf_lo(u.z) * al; acc[5] += bf_hi(u.z) * al;
            acc[6] += bf_lo(u.w) * al; acc[7] += bf_hi(u.w) * al;
        }
    } else {  // cold fallback, ~never taken
        float invh = s_inv[head];
        float adh[4] = {ad.x, ad.y, ad.z, ad.w};
        for (int j = g; j < deg; j += 8) {
            int s = esrc[start + j];
            float e = a_src[(size_t)s * 4 + head] + adh[head];
            e = e > 0.f ? e : SLOPE * e;
            float al = __expf(e) * invh;
            uint4 u = *(const uint4*)(hb + (size_t)s * 128 + c16 * 8);
            acc[0] += bf_lo(u.x) * al; acc[1] += bf_hi(u.x) * al;
            acc[2] += bf_lo(u.y) * al; acc[3] += bf_hi(u.y) * al;
            acc[4] += bf_lo(u.z) * al; acc[5] += bf_hi(u.z) * al;
            acc[6] += bf_lo(u.w) * al; acc[7] += bf_hi(u.w) * al;
        }
    }
    // sum the 4 groups within each wave (lanes c16, c16+16, c16+32, c16+48)
#pragma unroll
    for (int k = 0; k < 8; k++) {
        acc[k] += __shfl_xor(acc[k], 16);
        acc[k] += __shfl_xor(acc[k], 32);
    }
    if (t >= 64 && (t & 63) < 16) {
#pragma unroll
        for (int k = 0; k < 8; k++) s_tmp[t & 15][k] = acc[k];
    }
    __syncthreads();
    if (t < 16) {
        float y[8];
        float sum = 0.f;
#pragma unroll
        for (int k = 0; k < 8; k++) {
            y[k] = acc[k] + s_tmp[t][k] + bias[t * 8 + k];
            sum += y[k];
        }
#pragma unroll
        for (int m = 1; m < 16; m <<= 1) sum += __shfl_xor(sum, m);
        float mu = sum * (1.f / 128.f);
        float ss = 0.f;
        float d[8];
#pragma unroll
        for (int k = 0; k < 8; k++) { d[k] = y[k] - mu; ss += d[k] * d[k]; }
#pragma unroll
        for (int m = 1; m < 16; m <<= 1) ss += __shfl_xor(ss, m);
        float is = rsqrtf(ss * (1.f / 128.f) + 1e-5f);
        float o[8];
#pragma unroll
        for (int k = 0; k < 8; k++) {
            float z = gamma[t * 8 + k] * (d[k] * is) + beta[t * 8 + k];
            o[k] = z > 0.f ? z : __expf(z) - 1.f;
        }
        float4* op = (float4*)(xout + (size_t)n * 128 + t * 8);
        op[0] = make_float4(o[0], o[1], o[2], o[3]);
        op[1] = make_float4(o[4], o[5], o[6], o[7]);
    }
}

// -------- final layer: H=1, C=32 (bf16 h), no LN/ELU, writes d_out --------
__global__ __launch_bounds__(64) void k_agg_final(
    const unsigned short* __restrict__ hb, const float* __restrict__ a_src,
    const float* __restrict__ a_dst, const int* __restrict__ row_ptr,
    const int* __restrict__ esrc, const float* __restrict__ bf,
    float* __restrict__ out) {
    int n = blockIdx.x;
    int t = threadIdx.x;
    int start = row_ptr[n];
    int end = (n == NN - 1) ? ETOT : row_ptr[n + 1];
    int deg = end - start;
    float adn = a_dst[n];

    __shared__ int   s_src[MAXD];
    __shared__ float s_exp[MAXD];

    float dsum = 0.f;
    for (int k = start + t; k < end; k += 64) {
        int j = k - start;
        int s = esrc[k];
        float e = a_src[s] + adn;
        e = e > 0.f ? e : SLOPE * e;
        float x = __expf(e);
        if (j < MAXD) { s_src[j] = s; s_exp[j] = x; }
        dsum += x;
    }
#pragma unroll
    for (int m = 1; m < 64; m <<= 1) dsum += __shfl_xor(dsum, m);
    float inv = 1.f / (dsum + 1e-16f);
    __syncthreads();
    int ddc = deg < MAXD ? deg : MAXD;
    for (int idx = t; idx < ddc; idx += 64) s_exp[idx] *= inv;
    __syncthreads();

    // 8 edge-groups x 8 channel-threads x 4 bf16 channels
    int g = t >> 3, c8 = t & 7;
    float acc[4] = {0.f, 0.f, 0.f, 0.f};
    if (deg <= MAXD) {
        for (int j = g; j < deg; j += 8) {
            int s = s_src[j];
            float al = s_exp[j];
            uint2 u = *(const uint2*)(hb + (size_t)s * 32 + c8 * 4);
            acc[0] += bf_lo(u.x) * al; acc[1] += bf_hi(u.x) * al;
            acc[2] += bf_lo(u.y) * al; acc[3] += bf_hi(u.y) * al;
        }
    } else {
        for (int j = g; j < deg; j += 8) {
            int s = esrc[start + j];
            float e = a_src[s] + adn;
            e = e > 0.f ? e : SLOPE * e;
            float al = __expf(e) * inv;
            uint2 u = *(const uint2*)(hb + (size_t)s * 32 + c8 * 4);
            acc[0] += bf_lo(u.x) * al; acc[1] += bf_hi(u.x) * al;
            acc[2] += bf_lo(u.y) * al; acc[3] += bf_hi(u.y) * al;
        }
    }
#pragma unroll
    for (int k = 0; k < 4; k++) {
        acc[k] += __shfl_xor(acc[k], 8);
        acc[k] += __shfl_xor(acc[k], 16);
        acc[k] += __shfl_xor(acc[k], 32);
    }
    if (t < 8) {
        float4 b4 = ((const float4*)bf)[t];
        float4 o = make_float4(acc[0] + b4.x, acc[1] + b4.y, acc[2] + b4.z,
                               acc[3] + b4.w);
        ((float4*)out)[(size_t)n * 8 + t] = o;
    }
}

// ---------------- launch ----------------
extern "C" void kernel_launch(void* const* d_in, const int* in_sizes, int n_in,
                              void* d_out, int out_size, void* d_ws,
                              size_t ws_size, hipStream_t stream) {
    const float* x  = (const float*)d_in[0];
    const int* ei   = (const int*)d_in[1];
    const float* W[3]  = {(const float*)d_in[2], (const float*)d_in[8],  (const float*)d_in[14]};
    const float* AS[3] = {(const float*)d_in[3], (const float*)d_in[9],  (const float*)d_in[15]};
    const float* AD[3] = {(const float*)d_in[4], (const float*)d_in[10], (const float*)d_in[16]};
    const float* Bb[3] = {(const float*)d_in[5], (const float*)d_in[11], (const float*)d_in[17]};
    const float* G[3]  = {(const float*)d_in[6], (const float*)d_in[12], (const float*)d_in[18]};
    const float* BE[3] = {(const float*)d_in[7], (const float*)d_in[13], (const float*)d_in[19]};
    const float* Wf  = (const float*)d_in[20];
    const float* asf = (const float*)d_in[21];
    const float* adf = (const float*)d_in[22];
    const float* bfp = (const float*)d_in[23];
    float* out = (float*)d_out;

    float* xbuf = (float*)d_ws;                       // NN*128 f32
    unsigned short* hb = (unsigned short*)(xbuf + (size_t)NN * 128);  // NN*128 bf16
    float* a_s  = (float*)(hb + (size_t)NN * 128);
    float* a_d  = a_s + (size_t)NN * 4;
    int* row_ptr  = (int*)(a_d + (size_t)NN * 4);
    int* cnt      = row_ptr + NN;
    int* esrc     = cnt + NN;
    int* partials = esrc + ETOT;

    int nbN = (NN + 255) / 256;
    k_init_counts<<<nbN, 256, 0, stream>>>(cnt);
    k_count<<<(EE + 255) / 256, 256, 0, stream>>>(ei, cnt);
    int nchunks = (NN + 1023) / 1024;
    k_scan1<<<nchunks, 256, 0, stream>>>(cnt, row_ptr, partials);
    k_scan2<<<1, 128, 0, stream>>>(partials, nchunks);
    k_scan3<<<nbN, 256, 0, stream>>>(row_ptr, partials);
    k_copy_int<<<nbN, 256, 0, stream>>>(row_ptr, cnt);  // cnt becomes cursor
    k_fill<<<(ETOT + 255) / 256, 256, 0, stream>>>(ei, cnt, esrc);

    const float* xin = x;
    int K = 64;
    for (int l = 0; l < 3; l++) {
        k_gemm_att<128, 128, 16, 8, 8, 4><<<(NN + 127) / 128, 256, 0, stream>>>(
            xin, W[l], AS[l], AD[l], hb, a_s, a_d, NN, K);
        k_aggregate_ln<<<NN, 128, 0, stream>>>(hb, a_s, a_d, row_ptr, esrc,
                                               Bb[l], G[l], BE[l], xbuf);
        xin = xbuf;
        K = 128;
    }
    k_gemm_att<64, 32, 16, 4, 4, 1><<<(NN + 63) / 64, 128, 0, stream>>>(
        xbuf, Wf, asf, adf, hb, a_s, a_d, NN, 128);
    k_agg_final<<<NN, 64, 0, stream>>>(hb, a_s, a_d, row_ptr, esrc, bfp, out);
}

// Round 4
// 784.774 us; speedup vs baseline: 1.4717x; 1.1085x over previous
//
#include <hip/hip_runtime.h>
#include <hip/hip_bf16.h>

constexpr int NN   = 100000;
constexpr int EE   = 1600000;
constexpr int ETOT = EE + NN;
constexpr float SLOPE = 0.2f;
constexpr int MAXD = 96;    // degree cap for LDS edge cache (Poisson(16)+1, max~45)
constexpr int BSH = 10;     // nodes per bucket = 1024
constexpr int NB  = (NN + (1 << BSH) - 1) >> BSH;  // 98 buckets
constexpr int CCH = 8192;   // edges per scatter block

__device__ __forceinline__ float bf_lo(unsigned u) { return __uint_as_float(u << 16); }
__device__ __forceinline__ float bf_hi(unsigned u) { return __uint_as_float(u & 0xffff0000u); }

// ---------------- bucketed CSR build ----------------
__global__ void k_zero(int* p, int n) {
    int i = blockIdx.x * blockDim.x + threadIdx.x;
    if (i < n) p[i] = 0;
}

__global__ __launch_bounds__(256) void k_bhist(const int* __restrict__ ei,
                                               int* __restrict__ gbh) {
    __shared__ int h[NB];
    int t = threadIdx.x;
    if (t < NB) h[t] = 0;
    __syncthreads();
    int i = blockIdx.x * 2048 + t;
#pragma unroll
    for (int k = 0; k < 8; k++, i += 256)
        if (i < EE) atomicAdd(&h[ei[EE + i] >> BSH], 1);
    __syncthreads();
    if (t < NB && h[t]) atomicAdd(&gbh[t], h[t]);
}

__global__ void k_bscan(const int* __restrict__ gbh, int* __restrict__ ebase,
                        int* __restrict__ gcur) {
    __shared__ int sd[128];
    int t = threadIdx.x;
    int v = (t < NB) ? gbh[t] : 0;
    sd[t] = v;
    __syncthreads();
    for (int off = 1; off < 128; off <<= 1) {
        int x = (t >= off) ? sd[t - off] : 0;
        __syncthreads();
        sd[t] += x;
        __syncthreads();
    }
    int ex = sd[t] - v;
    if (t < NB) { ebase[t] = ex; gcur[t] = ex; }
    if (t == NB) ebase[NB] = EE;
}

__global__ __launch_bounds__(256) void k_bscatter(const int* __restrict__ ei,
                                                  int* __restrict__ gcur,
                                                  int* __restrict__ pbuf) {
    __shared__ int h[NB], base[NB], cur[NB];
    int t = threadIdx.x;
    if (t < NB) { h[t] = 0; cur[t] = 0; }
    __syncthreads();
    int c0 = blockIdx.x * CCH;
    int cend = c0 + CCH < EE ? c0 + CCH : EE;
    for (int i = c0 + t; i < cend; i += 256)
        atomicAdd(&h[ei[EE + i] >> BSH], 1);
    __syncthreads();
    if (t < NB && h[t] > 0) base[t] = atomicAdd(&gcur[t], h[t]);
    __syncthreads();
    for (int i = c0 + t; i < cend; i += 256) {
        int s = ei[i], d = ei[EE + i];
        int b = d >> BSH;
        int c = atomicAdd(&cur[b], 1);
        pbuf[base[b] + c] = s | ((d & ((1 << BSH) - 1)) << 17);
    }
}

// one block per bucket: degree hist -> scan -> row_ptr + self loops -> scatter esrc
__global__ __launch_bounds__(256) void k_bcsr(const int* __restrict__ pbuf,
                                              const int* __restrict__ ebase,
                                              int* __restrict__ row_ptr,
                                              int* __restrict__ esrc) {
    constexpr int BNODES = 1 << BSH;
    __shared__ int hist[BNODES];
    __shared__ int cur[BNODES];
    __shared__ int sd[256];
    int b = blockIdx.x, t = threadIdx.x;
    int node0 = b << BSH;
    int e0 = ebase[b], e1 = ebase[b + 1];
    for (int i = t; i < BNODES; i += 256) { hist[i] = 0; cur[i] = 0; }
    __syncthreads();
    for (int i = e0 + t; i < e1; i += 256)
        atomicAdd(&hist[pbuf[i] >> 17], 1);
    __syncthreads();
    int s0 = hist[4 * t], s1 = hist[4 * t + 1], s2 = hist[4 * t + 2], s3 = hist[4 * t + 3];
    int ts = s0 + s1 + s2 + s3;
    sd[t] = ts;
    __syncthreads();
    for (int off = 1; off < 256; off <<= 1) {
        int x = (t >= off) ? sd[t - off] : 0;
        __syncthreads();
        sd[t] += x;
        __syncthreads();
    }
    int ex = sd[t] - ts;
    hist[4 * t] = ex;
    hist[4 * t + 1] = ex + s0;
    hist[4 * t + 2] = ex + s0 + s1;
    hist[4 * t + 3] = ex + s0 + s1 + s2;
    __syncthreads();
    int rbase = e0 + node0;  // earlier buckets' edges + earlier nodes' self slots
    for (int nl = t; nl < BNODES; nl += 256) {
        int n = node0 + nl;
        if (n < NN) {
            int rp = rbase + hist[nl] + nl;
            row_ptr[n] = rp;
            esrc[rp] = n;  // self loop in slot 0
        }
    }
    __syncthreads();
    for (int i = e0 + t; i < e1; i += 256) {
        int p = pbuf[i];
        int nl = p >> 17;
        int c = atomicAdd(&cur[nl], 1);
        esrc[rbase + hist[nl] + nl + 1 + c] = p & 0x1FFFF;
    }
}

// ------- fp32 GEMM (full width in one col-block) + fused attention dots + bf16 h store -------
template <int BM, int BN, int BK, int TM, int TN, int H>
__global__ __launch_bounds__((BM / TM) * (BN / TN)) void k_gemm_att(
    const float* __restrict__ A, const float* __restrict__ B,
    const float* __restrict__ as_, const float* __restrict__ ad_,
    unsigned short* __restrict__ hb, float* __restrict__ a_s,
    float* __restrict__ a_d, int M, int K) {
    constexpr int THREADS = (BM / TM) * (BN / TN);
    constexpr int TX = BN / TN;
    __shared__ __align__(16) float As[BK][BM + 4];
    __shared__ __align__(16) float Bs[BK][BN + 4];
    int tid = threadIdx.x;
    int tx = tid % TX, ty = tid / TX;
    int rowBase = blockIdx.x * BM;
    float acc[TM][TN];
#pragma unroll
    for (int i = 0; i < TM; i++)
#pragma unroll
        for (int j = 0; j < TN; j++) acc[i][j] = 0.f;

    constexpr int LA = (BM * BK) / (THREADS * 4);
    constexpr int LB = (BK * BN) / (THREADS * 4);
    for (int k0 = 0; k0 < K; k0 += BK) {
#pragma unroll
        for (int l = 0; l < LA; l++) {
            int idx = tid + l * THREADS;
            int m = idx / (BK / 4);
            int kk = (idx % (BK / 4)) * 4;
            float4 v = make_float4(0.f, 0.f, 0.f, 0.f);
            int gr = rowBase + m;
            if (gr < M) v = *(const float4*)(A + (size_t)gr * K + k0 + kk);
            As[kk + 0][m] = v.x; As[kk + 1][m] = v.y;
            As[kk + 2][m] = v.z; As[kk + 3][m] = v.w;
        }
#pragma unroll
        for (int l = 0; l < LB; l++) {
            int idx = tid + l * THREADS;
            int kk = idx / (BN / 4);
            int c = (idx % (BN / 4)) * 4;
            float4 v = *(const float4*)(B + (size_t)(k0 + kk) * BN + c);
            *(float4*)(&Bs[kk][c]) = v;
        }
        __syncthreads();
#pragma unroll
        for (int k = 0; k < BK; k++) {
            float a[TM], b[TN];
#pragma unroll
            for (int i = 0; i < TM; i++) a[i] = As[k][ty * TM + i];
#pragma unroll
            for (int j = 0; j < TN; j++) b[j] = Bs[k][tx * TN + j];
#pragma unroll
            for (int i = 0; i < TM; i++)
#pragma unroll
                for (int j = 0; j < TN; j++) acc[i][j] += a[i] * b[j];
        }
        __syncthreads();
    }

    int head = (tx * TN) >> 5;
    int cc0 = (tx * TN) & 31;
    float sw[TN], dw[TN];
#pragma unroll
    for (int j = 0; j < TN; j++) {
        sw[j] = as_[head * 32 + cc0 + j];
        dw[j] = ad_[head * 32 + cc0 + j];
    }
    constexpr int LPH = 32 / TN;
#pragma unroll
    for (int i = 0; i < TM; i++) {
        int gr = rowBase + ty * TM + i;
        float ps = 0.f, pd = 0.f;
#pragma unroll
        for (int j = 0; j < TN; j++) { ps += acc[i][j] * sw[j]; pd += acc[i][j] * dw[j]; }
#pragma unroll
        for (int m = 1; m < LPH; m <<= 1) {
            ps += __shfl_xor(ps, m);
            pd += __shfl_xor(pd, m);
        }
        if (gr < M) {
            if ((tx & (LPH - 1)) == 0) {
                a_s[(size_t)gr * H + head] = ps;
                a_d[(size_t)gr * H + head] = pd;
            }
            __hip_bfloat16 hv[TN];
#pragma unroll
            for (int j = 0; j < TN; j++) hv[j] = __float2bfloat16(acc[i][j]);
            if constexpr (TN == 8)
                *(uint4*)(hb + (size_t)gr * BN + tx * TN) = *(uint4*)hv;
            else
                *(uint2*)(hb + (size_t)gr * BN + tx * TN) = *(uint2*)hv;
        }
    }
}

// -------- fused softmax + aggregate(bf16 h) + bias + LayerNorm + ELU (H=4, 128ch) --------
__global__ __launch_bounds__(128) void k_aggregate_ln(
    const unsigned short* __restrict__ hb, const float* __restrict__ a_src,
    const float* __restrict__ a_dst, const int* __restrict__ row_ptr,
    const int* __restrict__ esrc, const float* __restrict__ bias,
    const float* __restrict__ gamma, const float* __restrict__ beta,
    float* __restrict__ xout) {
    int n = blockIdx.x;
    int t = threadIdx.x;
    int start = row_ptr[n];
    int end = (n == NN - 1) ? ETOT : row_ptr[n + 1];
    int deg = end - start;

    __shared__ int   s_src[MAXD];
    __shared__ float s_exp[MAXD * 4];
    __shared__ float s_inv[4];
    __shared__ float4 wsum[2];
    __shared__ float s_tmp[16][8];

    float4 ad = ((const float4*)a_dst)[n];

    float4 dsum = make_float4(0.f, 0.f, 0.f, 0.f);
    for (int k = start + t; k < end; k += 128) {
        int j = k - start;
        int s = esrc[k];
        float4 a = ((const float4*)a_src)[s];
        float e0 = a.x + ad.x; e0 = e0 > 0.f ? e0 : SLOPE * e0; float x0 = __expf(e0);
        float e1 = a.y + ad.y; e1 = e1 > 0.f ? e1 : SLOPE * e1; float x1 = __expf(e1);
        float e2 = a.z + ad.z; e2 = e2 > 0.f ? e2 : SLOPE * e2; float x2 = __expf(e2);
        float e3 = a.w + ad.w; e3 = e3 > 0.f ? e3 : SLOPE * e3; float x3 = __expf(e3);
        if (j < MAXD) {
            s_src[j] = s;
            s_exp[j * 4 + 0] = x0; s_exp[j * 4 + 1] = x1;
            s_exp[j * 4 + 2] = x2; s_exp[j * 4 + 3] = x3;
        }
        dsum.x += x0; dsum.y += x1; dsum.z += x2; dsum.w += x3;
    }
#pragma unroll
    for (int m = 1; m < 64; m <<= 1) {
        dsum.x += __shfl_xor(dsum.x, m);
        dsum.y += __shfl_xor(dsum.y, m);
        dsum.z += __shfl_xor(dsum.z, m);
        dsum.w += __shfl_xor(dsum.w, m);
    }
    if ((t & 63) == 0) wsum[t >> 6] = dsum;
    __syncthreads();
    if (t == 0) {
        float4 d2 = make_float4(wsum[0].x + wsum[1].x, wsum[0].y + wsum[1].y,
                                wsum[0].z + wsum[1].z, wsum[0].w + wsum[1].w);
        s_inv[0] = 1.f / (d2.x + 1e-16f);
        s_inv[1] = 1.f / (d2.y + 1e-16f);
        s_inv[2] = 1.f / (d2.z + 1e-16f);
        s_inv[3] = 1.f / (d2.w + 1e-16f);
    }
    __syncthreads();
    int dd4 = (deg < MAXD ? deg : MAXD) * 4;
    for (int idx = t; idx < dd4; idx += 128) s_exp[idx] *= s_inv[idx & 3];
    __syncthreads();

    int g = t >> 4, c16 = t & 15, head = c16 >> 2;
    float acc[8];
#pragma unroll
    for (int k = 0; k < 8; k++) acc[k] = 0.f;
    if (deg <= MAXD) {
        for (int j = g; j < deg; j += 8) {
            int s = s_src[j];
            float al = s_exp[j * 4 + head];
            uint4 u = *(const uint4*)(hb + (size_t)s * 128 + c16 * 8);
            acc[0] += bf_lo(u.x) * al; acc[1] += bf_hi(u.x) * al;
            acc[2] += bf_lo(u.y) * al; acc[3] += bf_hi(u.y) * al;
            acc[4] += bf_lo(u.z) * al; acc[5] += bf_hi(u.z) * al;
            acc[6] += bf_lo(u.w) * al; acc[7] += bf_hi(u.w) * al;
        }
    } else {
        float invh = s_inv[head];
        float adh[4] = {ad.x, ad.y, ad.z, ad.w};
        for (int j = g; j < deg; j += 8) {
            int s = esrc[start + j];
            float e = a_src[(size_t)s * 4 + head] + adh[head];
            e = e > 0.f ? e : SLOPE * e;
            float al = __expf(e) * invh;
            uint4 u = *(const uint4*)(hb + (size_t)s * 128 + c16 * 8);
            acc[0] += bf_lo(u.x) * al; acc[1] += bf_hi(u.x) * al;
            acc[2] += bf_lo(u.y) * al; acc[3] += bf_hi(u.y) * al;
            acc[4] += bf_lo(u.z) * al; acc[5] += bf_hi(u.z) * al;
            acc[6] += bf_lo(u.w) * al; acc[7] += bf_hi(u.w) * al;
        }
    }
#pragma unroll
    for (int k = 0; k < 8; k++) {
        acc[k] += __shfl_xor(acc[k], 16);
        acc[k] += __shfl_xor(acc[k], 32);
    }
    if (t >= 64 && (t & 63) < 16) {
#pragma unroll
        for (int k = 0; k < 8; k++) s_tmp[t & 15][k] = acc[k];
    }
    __syncthreads();
    if (t < 16) {
        float y[8];
        float sum = 0.f;
#pragma unroll
        for (int k = 0; k < 8; k++) {
            y[k] = acc[k] + s_tmp[t][k] + bias[t * 8 + k];
            sum += y[k];
        }
#pragma unroll
        for (int m = 1; m < 16; m <<= 1) sum += __shfl_xor(sum, m);
        float mu = sum * (1.f / 128.f);
        float ss = 0.f;
        float d[8];
#pragma unroll
        for (int k = 0; k < 8; k++) { d[k] = y[k] - mu; ss += d[k] * d[k]; }
#pragma unroll
        for (int m = 1; m < 16; m <<= 1) ss += __shfl_xor(ss, m);
        float is = rsqrtf(ss * (1.f / 128.f) + 1e-5f);
        float o[8];
#pragma unroll
        for (int k = 0; k < 8; k++) {
            float z = gamma[t * 8 + k] * (d[k] * is) + beta[t * 8 + k];
            o[k] = z > 0.f ? z : __expf(z) - 1.f;
        }
        float4* op = (float4*)(xout + (size_t)n * 128 + t * 8);
        op[0] = make_float4(o[0], o[1], o[2], o[3]);
        op[1] = make_float4(o[4], o[5], o[6], o[7]);
    }
}

// -------- final layer: H=1, C=32 (bf16 h), no LN/ELU, writes d_out --------
__global__ __launch_bounds__(64) void k_agg_final(
    const unsigned short* __restrict__ hb, const float* __restrict__ a_src,
    const float* __restrict__ a_dst, const int* __restrict__ row_ptr,
    const int* __restrict__ esrc, const float* __restrict__ bf,
    float* __restrict__ out) {
    int n = blockIdx.x;
    int t = threadIdx.x;
    int start = row_ptr[n];
    int end = (n == NN - 1) ? ETOT : row_ptr[n + 1];
    int deg = end - start;
    float adn = a_dst[n];

    __shared__ int   s_src[MAXD];
    __shared__ float s_exp[MAXD];

    float dsum = 0.f;
    for (int k = start + t; k < end; k += 64) {
        int j = k - start;
        int s = esrc[k];
        float e = a_src[s] + adn;
        e = e > 0.f ? e : SLOPE * e;
        float x = __expf(e);
        if (j < MAXD) { s_src[j] = s; s_exp[j] = x; }
        dsum += x;
    }
#pragma unroll
    for (int m = 1; m < 64; m <<= 1) dsum += __shfl_xor(dsum, m);
    float inv = 1.f / (dsum + 1e-16f);
    __syncthreads();
    int ddc = deg < MAXD ? deg : MAXD;
    for (int idx = t; idx < ddc; idx += 64) s_exp[idx] *= inv;
    __syncthreads();

    int g = t >> 3, c8 = t & 7;
    float acc[4] = {0.f, 0.f, 0.f, 0.f};
    if (deg <= MAXD) {
        for (int j = g; j < deg; j += 8) {
            int s = s_src[j];
            float al = s_exp[j];
            uint2 u = *(const uint2*)(hb + (size_t)s * 32 + c8 * 4);
            acc[0] += bf_lo(u.x) * al; acc[1] += bf_hi(u.x) * al;
            acc[2] += bf_lo(u.y) * al; acc[3] += bf_hi(u.y) * al;
        }
    } else {
        for (int j = g; j < deg; j += 8) {
            int s = esrc[start + j];
            float e = a_src[s] + adn;
            e = e > 0.f ? e : SLOPE * e;
            float al = __expf(e) * inv;
            uint2 u = *(const uint2*)(hb + (size_t)s * 32 + c8 * 4);
            acc[0] += bf_lo(u.x) * al; acc[1] += bf_hi(u.x) * al;
            acc[2] += bf_lo(u.y) * al; acc[3] += bf_hi(u.y) * al;
        }
    }
#pragma unroll
    for (int k = 0; k < 4; k++) {
        acc[k] += __shfl_xor(acc[k], 8);
        acc[k] += __shfl_xor(acc[k], 16);
        acc[k] += __shfl_xor(acc[k], 32);
    }
    if (t < 8) {
        float4 b4 = ((const float4*)bf)[t];
        float4 o = make_float4(acc[0] + b4.x, acc[1] + b4.y, acc[2] + b4.z,
                               acc[3] + b4.w);
        ((float4*)out)[(size_t)n * 8 + t] = o;
    }
}

// ---------------- launch ----------------
extern "C" void kernel_launch(void* const* d_in, const int* in_sizes, int n_in,
                              void* d_out, int out_size, void* d_ws,
                              size_t ws_size, hipStream_t stream) {
    const float* x  = (const float*)d_in[0];
    const int* ei   = (const int*)d_in[1];
    const float* W[3]  = {(const float*)d_in[2], (const float*)d_in[8],  (const float*)d_in[14]};
    const float* AS[3] = {(const float*)d_in[3], (const float*)d_in[9],  (const float*)d_in[15]};
    const float* AD[3] = {(const float*)d_in[4], (const float*)d_in[10], (const float*)d_in[16]};
    const float* Bb[3] = {(const float*)d_in[5], (const float*)d_in[11], (const float*)d_in[17]};
    const float* G[3]  = {(const float*)d_in[6], (const float*)d_in[12], (const float*)d_in[18]};
    const float* BE[3] = {(const float*)d_in[7], (const float*)d_in[13], (const float*)d_in[19]};
    const float* Wf  = (const float*)d_in[20];
    const float* asf = (const float*)d_in[21];
    const float* adf = (const float*)d_in[22];
    const float* bfp = (const float*)d_in[23];
    float* out = (float*)d_out;

    float* xbuf = (float*)d_ws;                                       // NN*128 f32
    unsigned short* hb = (unsigned short*)(xbuf + (size_t)NN * 128);  // NN*128 bf16
    float* a_s  = (float*)(hb + (size_t)NN * 128);
    float* a_d  = a_s + (size_t)NN * 4;
    int* row_ptr = (int*)(a_d + (size_t)NN * 4);
    int* esrc    = row_ptr + NN;
    int* gbh     = esrc + ETOT;
    int* ebase   = gbh + NB;
    int* gcur    = ebase + NB + 1;
    int* pbuf    = (int*)xbuf;  // alias: dead before first gemm writes

    k_zero<<<1, 128, 0, stream>>>(gbh, NB);
    k_bhist<<<(EE + 2047) / 2048, 256, 0, stream>>>(ei, gbh);
    k_bscan<<<1, 128, 0, stream>>>(gbh, ebase, gcur);
    k_bscatter<<<(EE + CCH - 1) / CCH, 256, 0, stream>>>(ei, gcur, pbuf);
    k_bcsr<<<NB, 256, 0, stream>>>(pbuf, ebase, row_ptr, esrc);

    const float* xin = x;
    int K = 64;
    for (int l = 0; l < 3; l++) {
        k_gemm_att<128, 128, 16, 8, 8, 4><<<(NN + 127) / 128, 256, 0, stream>>>(
            xin, W[l], AS[l], AD[l], hb, a_s, a_d, NN, K);
        k_aggregate_ln<<<NN, 128, 0, stream>>>(hb, a_s, a_d, row_ptr, esrc,
                                               Bb[l], G[l], BE[l], xbuf);
        xin = xbuf;
        K = 128;
    }
    k_gemm_att<64, 32, 16, 4, 4, 1><<<(NN + 63) / 64, 128, 0, stream>>>(
        xbuf, Wf, asf, adf, hb, a_s, a_d, NN, 128);
    k_agg_final<<<NN, 64, 0, stream>>>(hb, a_s, a_d, row_ptr, esrc, bfp, out);
}

// Round 6
// 652.120 us; speedup vs baseline: 1.7711x; 1.2034x over previous
//
#include <hip/hip_runtime.h>
#include <hip/hip_bf16.h>

constexpr int NN   = 100000;
constexpr int EE   = 1600000;
constexpr int ETOT = EE + NN;
constexpr float SLOPE = 0.2f;
constexpr int BSH = 10;     // nodes per bucket = 1024
constexpr int NB  = (NN + (1 << BSH) - 1) >> BSH;  // 98 buckets
constexpr int CCH = 8192;   // edges per scatter block

__device__ __forceinline__ float bf_lo(unsigned u) { return __uint_as_float(u << 16); }
__device__ __forceinline__ float bf_hi(unsigned u) { return __uint_as_float(u & 0xffff0000u); }

// ---------------- bucketed CSR build ----------------
__global__ void k_zero(int* p, int n) {
    int i = blockIdx.x * blockDim.x + threadIdx.x;
    if (i < n) p[i] = 0;
}

__global__ __launch_bounds__(256) void k_bhist(const int* __restrict__ ei,
                                               int* __restrict__ gbh) {
    __shared__ int h[NB];
    int t = threadIdx.x;
    if (t < NB) h[t] = 0;
    __syncthreads();
    int i = blockIdx.x * 2048 + t;
#pragma unroll
    for (int k = 0; k < 8; k++, i += 256)
        if (i < EE) atomicAdd(&h[ei[EE + i] >> BSH], 1);
    __syncthreads();
    if (t < NB && h[t]) atomicAdd(&gbh[t], h[t]);
}

__global__ void k_bscan(const int* __restrict__ gbh, int* __restrict__ ebase,
                        int* __restrict__ gcur) {
    __shared__ int sd[128];
    int t = threadIdx.x;
    int v = (t < NB) ? gbh[t] : 0;
    sd[t] = v;
    __syncthreads();
    for (int off = 1; off < 128; off <<= 1) {
        int x = (t >= off) ? sd[t - off] : 0;
        __syncthreads();
        sd[t] += x;
        __syncthreads();
    }
    int ex = sd[t] - v;
    if (t < NB) { ebase[t] = ex; gcur[t] = ex; }
    if (t == NB) ebase[NB] = EE;
}

__global__ __launch_bounds__(256) void k_bscatter(const int* __restrict__ ei,
                                                  int* __restrict__ gcur,
                                                  int* __restrict__ pbuf) {
    __shared__ int h[NB], base[NB], cur[NB];
    int t = threadIdx.x;
    if (t < NB) { h[t] = 0; cur[t] = 0; }
    __syncthreads();
    int c0 = blockIdx.x * CCH;
    int cend = c0 + CCH < EE ? c0 + CCH : EE;
    for (int i = c0 + t; i < cend; i += 256)
        atomicAdd(&h[ei[EE + i] >> BSH], 1);
    __syncthreads();
    if (t < NB && h[t] > 0) base[t] = atomicAdd(&gcur[t], h[t]);
    __syncthreads();
    for (int i = c0 + t; i < cend; i += 256) {
        int s = ei[i], d = ei[EE + i];
        int b = d >> BSH;
        int c = atomicAdd(&cur[b], 1);
        pbuf[base[b] + c] = s | ((d & ((1 << BSH) - 1)) << 17);
    }
}

// one block per bucket: degree hist -> scan -> row_ptr + self loops -> scatter esrc
__global__ __launch_bounds__(256) void k_bcsr(const int* __restrict__ pbuf,
                                              const int* __restrict__ ebase,
                                              int* __restrict__ row_ptr,
                                              int* __restrict__ esrc) {
    constexpr int BNODES = 1 << BSH;
    __shared__ int hist[BNODES];
    __shared__ int cur[BNODES];
    __shared__ int sd[256];
    int b = blockIdx.x, t = threadIdx.x;
    int node0 = b << BSH;
    int e0 = ebase[b], e1 = ebase[b + 1];
    for (int i = t; i < BNODES; i += 256) { hist[i] = 0; cur[i] = 0; }
    __syncthreads();
    for (int i = e0 + t; i < e1; i += 256)
        atomicAdd(&hist[pbuf[i] >> 17], 1);
    __syncthreads();
    int s0 = hist[4 * t], s1 = hist[4 * t + 1], s2 = hist[4 * t + 2], s3 = hist[4 * t + 3];
    int ts = s0 + s1 + s2 + s3;
    sd[t] = ts;
    __syncthreads();
    for (int off = 1; off < 256; off <<= 1) {
        int x = (t >= off) ? sd[t - off] : 0;
        __syncthreads();
        sd[t] += x;
        __syncthreads();
    }
    int ex = sd[t] - ts;
    hist[4 * t] = ex;
    hist[4 * t + 1] = ex + s0;
    hist[4 * t + 2] = ex + s0 + s1;
    hist[4 * t + 3] = ex + s0 + s1 + s2;
    __syncthreads();
    int rbase = e0 + node0;
    for (int nl = t; nl < BNODES; nl += 256) {
        int n = node0 + nl;
        if (n < NN) {
            int rp = rbase + hist[nl] + nl;
            row_ptr[n] = rp;
            esrc[rp] = n;  // self loop in slot 0
        }
    }
    __syncthreads();
    for (int i = e0 + t; i < e1; i += 256) {
        int p = pbuf[i];
        int nl = p >> 17;
        int c = atomicAdd(&cur[nl], 1);
        esrc[rbase + hist[nl] + nl + 1 + c] = p & 0x1FFFF;
    }
}

// ------- fp32 GEMM (full width in one col-block) + fused attention dots + bf16 h store -------
template <int BM, int BN, int BK, int TM, int TN, int H>
__global__ __launch_bounds__((BM / TM) * (BN / TN)) void k_gemm_att(
    const float* __restrict__ A, const float* __restrict__ B,
    const float* __restrict__ as_, const float* __restrict__ ad_,
    unsigned short* __restrict__ hb, float* __restrict__ a_s,
    float* __restrict__ a_d, int M, int K) {
    constexpr int THREADS = (BM / TM) * (BN / TN);
    constexpr int TX = BN / TN;
    __shared__ __align__(16) float As[BK][BM + 4];
    __shared__ __align__(16) float Bs[BK][BN + 4];
    int tid = threadIdx.x;
    int tx = tid % TX, ty = tid / TX;
    int rowBase = blockIdx.x * BM;
    float acc[TM][TN];
#pragma unroll
    for (int i = 0; i < TM; i++)
#pragma unroll
        for (int j = 0; j < TN; j++) acc[i][j] = 0.f;

    constexpr int LA = (BM * BK) / (THREADS * 4);
    constexpr int LB = (BK * BN) / (THREADS * 4);
    for (int k0 = 0; k0 < K; k0 += BK) {
#pragma unroll
        for (int l = 0; l < LA; l++) {
            int idx = tid + l * THREADS;
            int m = idx / (BK / 4);
            int kk = (idx % (BK / 4)) * 4;
            float4 v = make_float4(0.f, 0.f, 0.f, 0.f);
            int gr = rowBase + m;
            if (gr < M) v = *(const float4*)(A + (size_t)gr * K + k0 + kk);
            As[kk + 0][m] = v.x; As[kk + 1][m] = v.y;
            As[kk + 2][m] = v.z; As[kk + 3][m] = v.w;
        }
#pragma unroll
        for (int l = 0; l < LB; l++) {
            int idx = tid + l * THREADS;
            int kk = idx / (BN / 4);
            int c = (idx % (BN / 4)) * 4;
            float4 v = *(const float4*)(B + (size_t)(k0 + kk) * BN + c);
            *(float4*)(&Bs[kk][c]) = v;
        }
        __syncthreads();
#pragma unroll
        for (int k = 0; k < BK; k++) {
            float a[TM], b[TN];
#pragma unroll
            for (int i = 0; i < TM; i++) a[i] = As[k][ty * TM + i];
#pragma unroll
            for (int j = 0; j < TN; j++) b[j] = Bs[k][tx * TN + j];
#pragma unroll
            for (int i = 0; i < TM; i++)
#pragma unroll
                for (int j = 0; j < TN; j++) acc[i][j] += a[i] * b[j];
        }
        __syncthreads();
    }

    int head = (tx * TN) >> 5;
    int cc0 = (tx * TN) & 31;
    float sw[TN], dw[TN];
#pragma unroll
    for (int j = 0; j < TN; j++) {
        sw[j] = as_[head * 32 + cc0 + j];
        dw[j] = ad_[head * 32 + cc0 + j];
    }
    constexpr int LPH = 32 / TN;
#pragma unroll
    for (int i = 0; i < TM; i++) {
        int gr = rowBase + ty * TM + i;
        float ps = 0.f, pd = 0.f;
#pragma unroll
        for (int j = 0; j < TN; j++) { ps += acc[i][j] * sw[j]; pd += acc[i][j] * dw[j]; }
#pragma unroll
        for (int m = 1; m < LPH; m <<= 1) {
            ps += __shfl_xor(ps, m);
            pd += __shfl_xor(pd, m);
        }
        if (gr < M) {
            if ((tx & (LPH - 1)) == 0) {
                a_s[(size_t)gr * H + head] = ps;
                a_d[(size_t)gr * H + head] = pd;
            }
            __hip_bfloat16 hv[TN];
#pragma unroll
            for (int j = 0; j < TN; j++) hv[j] = __float2bfloat16(acc[i][j]);
            if constexpr (TN == 8)
                *(uint4*)(hb + (size_t)gr * BN + tx * TN) = *(uint4*)hv;
            else
                *(uint2*)(hb + (size_t)gr * BN + tx * TN) = *(uint2*)hv;
        }
    }
}

// -------- wave-per-node: softmax + aggregate(bf16 h) + bias + LN + ELU (H=4, 128ch) --------
// lane j owns edge j (deg<=64 in practice). Aggregation loop has a WAVE-UNIFORM trip
// count with clamped shuffle index so every __shfl executes with all 64 lanes active
// (ds_bpermute from an exec-inactive lane is undefined — the R5 bug).
__global__ __launch_bounds__(256) void k_aggregate_ln(
    const unsigned short* __restrict__ hb, const float* __restrict__ a_src,
    const float* __restrict__ a_dst, const int* __restrict__ row_ptr,
    const int* __restrict__ esrc, const float* __restrict__ bias,
    const float* __restrict__ gamma, const float* __restrict__ beta,
    float* __restrict__ xout) {
    int lane = threadIdx.x & 63;
    int n = blockIdx.x * 4 + (threadIdx.x >> 6);
    if (n >= NN) return;
    int start = row_ptr[n];
    int end = (n == NN - 1) ? ETOT : row_ptr[n + 1];
    int deg = end - start;

    float4 ad = ((const float4*)a_dst)[n];
    int g = lane >> 4, c16 = lane & 15, head = c16 >> 2;
    float acc[8];
#pragma unroll
    for (int k = 0; k < 8; k++) acc[k] = 0.f;

    if (deg <= 64) {
        int msrc = 0;
        float me0 = 0.f, me1 = 0.f, me2 = 0.f, me3 = 0.f;
        if (lane < deg) {
            int s = esrc[start + lane];
            msrc = s;
            float4 a = ((const float4*)a_src)[s];
            float e0 = a.x + ad.x; e0 = e0 > 0.f ? e0 : SLOPE * e0; me0 = __expf(e0);
            float e1 = a.y + ad.y; e1 = e1 > 0.f ? e1 : SLOPE * e1; me1 = __expf(e1);
            float e2 = a.z + ad.z; e2 = e2 > 0.f ? e2 : SLOPE * e2; me2 = __expf(e2);
            float e3 = a.w + ad.w; e3 = e3 > 0.f ? e3 : SLOPE * e3; me3 = __expf(e3);
        }
        float d0 = me0, d1 = me1, d2 = me2, d3 = me3;
#pragma unroll
        for (int m = 1; m < 64; m <<= 1) {
            d0 += __shfl_xor(d0, m);
            d1 += __shfl_xor(d1, m);
            d2 += __shfl_xor(d2, m);
            d3 += __shfl_xor(d3, m);
        }
        me0 *= 1.f / (d0 + 1e-16f);
        me1 *= 1.f / (d1 + 1e-16f);
        me2 *= 1.f / (d2 + 1e-16f);
        me3 *= 1.f / (d3 + 1e-16f);
        int iters = (deg + 3) >> 2;  // uniform trip count across the wave
        for (int it = 0; it < iters; it++) {
            int j = g + (it << 2);
            int jj = j < deg ? j : 0;  // clamp: shuffle sources stay active lanes
            int s = __shfl(msrc, jj);
            float a0 = __shfl(me0, jj), a1 = __shfl(me1, jj);
            float a2 = __shfl(me2, jj), a3 = __shfl(me3, jj);
            if (j < deg) {
                float al = head == 0 ? a0 : head == 1 ? a1 : head == 2 ? a2 : a3;
                uint4 u = *(const uint4*)(hb + (size_t)s * 128 + c16 * 8);
                acc[0] += bf_lo(u.x) * al; acc[1] += bf_hi(u.x) * al;
                acc[2] += bf_lo(u.y) * al; acc[3] += bf_hi(u.y) * al;
                acc[4] += bf_lo(u.z) * al; acc[5] += bf_hi(u.z) * al;
                acc[6] += bf_lo(u.w) * al; acc[7] += bf_hi(u.w) * al;
            }
        }
    } else {  // cold fallback: two-pass recompute, ~never taken
        float d0 = 0.f, d1 = 0.f, d2 = 0.f, d3 = 0.f;
        for (int k = start + lane; k < end; k += 64) {
            int s = esrc[k];
            float4 a = ((const float4*)a_src)[s];
            float e0 = a.x + ad.x; e0 = e0 > 0.f ? e0 : SLOPE * e0; d0 += __expf(e0);
            float e1 = a.y + ad.y; e1 = e1 > 0.f ? e1 : SLOPE * e1; d1 += __expf(e1);
            float e2 = a.z + ad.z; e2 = e2 > 0.f ? e2 : SLOPE * e2; d2 += __expf(e2);
            float e3 = a.w + ad.w; e3 = e3 > 0.f ? e3 : SLOPE * e3; d3 += __expf(e3);
        }
#pragma unroll
        for (int m = 1; m < 64; m <<= 1) {
            d0 += __shfl_xor(d0, m);
            d1 += __shfl_xor(d1, m);
            d2 += __shfl_xor(d2, m);
            d3 += __shfl_xor(d3, m);
        }
        float invh = head == 0 ? 1.f / (d0 + 1e-16f) : head == 1 ? 1.f / (d1 + 1e-16f)
                   : head == 2 ? 1.f / (d2 + 1e-16f) : 1.f / (d3 + 1e-16f);
        float adh = head == 0 ? ad.x : head == 1 ? ad.y : head == 2 ? ad.z : ad.w;
        for (int j = g; j < deg; j += 4) {
            int s = esrc[start + j];
            float e = a_src[(size_t)s * 4 + head] + adh;
            e = e > 0.f ? e : SLOPE * e;
            float al = __expf(e) * invh;
            uint4 u = *(const uint4*)(hb + (size_t)s * 128 + c16 * 8);
            acc[0] += bf_lo(u.x) * al; acc[1] += bf_hi(u.x) * al;
            acc[2] += bf_lo(u.y) * al; acc[3] += bf_hi(u.y) * al;
            acc[4] += bf_lo(u.z) * al; acc[5] += bf_hi(u.z) * al;
            acc[6] += bf_lo(u.w) * al; acc[7] += bf_hi(u.w) * al;
        }
    }

    // reduce the 4 edge-groups (lanes c16, c16+16, c16+32, c16+48) — full exec here
#pragma unroll
    for (int k = 0; k < 8; k++) {
        acc[k] += __shfl_xor(acc[k], 16);
        acc[k] += __shfl_xor(acc[k], 32);
    }
    if (lane < 16) {
        float y[8];
        float sum = 0.f;
        const float4* bp = (const float4*)(bias + lane * 8);
        float4 b0 = bp[0], b1 = bp[1];
#pragma unroll
        for (int k = 0; k < 8; k++) {
            float b = k < 4 ? (&b0.x)[k] : (&b1.x)[k - 4];
            y[k] = acc[k] + b;
            sum += y[k];
        }
#pragma unroll
        for (int m = 1; m < 16; m <<= 1) sum += __shfl_xor(sum, m);
        float mu = sum * (1.f / 128.f);
        float ss = 0.f;
        float d[8];
#pragma unroll
        for (int k = 0; k < 8; k++) { d[k] = y[k] - mu; ss += d[k] * d[k]; }
#pragma unroll
        for (int m = 1; m < 16; m <<= 1) ss += __shfl_xor(ss, m);
        float is = rsqrtf(ss * (1.f / 128.f) + 1e-5f);
        const float4* gp = (const float4*)(gamma + lane * 8);
        const float4* ep = (const float4*)(beta + lane * 8);
        float4 g0 = gp[0], g1 = gp[1], e0 = ep[0], e1 = ep[1];
        float o[8];
#pragma unroll
        for (int k = 0; k < 8; k++) {
            float gm = k < 4 ? (&g0.x)[k] : (&g1.x)[k - 4];
            float bt = k < 4 ? (&e0.x)[k] : (&e1.x)[k - 4];
            float z = gm * (d[k] * is) + bt;
            o[k] = z > 0.f ? z : __expf(z) - 1.f;
        }
        float4* op = (float4*)(xout + (size_t)n * 128 + lane * 8);
        op[0] = make_float4(o[0], o[1], o[2], o[3]);
        op[1] = make_float4(o[4], o[5], o[6], o[7]);
    }
}

// -------- final layer, wave-per-node: H=1, C=32 (bf16 h), no LN/ELU, writes d_out --------
__global__ __launch_bounds__(256) void k_agg_final(
    const unsigned short* __restrict__ hb, const float* __restrict__ a_src,
    const float* __restrict__ a_dst, const int* __restrict__ row_ptr,
    const int* __restrict__ esrc, const float* __restrict__ bf,
    float* __restrict__ out) {
    int lane = threadIdx.x & 63;
    int n = blockIdx.x * 4 + (threadIdx.x >> 6);
    if (n >= NN) return;
    int start = row_ptr[n];
    int end = (n == NN - 1) ? ETOT : row_ptr[n + 1];
    int deg = end - start;
    float adn = a_dst[n];

    int g = lane >> 3, c8 = lane & 7;
    float acc[4] = {0.f, 0.f, 0.f, 0.f};

    if (deg <= 64) {
        int msrc = 0;
        float me = 0.f;
        if (lane < deg) {
            int s = esrc[start + lane];
            msrc = s;
            float e = a_src[s] + adn;
            e = e > 0.f ? e : SLOPE * e;
            me = __expf(e);
        }
        float d = me;
#pragma unroll
        for (int m = 1; m < 64; m <<= 1) d += __shfl_xor(d, m);
        me *= 1.f / (d + 1e-16f);
        int iters = (deg + 7) >> 3;  // uniform trip count
        for (int it = 0; it < iters; it++) {
            int j = g + (it << 3);
            int jj = j < deg ? j : 0;
            int s = __shfl(msrc, jj);
            float al = __shfl(me, jj);
            if (j < deg) {
                uint2 u = *(const uint2*)(hb + (size_t)s * 32 + c8 * 4);
                acc[0] += bf_lo(u.x) * al; acc[1] += bf_hi(u.x) * al;
                acc[2] += bf_lo(u.y) * al; acc[3] += bf_hi(u.y) * al;
            }
        }
    } else {
        float d = 0.f;
        for (int k = start + lane; k < end; k += 64) {
            int s = esrc[k];
            float e = a_src[s] + adn;
            e = e > 0.f ? e : SLOPE * e;
            d += __expf(e);
        }
#pragma unroll
        for (int m = 1; m < 64; m <<= 1) d += __shfl_xor(d, m);
        float inv = 1.f / (d + 1e-16f);
        for (int j = g; j < deg; j += 8) {
            int s = esrc[start + j];
            float e = a_src[s] + adn;
            e = e > 0.f ? e : SLOPE * e;
            float al = __expf(e) * inv;
            uint2 u = *(const uint2*)(hb + (size_t)s * 32 + c8 * 4);
            acc[0] += bf_lo(u.x) * al; acc[1] += bf_hi(u.x) * al;
            acc[2] += bf_lo(u.y) * al; acc[3] += bf_hi(u.y) * al;
        }
    }
#pragma unroll
    for (int k = 0; k < 4; k++) {
        acc[k] += __shfl_xor(acc[k], 8);
        acc[k] += __shfl_xor(acc[k], 16);
        acc[k] += __shfl_xor(acc[k], 32);
    }
    if (lane < 8) {
        float4 b4 = ((const float4*)bf)[lane];
        float4 o = make_float4(acc[0] + b4.x, acc[1] + b4.y, acc[2] + b4.z,
                               acc[3] + b4.w);
        ((float4*)out)[(size_t)n * 8 + lane] = o;
    }
}

// ---------------- launch ----------------
extern "C" void kernel_launch(void* const* d_in, const int* in_sizes, int n_in,
                              void* d_out, int out_size, void* d_ws,
                              size_t ws_size, hipStream_t stream) {
    const float* x  = (const float*)d_in[0];
    const int* ei   = (const int*)d_in[1];
    const float* W[3]  = {(const float*)d_in[2], (const float*)d_in[8],  (const float*)d_in[14]};
    const float* AS[3] = {(const float*)d_in[3], (const float*)d_in[9],  (const float*)d_in[15]};
    const float* AD[3] = {(const float*)d_in[4], (const float*)d_in[10], (const float*)d_in[16]};
    const float* Bb[3] = {(const float*)d_in[5], (const float*)d_in[11], (const float*)d_in[17]};
    const float* G[3]  = {(const float*)d_in[6], (const float*)d_in[12], (const float*)d_in[18]};
    const float* BE[3] = {(const float*)d_in[7], (const float*)d_in[13], (const float*)d_in[19]};
    const float* Wf  = (const float*)d_in[20];
    const float* asf = (const float*)d_in[21];
    const float* adf = (const float*)d_in[22];
    const float* bfp = (const float*)d_in[23];
    float* out = (float*)d_out;

    float* xbuf = (float*)d_ws;                                       // NN*128 f32
    unsigned short* hb = (unsigned short*)(xbuf + (size_t)NN * 128);  // NN*128 bf16
    float* a_s  = (float*)(hb + (size_t)NN * 128);
    float* a_d  = a_s + (size_t)NN * 4;
    int* row_ptr = (int*)(a_d + (size_t)NN * 4);
    int* esrc    = row_ptr + NN;
    int* gbh     = esrc + ETOT;
    int* ebase   = gbh + NB;
    int* gcur    = ebase + NB + 1;
    int* pbuf    = (int*)xbuf;  // alias: dead before first gemm writes

    k_zero<<<1, 128, 0, stream>>>(gbh, NB);
    k_bhist<<<(EE + 2047) / 2048, 256, 0, stream>>>(ei, gbh);
    k_bscan<<<1, 128, 0, stream>>>(gbh, ebase, gcur);
    k_bscatter<<<(EE + CCH - 1) / CCH, 256, 0, stream>>>(ei, gcur, pbuf);
    k_bcsr<<<NB, 256, 0, stream>>>(pbuf, ebase, row_ptr, esrc);

    const float* xin = x;
    int K = 64;
    for (int l = 0; l < 3; l++) {
        k_gemm_att<128, 128, 16, 8, 8, 4><<<(NN + 127) / 128, 256, 0, stream>>>(
            xin, W[l], AS[l], AD[l], hb, a_s, a_d, NN, K);
        k_aggregate_ln<<<(NN + 3) / 4, 256, 0, stream>>>(hb, a_s, a_d, row_ptr,
                                                         esrc, Bb[l], G[l], BE[l], xbuf);
        xin = xbuf;
        K = 128;
    }
    k_gemm_att<64, 32, 16, 4, 4, 1><<<(NN + 63) / 64, 128, 0, stream>>>(
        xbuf, Wf, asf, adf, hb, a_s, a_d, NN, 128);
    k_agg_final<<<(NN + 3) / 4, 256, 0, stream>>>(hb, a_s, a_d, row_ptr, esrc,
                                                  bfp, out);
}

// Round 7
// 600.837 us; speedup vs baseline: 1.9222x; 1.0854x over previous
//
#include <hip/hip_runtime.h>
#include <hip/hip_bf16.h>

constexpr int NN   = 100000;
constexpr int EE   = 1600000;
constexpr int ETOT = EE + NN;
constexpr float SLOPE = 0.2f;
constexpr int BSH = 10;     // nodes per bucket = 1024
constexpr int NB  = (NN + (1 << BSH) - 1) >> BSH;  // 98 buckets
constexpr int CCH = 8192;   // edges per scatter block

typedef __attribute__((ext_vector_type(8))) short short8;
typedef __attribute__((ext_vector_type(4))) float f32x4;

__device__ __forceinline__ float bf_lo(unsigned u) { return __uint_as_float(u << 16); }
__device__ __forceinline__ float bf_hi(unsigned u) { return __uint_as_float(u & 0xffff0000u); }
__device__ __forceinline__ unsigned short f2bf(float f) {
    __hip_bfloat16 h = __float2bfloat16(f);
    return *(unsigned short*)&h;
}

// ---------------- dtype conversions ----------------
__global__ void k_cvt_x(const float* __restrict__ x, unsigned short* __restrict__ xb) {
    int i = blockIdx.x * blockDim.x + threadIdx.x;   // 8 floats per thread
    if (i >= NN * 64 / 8) return;
    const float4* xp = (const float4*)(x + (size_t)i * 8);
    float4 v0 = xp[0], v1 = xp[1];
    unsigned short o[8] = {f2bf(v0.x), f2bf(v0.y), f2bf(v0.z), f2bf(v0.w),
                           f2bf(v1.x), f2bf(v1.y), f2bf(v1.z), f2bf(v1.w)};
    *(uint4*)(xb + (size_t)i * 8) = *(uint4*)o;
}

// W [K][N] fp32 -> Wt [N][K] bf16
__global__ void k_cvt_wt(const float* __restrict__ W, unsigned short* __restrict__ Wt,
                         int K, int N) {
    int i = blockIdx.x * blockDim.x + threadIdx.x;
    if (i >= K * N) return;
    int k = i / N, n = i % N;
    Wt[(size_t)n * K + k] = f2bf(W[i]);
}

// ---------------- bucketed CSR build ----------------
__global__ void k_zero(int* p, int n) {
    int i = blockIdx.x * blockDim.x + threadIdx.x;
    if (i < n) p[i] = 0;
}

__global__ __launch_bounds__(256) void k_bhist(const int* __restrict__ ei,
                                               int* __restrict__ gbh) {
    __shared__ int h[NB];
    int t = threadIdx.x;
    if (t < NB) h[t] = 0;
    __syncthreads();
    int i = blockIdx.x * 2048 + t;
#pragma unroll
    for (int k = 0; k < 8; k++, i += 256)
        if (i < EE) atomicAdd(&h[ei[EE + i] >> BSH], 1);
    __syncthreads();
    if (t < NB && h[t]) atomicAdd(&gbh[t], h[t]);
}

__global__ void k_bscan(const int* __restrict__ gbh, int* __restrict__ ebase,
                        int* __restrict__ gcur) {
    __shared__ int sd[128];
    int t = threadIdx.x;
    int v = (t < NB) ? gbh[t] : 0;
    sd[t] = v;
    __syncthreads();
    for (int off = 1; off < 128; off <<= 1) {
        int x = (t >= off) ? sd[t - off] : 0;
        __syncthreads();
        sd[t] += x;
        __syncthreads();
    }
    int ex = sd[t] - v;
    if (t < NB) { ebase[t] = ex; gcur[t] = ex; }
    if (t == NB) ebase[NB] = EE;
}

__global__ __launch_bounds__(256) void k_bscatter(const int* __restrict__ ei,
                                                  int* __restrict__ gcur,
                                                  int* __restrict__ pbuf) {
    __shared__ int h[NB], base[NB], cur[NB];
    int t = threadIdx.x;
    if (t < NB) { h[t] = 0; cur[t] = 0; }
    __syncthreads();
    int c0 = blockIdx.x * CCH;
    int cend = c0 + CCH < EE ? c0 + CCH : EE;
    for (int i = c0 + t; i < cend; i += 256)
        atomicAdd(&h[ei[EE + i] >> BSH], 1);
    __syncthreads();
    if (t < NB && h[t] > 0) base[t] = atomicAdd(&gcur[t], h[t]);
    __syncthreads();
    for (int i = c0 + t; i < cend; i += 256) {
        int s = ei[i], d = ei[EE + i];
        int b = d >> BSH;
        int c = atomicAdd(&cur[b], 1);
        pbuf[base[b] + c] = s | ((d & ((1 << BSH) - 1)) << 17);
    }
}

__global__ __launch_bounds__(256) void k_bcsr(const int* __restrict__ pbuf,
                                              const int* __restrict__ ebase,
                                              int* __restrict__ row_ptr,
                                              int* __restrict__ esrc) {
    constexpr int BNODES = 1 << BSH;
    __shared__ int hist[BNODES];
    __shared__ int cur[BNODES];
    __shared__ int sd[256];
    int b = blockIdx.x, t = threadIdx.x;
    int node0 = b << BSH;
    int e0 = ebase[b], e1 = ebase[b + 1];
    for (int i = t; i < BNODES; i += 256) { hist[i] = 0; cur[i] = 0; }
    __syncthreads();
    for (int i = e0 + t; i < e1; i += 256)
        atomicAdd(&hist[pbuf[i] >> 17], 1);
    __syncthreads();
    int s0 = hist[4 * t], s1 = hist[4 * t + 1], s2 = hist[4 * t + 2], s3 = hist[4 * t + 3];
    int ts = s0 + s1 + s2 + s3;
    sd[t] = ts;
    __syncthreads();
    for (int off = 1; off < 256; off <<= 1) {
        int x = (t >= off) ? sd[t - off] : 0;
        __syncthreads();
        sd[t] += x;
        __syncthreads();
    }
    int ex = sd[t] - ts;
    hist[4 * t] = ex;
    hist[4 * t + 1] = ex + s0;
    hist[4 * t + 2] = ex + s0 + s1;
    hist[4 * t + 3] = ex + s0 + s1 + s2;
    __syncthreads();
    int rbase = e0 + node0;
    for (int nl = t; nl < BNODES; nl += 256) {
        int n = node0 + nl;
        if (n < NN) {
            int rp = rbase + hist[nl] + nl;
            row_ptr[n] = rp;
            esrc[rp] = n;  // self loop in slot 0
        }
    }
    __syncthreads();
    for (int i = e0 + t; i < e1; i += 256) {
        int p = pbuf[i];
        int nl = p >> 17;
        int c = atomicAdd(&cur[nl], 1);
        esrc[rbase + hist[nl] + nl + 1 + c] = p & 0x1FFFF;
    }
}

// ------- bf16 MFMA GEMM (BMx BN tile, BN = full width) + fused att dots + bf16 h -------
// A [M][K] bf16 row-major, Bt [BN][K] bf16 (W transposed). 256 threads = 4 waves,
// wave w owns rows w*32..w*32+31 (2 row-tiles). K staged in 64-wide LDS slabs.
// MFMA 16x16x32 bf16: A-frag A[m=lane&15][k=quad*8+j]; B-frag Bt[n=lane&15][k=quad*8+j];
// C/D: col=lane&15, row=quad*4+reg  [per cdna_hip_programming.md §3, m89/m74 verified].
template <int BN, int H>
__global__ __launch_bounds__(256) void k_mfma_att(
    const unsigned short* __restrict__ Ab, const unsigned short* __restrict__ Bt,
    const float* __restrict__ as_, const float* __restrict__ ad_,
    unsigned short* __restrict__ hb, float* __restrict__ a_s,
    float* __restrict__ a_d, int M, int K) {
    constexpr int NCT = BN / 16;
    constexpr int LDK = 72;  // 64-slab + 8-short pad: rows 144 B apart (16B-aligned, 2-way bank alias)
    __shared__ unsigned short As[128 * LDK];
    __shared__ unsigned short Bs[BN * LDK];
    int tid = threadIdx.x;
    int lane = tid & 63, w = tid >> 6;
    int q = lane >> 4, col = lane & 15;
    int rowBase = blockIdx.x * 128;

    f32x4 acc[2][NCT];
#pragma unroll
    for (int rt = 0; rt < 2; rt++)
#pragma unroll
        for (int ct = 0; ct < NCT; ct++) acc[rt][ct] = (f32x4){0.f, 0.f, 0.f, 0.f};

    int u = tid & 7;      // 8 x uint4 (16B) per 64-short row-slab
    int r0 = tid >> 3;
    int nph = K >> 6;
    for (int ph = 0; ph < nph; ph++) {
        int kof = ph * 64 + u * 8;
#pragma unroll
        for (int rr = r0; rr < 128; rr += 32) {
            int gr = rowBase + rr;
            uint4 v = make_uint4(0, 0, 0, 0);
            if (gr < M) v = *(const uint4*)(Ab + (size_t)gr * K + kof);
            *(uint4*)(&As[rr * LDK + u * 8]) = v;
        }
#pragma unroll
        for (int br = r0; br < BN; br += 32) {
            uint4 v = *(const uint4*)(Bt + (size_t)br * K + kof);
            *(uint4*)(&Bs[br * LDK + u * 8]) = v;
        }
        __syncthreads();

        short8 af[2][2];
#pragma unroll
        for (int rt = 0; rt < 2; rt++)
#pragma unroll
            for (int kt = 0; kt < 2; kt++)
                af[rt][kt] = *(const short8*)(&As[(w * 32 + rt * 16 + col) * LDK + kt * 32 + q * 8]);
#pragma unroll
        for (int kt = 0; kt < 2; kt++)
#pragma unroll
            for (int ct = 0; ct < NCT; ct++) {
                short8 bf = *(const short8*)(&Bs[(ct * 16 + col) * LDK + kt * 32 + q * 8]);
#pragma unroll
                for (int rt = 0; rt < 2; rt++)
                    acc[rt][ct] = __builtin_amdgcn_mfma_f32_16x16x32_bf16(
                        af[rt][kt], bf, acc[rt][ct], 0, 0, 0);
            }
        __syncthreads();
    }

    // epilogue: att dots via in-quad butterflies + bf16 h store
    float swv[NCT], dwv[NCT];
#pragma unroll
    for (int ct = 0; ct < NCT; ct++) {
        int c = ct * 16 + col;
        swv[ct] = as_[c];
        dwv[ct] = ad_[c];
    }
#pragma unroll
    for (int rt = 0; rt < 2; rt++) {
#pragma unroll
        for (int r = 0; r < 4; r++) {
            int gr = rowBase + w * 32 + rt * 16 + q * 4 + r;
            if constexpr (H == 4) {
                float ps[4] = {0, 0, 0, 0}, pd[4] = {0, 0, 0, 0};
#pragma unroll
                for (int ct = 0; ct < NCT; ct++) {
                    float v = acc[rt][ct][r];
                    ps[ct >> 1] += v * swv[ct];
                    pd[ct >> 1] += v * dwv[ct];
                }
#pragma unroll
                for (int m = 1; m < 16; m <<= 1)
#pragma unroll
                    for (int h = 0; h < 4; h++) {
                        ps[h] += __shfl_xor(ps[h], m);
                        pd[h] += __shfl_xor(pd[h], m);
                    }
                if (gr < M) {
#pragma unroll
                    for (int ct = 0; ct < NCT; ct++)
                        hb[(size_t)gr * BN + ct * 16 + col] = f2bf(acc[rt][ct][r]);
                    if (col == 0) {
                        *(float4*)(a_s + (size_t)gr * 4) = make_float4(ps[0], ps[1], ps[2], ps[3]);
                        *(float4*)(a_d + (size_t)gr * 4) = make_float4(pd[0], pd[1], pd[2], pd[3]);
                    }
                }
            } else {
                float ps = 0.f, pd = 0.f;
#pragma unroll
                for (int ct = 0; ct < NCT; ct++) {
                    float v = acc[rt][ct][r];
                    ps += v * swv[ct];
                    pd += v * dwv[ct];
                }
#pragma unroll
                for (int m = 1; m < 16; m <<= 1) {
                    ps += __shfl_xor(ps, m);
                    pd += __shfl_xor(pd, m);
                }
                if (gr < M) {
#pragma unroll
                    for (int ct = 0; ct < NCT; ct++)
                        hb[(size_t)gr * BN + ct * 16 + col] = f2bf(acc[rt][ct][r]);
                    if (col == 0) { a_s[gr] = ps; a_d[gr] = pd; }
                }
            }
        }
    }
}

// -------- wave-per-node: softmax + aggregate(bf16 h) + bias + LN + ELU -> bf16 x --------
__global__ __launch_bounds__(256) void k_aggregate_ln(
    const unsigned short* __restrict__ hb, const float* __restrict__ a_src,
    const float* __restrict__ a_dst, const int* __restrict__ row_ptr,
    const int* __restrict__ esrc, const float* __restrict__ bias,
    const float* __restrict__ gamma, const float* __restrict__ beta,
    unsigned short* __restrict__ xb) {
    int lane = threadIdx.x & 63;
    int n = blockIdx.x * 4 + (threadIdx.x >> 6);
    if (n >= NN) return;
    int start = row_ptr[n];
    int end = (n == NN - 1) ? ETOT : row_ptr[n + 1];
    int deg = end - start;

    float4 ad = ((const float4*)a_dst)[n];
    int g = lane >> 4, c16 = lane & 15, head = c16 >> 2;
    float acc[8];
#pragma unroll
    for (int k = 0; k < 8; k++) acc[k] = 0.f;

    if (deg <= 64) {
        int msrc = 0;
        float me0 = 0.f, me1 = 0.f, me2 = 0.f, me3 = 0.f;
        if (lane < deg) {
            int s = esrc[start + lane];
            msrc = s;
            float4 a = ((const float4*)a_src)[s];
            float e0 = a.x + ad.x; e0 = e0 > 0.f ? e0 : SLOPE * e0; me0 = __expf(e0);
            float e1 = a.y + ad.y; e1 = e1 > 0.f ? e1 : SLOPE * e1; me1 = __expf(e1);
            float e2 = a.z + ad.z; e2 = e2 > 0.f ? e2 : SLOPE * e2; me2 = __expf(e2);
            float e3 = a.w + ad.w; e3 = e3 > 0.f ? e3 : SLOPE * e3; me3 = __expf(e3);
        }
        float d0 = me0, d1 = me1, d2 = me2, d3 = me3;
#pragma unroll
        for (int m = 1; m < 64; m <<= 1) {
            d0 += __shfl_xor(d0, m);
            d1 += __shfl_xor(d1, m);
            d2 += __shfl_xor(d2, m);
            d3 += __shfl_xor(d3, m);
        }
        me0 *= 1.f / (d0 + 1e-16f);
        me1 *= 1.f / (d1 + 1e-16f);
        me2 *= 1.f / (d2 + 1e-16f);
        me3 *= 1.f / (d3 + 1e-16f);
        int iters = (deg + 3) >> 2;  // uniform trip count; clamped shuffle idx (exec-safe)
        for (int it = 0; it < iters; it++) {
            int j = g + (it << 2);
            int jj = j < deg ? j : 0;
            int s = __shfl(msrc, jj);
            float a0 = __shfl(me0, jj), a1 = __shfl(me1, jj);
            float a2 = __shfl(me2, jj), a3 = __shfl(me3, jj);
            if (j < deg) {
                float al = head == 0 ? a0 : head == 1 ? a1 : head == 2 ? a2 : a3;
                uint4 uu = *(const uint4*)(hb + (size_t)s * 128 + c16 * 8);
                acc[0] += bf_lo(uu.x) * al; acc[1] += bf_hi(uu.x) * al;
                acc[2] += bf_lo(uu.y) * al; acc[3] += bf_hi(uu.y) * al;
                acc[4] += bf_lo(uu.z) * al; acc[5] += bf_hi(uu.z) * al;
                acc[6] += bf_lo(uu.w) * al; acc[7] += bf_hi(uu.w) * al;
            }
        }
    } else {  // cold fallback
        float d0 = 0.f, d1 = 0.f, d2 = 0.f, d3 = 0.f;
        for (int k = start + lane; k < end; k += 64) {
            int s = esrc[k];
            float4 a = ((const float4*)a_src)[s];
            float e0 = a.x + ad.x; e0 = e0 > 0.f ? e0 : SLOPE * e0; d0 += __expf(e0);
            float e1 = a.y + ad.y; e1 = e1 > 0.f ? e1 : SLOPE * e1; d1 += __expf(e1);
            float e2 = a.z + ad.z; e2 = e2 > 0.f ? e2 : SLOPE * e2; d2 += __expf(e2);
            float e3 = a.w + ad.w; e3 = e3 > 0.f ? e3 : SLOPE * e3; d3 += __expf(e3);
        }
#pragma unroll
        for (int m = 1; m < 64; m <<= 1) {
            d0 += __shfl_xor(d0, m);
            d1 += __shfl_xor(d1, m);
            d2 += __shfl_xor(d2, m);
            d3 += __shfl_xor(d3, m);
        }
        float invh = head == 0 ? 1.f / (d0 + 1e-16f) : head == 1 ? 1.f / (d1 + 1e-16f)
                   : head == 2 ? 1.f / (d2 + 1e-16f) : 1.f / (d3 + 1e-16f);
        float adh = head == 0 ? ad.x : head == 1 ? ad.y : head == 2 ? ad.z : ad.w;
        for (int j = g; j < deg; j += 4) {
            int s = esrc[start + j];
            float e = a_src[(size_t)s * 4 + head] + adh;
            e = e > 0.f ? e : SLOPE * e;
            float al = __expf(e) * invh;
            uint4 uu = *(const uint4*)(hb + (size_t)s * 128 + c16 * 8);
            acc[0] += bf_lo(uu.x) * al; acc[1] += bf_hi(uu.x) * al;
            acc[2] += bf_lo(uu.y) * al; acc[3] += bf_hi(uu.y) * al;
            acc[4] += bf_lo(uu.z) * al; acc[5] += bf_hi(uu.z) * al;
            acc[6] += bf_lo(uu.w) * al; acc[7] += bf_hi(uu.w) * al;
        }
    }

#pragma unroll
    for (int k = 0; k < 8; k++) {
        acc[k] += __shfl_xor(acc[k], 16);
        acc[k] += __shfl_xor(acc[k], 32);
    }
    if (lane < 16) {
        float y[8];
        float sum = 0.f;
        const float4* bp = (const float4*)(bias + lane * 8);
        float4 b0 = bp[0], b1 = bp[1];
#pragma unroll
        for (int k = 0; k < 8; k++) {
            float b = k < 4 ? (&b0.x)[k] : (&b1.x)[k - 4];
            y[k] = acc[k] + b;
            sum += y[k];
        }
#pragma unroll
        for (int m = 1; m < 16; m <<= 1) sum += __shfl_xor(sum, m);
        float mu = sum * (1.f / 128.f);
        float ss = 0.f;
        float d[8];
#pragma unroll
        for (int k = 0; k < 8; k++) { d[k] = y[k] - mu; ss += d[k] * d[k]; }
#pragma unroll
        for (int m = 1; m < 16; m <<= 1) ss += __shfl_xor(ss, m);
        float is = rsqrtf(ss * (1.f / 128.f) + 1e-5f);
        const float4* gp = (const float4*)(gamma + lane * 8);
        const float4* ep = (const float4*)(beta + lane * 8);
        float4 g0 = gp[0], g1 = gp[1], e0 = ep[0], e1 = ep[1];
        unsigned short o16[8];
#pragma unroll
        for (int k = 0; k < 8; k++) {
            float gm = k < 4 ? (&g0.x)[k] : (&g1.x)[k - 4];
            float bt = k < 4 ? (&e0.x)[k] : (&e1.x)[k - 4];
            float z = gm * (d[k] * is) + bt;
            o16[k] = f2bf(z > 0.f ? z : __expf(z) - 1.f);
        }
        *(uint4*)(xb + (size_t)n * 128 + lane * 8) = *(uint4*)o16;
    }
}

// -------- final layer, wave-per-node: H=1, C=32 (bf16 h), writes fp32 d_out --------
__global__ __launch_bounds__(256) void k_agg_final(
    const unsigned short* __restrict__ hb, const float* __restrict__ a_src,
    const float* __restrict__ a_dst, const int* __restrict__ row_ptr,
    const int* __restrict__ esrc, const float* __restrict__ bf,
    float* __restrict__ out) {
    int lane = threadIdx.x & 63;
    int n = blockIdx.x * 4 + (threadIdx.x >> 6);
    if (n >= NN) return;
    int start = row_ptr[n];
    int end = (n == NN - 1) ? ETOT : row_ptr[n + 1];
    int deg = end - start;
    float adn = a_dst[n];

    int g = lane >> 3, c8 = lane & 7;
    float acc[4] = {0.f, 0.f, 0.f, 0.f};

    if (deg <= 64) {
        int msrc = 0;
        float me = 0.f;
        if (lane < deg) {
            int s = esrc[start + lane];
            msrc = s;
            float e = a_src[s] + adn;
            e = e > 0.f ? e : SLOPE * e;
            me = __expf(e);
        }
        float d = me;
#pragma unroll
        for (int m = 1; m < 64; m <<= 1) d += __shfl_xor(d, m);
        me *= 1.f / (d + 1e-16f);
        int iters = (deg + 7) >> 3;
        for (int it = 0; it < iters; it++) {
            int j = g + (it << 3);
            int jj = j < deg ? j : 0;
            int s = __shfl(msrc, jj);
            float al = __shfl(me, jj);
            if (j < deg) {
                uint2 u = *(const uint2*)(hb + (size_t)s * 32 + c8 * 4);
                acc[0] += bf_lo(u.x) * al; acc[1] += bf_hi(u.x) * al;
                acc[2] += bf_lo(u.y) * al; acc[3] += bf_hi(u.y) * al;
            }
        }
    } else {
        float d = 0.f;
        for (int k = start + lane; k < end; k += 64) {
            int s = esrc[k];
            float e = a_src[s] + adn;
            e = e > 0.f ? e : SLOPE * e;
            d += __expf(e);
        }
#pragma unroll
        for (int m = 1; m < 64; m <<= 1) d += __shfl_xor(d, m);
        float inv = 1.f / (d + 1e-16f);
        for (int j = g; j < deg; j += 8) {
            int s = esrc[start + j];
            float e = a_src[s] + adn;
            e = e > 0.f ? e : SLOPE * e;
            float al = __expf(e) * inv;
            uint2 u = *(const uint2*)(hb + (size_t)s * 32 + c8 * 4);
            acc[0] += bf_lo(u.x) * al; acc[1] += bf_hi(u.x) * al;
            acc[2] += bf_lo(u.y) * al; acc[3] += bf_hi(u.y) * al;
        }
    }
#pragma unroll
    for (int k = 0; k < 4; k++) {
        acc[k] += __shfl_xor(acc[k], 8);
        acc[k] += __shfl_xor(acc[k], 16);
        acc[k] += __shfl_xor(acc[k], 32);
    }
    if (lane < 8) {
        float4 b4 = ((const float4*)bf)[lane];
        float4 o = make_float4(acc[0] + b4.x, acc[1] + b4.y, acc[2] + b4.z,
                               acc[3] + b4.w);
        ((float4*)out)[(size_t)n * 8 + lane] = o;
    }
}

// ---------------- launch ----------------
extern "C" void kernel_launch(void* const* d_in, const int* in_sizes, int n_in,
                              void* d_out, int out_size, void* d_ws,
                              size_t ws_size, hipStream_t stream) {
    const float* x  = (const float*)d_in[0];
    const int* ei   = (const int*)d_in[1];
    const float* W[3]  = {(const float*)d_in[2], (const float*)d_in[8],  (const float*)d_in[14]};
    const float* AS[3] = {(const float*)d_in[3], (const float*)d_in[9],  (const float*)d_in[15]};
    const float* AD[3] = {(const float*)d_in[4], (const float*)d_in[10], (const float*)d_in[16]};
    const float* Bb[3] = {(const float*)d_in[5], (const float*)d_in[11], (const float*)d_in[17]};
    const float* G[3]  = {(const float*)d_in[6], (const float*)d_in[12], (const float*)d_in[18]};
    const float* BE[3] = {(const float*)d_in[7], (const float*)d_in[13], (const float*)d_in[19]};
    const float* Wf  = (const float*)d_in[20];
    const float* asf = (const float*)d_in[21];
    const float* adf = (const float*)d_in[22];
    const float* bfp = (const float*)d_in[23];
    float* out = (float*)d_out;

    unsigned short* xb = (unsigned short*)d_ws;          // NN*128 bf16 (layer0 uses [NN][64])
    unsigned short* hb = xb + (size_t)NN * 128;          // NN*128 bf16
    float* a_s = (float*)(hb + (size_t)NN * 128);
    float* a_d = a_s + (size_t)NN * 4;
    int* row_ptr = (int*)(a_d + (size_t)NN * 4);
    int* esrc    = row_ptr + NN;
    int* gbh     = esrc + ETOT;
    int* ebase   = gbh + NB;
    int* gcur    = ebase + NB + 1;
    int* pbuf    = gcur + NB;                            // EE ints
    unsigned short* Wt0 = (unsigned short*)(pbuf + EE);  // 128*64
    unsigned short* Wt1 = Wt0 + 128 * 64;                // 128*128
    unsigned short* Wt2 = Wt1 + 128 * 128;               // 128*128
    unsigned short* Wtf = Wt2 + 128 * 128;               // 32*128

    // dtype prep
    k_cvt_x<<<(NN * 64 / 8 + 255) / 256, 256, 0, stream>>>(x, xb);
    k_cvt_wt<<<(64 * 128 + 255) / 256, 256, 0, stream>>>(W[0], Wt0, 64, 128);
    k_cvt_wt<<<(128 * 128 + 255) / 256, 256, 0, stream>>>(W[1], Wt1, 128, 128);
    k_cvt_wt<<<(128 * 128 + 255) / 256, 256, 0, stream>>>(W[2], Wt2, 128, 128);
    k_cvt_wt<<<(128 * 32 + 255) / 256, 256, 0, stream>>>(Wf, Wtf, 128, 32);

    // CSR build
    k_zero<<<1, 128, 0, stream>>>(gbh, NB);
    k_bhist<<<(EE + 2047) / 2048, 256, 0, stream>>>(ei, gbh);
    k_bscan<<<1, 128, 0, stream>>>(gbh, ebase, gcur);
    k_bscatter<<<(EE + CCH - 1) / CCH, 256, 0, stream>>>(ei, gcur, pbuf);
    k_bcsr<<<NB, 256, 0, stream>>>(pbuf, ebase, row_ptr, esrc);

    // layers
    const unsigned short* Wts[3] = {Wt0, Wt1, Wt2};
    int K = 64;
    int gblk = (NN + 127) / 128;
    for (int l = 0; l < 3; l++) {
        k_mfma_att<128, 4><<<gblk, 256, 0, stream>>>(xb, Wts[l], AS[l], AD[l],
                                                     hb, a_s, a_d, NN, K);
        k_aggregate_ln<<<(NN + 3) / 4, 256, 0, stream>>>(hb, a_s, a_d, row_ptr,
                                                         esrc, Bb[l], G[l], BE[l], xb);
        K = 128;
    }
    k_mfma_att<32, 1><<<gblk, 256, 0, stream>>>(xb, Wtf, asf, adf, hb, a_s, a_d,
                                                NN, 128);
    k_agg_final<<<(NN + 3) / 4, 256, 0, stream>>>(hb, a_s, a_d, row_ptr, esrc,
                                                  bfp, out);
}

// Round 8
// 596.599 us; speedup vs baseline: 1.9359x; 1.0071x over previous
//
#include <hip/hip_runtime.h>
#include <hip/hip_bf16.h>

constexpr int NN   = 100000;
constexpr int EE   = 1600000;
constexpr int ETOT = EE + NN;
constexpr float SLOPE = 0.2f;
constexpr int BSH = 10;     // nodes per bucket = 1024
constexpr int NB  = (NN + (1 << BSH) - 1) >> BSH;  // 98 buckets
constexpr int CCH = 8192;   // edges per scatter block

typedef __attribute__((ext_vector_type(8))) short short8;
typedef __attribute__((ext_vector_type(4))) float f32x4;

__device__ __forceinline__ float bf_lo(unsigned u) { return __uint_as_float(u << 16); }
__device__ __forceinline__ float bf_hi(unsigned u) { return __uint_as_float(u & 0xffff0000u); }
__device__ __forceinline__ unsigned short f2bf(float f) {
    __hip_bfloat16 h = __float2bfloat16(f);
    return *(unsigned short*)&h;
}
// wave-local LDS RAW ordering: DS pipe is in-order per wave; wait + compiler barrier
__device__ __forceinline__ void wave_lds_fence() {
    __asm__ volatile("s_waitcnt lgkmcnt(0)" ::: "memory");
}

// ---------------- dtype conversions ----------------
__global__ void k_cvt_x(const float* __restrict__ x, unsigned short* __restrict__ xb) {
    int i = blockIdx.x * blockDim.x + threadIdx.x;   // 8 floats per thread
    if (i >= NN * 64 / 8) return;
    const float4* xp = (const float4*)(x + (size_t)i * 8);
    float4 v0 = xp[0], v1 = xp[1];
    unsigned short o[8] = {f2bf(v0.x), f2bf(v0.y), f2bf(v0.z), f2bf(v0.w),
                           f2bf(v1.x), f2bf(v1.y), f2bf(v1.z), f2bf(v1.w)};
    *(uint4*)(xb + (size_t)i * 8) = *(uint4*)o;
}

// W [K][N] fp32 -> Wt [N][K] bf16
__global__ void k_cvt_wt(const float* __restrict__ W, unsigned short* __restrict__ Wt,
                         int K, int N) {
    int i = blockIdx.x * blockDim.x + threadIdx.x;
    if (i >= K * N) return;
    int k = i / N, n = i % N;
    Wt[(size_t)n * K + k] = f2bf(W[i]);
}

// ---------------- bucketed CSR build ----------------
__global__ void k_zero(int* p, int n) {
    int i = blockIdx.x * blockDim.x + threadIdx.x;
    if (i < n) p[i] = 0;
}

__global__ __launch_bounds__(256) void k_bhist(const int* __restrict__ ei,
                                               int* __restrict__ gbh) {
    __shared__ int h[NB];
    int t = threadIdx.x;
    if (t < NB) h[t] = 0;
    __syncthreads();
    int i = blockIdx.x * 2048 + t;
#pragma unroll
    for (int k = 0; k < 8; k++, i += 256)
        if (i < EE) atomicAdd(&h[ei[EE + i] >> BSH], 1);
    __syncthreads();
    if (t < NB && h[t]) atomicAdd(&gbh[t], h[t]);
}

__global__ void k_bscan(const int* __restrict__ gbh, int* __restrict__ ebase,
                        int* __restrict__ gcur) {
    __shared__ int sd[128];
    int t = threadIdx.x;
    int v = (t < NB) ? gbh[t] : 0;
    sd[t] = v;
    __syncthreads();
    for (int off = 1; off < 128; off <<= 1) {
        int x = (t >= off) ? sd[t - off] : 0;
        __syncthreads();
        sd[t] += x;
        __syncthreads();
    }
    int ex = sd[t] - v;
    if (t < NB) { ebase[t] = ex; gcur[t] = ex; }
    if (t == NB) ebase[NB] = EE;
}

__global__ __launch_bounds__(256) void k_bscatter(const int* __restrict__ ei,
                                                  int* __restrict__ gcur,
                                                  int* __restrict__ pbuf) {
    __shared__ int h[NB], base[NB], cur[NB];
    int t = threadIdx.x;
    if (t < NB) { h[t] = 0; cur[t] = 0; }
    __syncthreads();
    int c0 = blockIdx.x * CCH;
    int cend = c0 + CCH < EE ? c0 + CCH : EE;
    for (int i = c0 + t; i < cend; i += 256)
        atomicAdd(&h[ei[EE + i] >> BSH], 1);
    __syncthreads();
    if (t < NB && h[t] > 0) base[t] = atomicAdd(&gcur[t], h[t]);
    __syncthreads();
    for (int i = c0 + t; i < cend; i += 256) {
        int s = ei[i], d = ei[EE + i];
        int b = d >> BSH;
        int c = atomicAdd(&cur[b], 1);
        pbuf[base[b] + c] = s | ((d & ((1 << BSH) - 1)) << 17);
    }
}

__global__ __launch_bounds__(256) void k_bcsr(const int* __restrict__ pbuf,
                                              const int* __restrict__ ebase,
                                              int* __restrict__ row_ptr,
                                              int* __restrict__ esrc) {
    constexpr int BNODES = 1 << BSH;
    __shared__ int hist[BNODES];
    __shared__ int cur[BNODES];
    __shared__ int sd[256];
    int b = blockIdx.x, t = threadIdx.x;
    int node0 = b << BSH;
    int e0 = ebase[b], e1 = ebase[b + 1];
    for (int i = t; i < BNODES; i += 256) { hist[i] = 0; cur[i] = 0; }
    __syncthreads();
    for (int i = e0 + t; i < e1; i += 256)
        atomicAdd(&hist[pbuf[i] >> 17], 1);
    __syncthreads();
    int s0 = hist[4 * t], s1 = hist[4 * t + 1], s2 = hist[4 * t + 2], s3 = hist[4 * t + 3];
    int ts = s0 + s1 + s2 + s3;
    sd[t] = ts;
    __syncthreads();
    for (int off = 1; off < 256; off <<= 1) {
        int x = (t >= off) ? sd[t - off] : 0;
        __syncthreads();
        sd[t] += x;
        __syncthreads();
    }
    int ex = sd[t] - ts;
    hist[4 * t] = ex;
    hist[4 * t + 1] = ex + s0;
    hist[4 * t + 2] = ex + s0 + s1;
    hist[4 * t + 3] = ex + s0 + s1 + s2;
    __syncthreads();
    int rbase = e0 + node0;
    for (int nl = t; nl < BNODES; nl += 256) {
        int n = node0 + nl;
        if (n < NN) {
            int rp = rbase + hist[nl] + nl;
            row_ptr[n] = rp;
            esrc[rp] = n;  // self loop in slot 0
        }
    }
    __syncthreads();
    for (int i = e0 + t; i < e1; i += 256) {
        int p = pbuf[i];
        int nl = p >> 17;
        int c = atomicAdd(&cur[nl], 1);
        esrc[rbase + hist[nl] + nl + 1 + c] = p & 0x1FFFF;
    }
}

// ------- bf16 MFMA GEMM (128xBN tile, BN = full width) + fused att dots + bf16 h -------
template <int BN, int H>
__global__ __launch_bounds__(256) void k_mfma_att(
    const unsigned short* __restrict__ Ab, const unsigned short* __restrict__ Bt,
    const float* __restrict__ as_, const float* __restrict__ ad_,
    unsigned short* __restrict__ hb, float* __restrict__ a_s,
    float* __restrict__ a_d, int M, int K) {
    constexpr int NCT = BN / 16;
    constexpr int LDK = 72;  // 64-slab + 8-short pad
    __shared__ unsigned short As[128 * LDK];
    __shared__ unsigned short Bs[BN * LDK];
    int tid = threadIdx.x;
    int lane = tid & 63, w = tid >> 6;
    int q = lane >> 4, col = lane & 15;
    int rowBase = blockIdx.x * 128;

    f32x4 acc[2][NCT];
#pragma unroll
    for (int rt = 0; rt < 2; rt++)
#pragma unroll
        for (int ct = 0; ct < NCT; ct++) acc[rt][ct] = (f32x4){0.f, 0.f, 0.f, 0.f};

    int u = tid & 7;
    int r0 = tid >> 3;
    int nph = K >> 6;
    for (int ph = 0; ph < nph; ph++) {
        int kof = ph * 64 + u * 8;
#pragma unroll
        for (int rr = r0; rr < 128; rr += 32) {
            int gr = rowBase + rr;
            uint4 v = make_uint4(0, 0, 0, 0);
            if (gr < M) v = *(const uint4*)(Ab + (size_t)gr * K + kof);
            *(uint4*)(&As[rr * LDK + u * 8]) = v;
        }
#pragma unroll
        for (int br = r0; br < BN; br += 32) {
            uint4 v = *(const uint4*)(Bt + (size_t)br * K + kof);
            *(uint4*)(&Bs[br * LDK + u * 8]) = v;
        }
        __syncthreads();

        short8 af[2][2];
#pragma unroll
        for (int rt = 0; rt < 2; rt++)
#pragma unroll
            for (int kt = 0; kt < 2; kt++)
                af[rt][kt] = *(const short8*)(&As[(w * 32 + rt * 16 + col) * LDK + kt * 32 + q * 8]);
#pragma unroll
        for (int kt = 0; kt < 2; kt++)
#pragma unroll
            for (int ct = 0; ct < NCT; ct++) {
                short8 bf = *(const short8*)(&Bs[(ct * 16 + col) * LDK + kt * 32 + q * 8]);
#pragma unroll
                for (int rt = 0; rt < 2; rt++)
                    acc[rt][ct] = __builtin_amdgcn_mfma_f32_16x16x32_bf16(
                        af[rt][kt], bf, acc[rt][ct], 0, 0, 0);
            }
        __syncthreads();
    }

    float swv[NCT], dwv[NCT];
#pragma unroll
    for (int ct = 0; ct < NCT; ct++) {
        int c = ct * 16 + col;
        swv[ct] = as_[c];
        dwv[ct] = ad_[c];
    }
#pragma unroll
    for (int rt = 0; rt < 2; rt++) {
#pragma unroll
        for (int r = 0; r < 4; r++) {
            int gr = rowBase + w * 32 + rt * 16 + q * 4 + r;
            if constexpr (H == 4) {
                float ps[4] = {0, 0, 0, 0}, pd[4] = {0, 0, 0, 0};
#pragma unroll
                for (int ct = 0; ct < NCT; ct++) {
                    float v = acc[rt][ct][r];
                    ps[ct >> 1] += v * swv[ct];
                    pd[ct >> 1] += v * dwv[ct];
                }
#pragma unroll
                for (int m = 1; m < 16; m <<= 1)
#pragma unroll
                    for (int h = 0; h < 4; h++) {
                        ps[h] += __shfl_xor(ps[h], m);
                        pd[h] += __shfl_xor(pd[h], m);
                    }
                if (gr < M) {
#pragma unroll
                    for (int ct = 0; ct < NCT; ct++)
                        hb[(size_t)gr * BN + ct * 16 + col] = f2bf(acc[rt][ct][r]);
                    if (col == 0) {
                        *(float4*)(a_s + (size_t)gr * 4) = make_float4(ps[0], ps[1], ps[2], ps[3]);
                        *(float4*)(a_d + (size_t)gr * 4) = make_float4(pd[0], pd[1], pd[2], pd[3]);
                    }
                }
            } else {
                float ps = 0.f, pd = 0.f;
#pragma unroll
                for (int ct = 0; ct < NCT; ct++) {
                    float v = acc[rt][ct][r];
                    ps += v * swv[ct];
                    pd += v * dwv[ct];
                }
#pragma unroll
                for (int m = 1; m < 16; m <<= 1) {
                    ps += __shfl_xor(ps, m);
                    pd += __shfl_xor(pd, m);
                }
                if (gr < M) {
#pragma unroll
                    for (int ct = 0; ct < NCT; ct++)
                        hb[(size_t)gr * BN + ct * 16 + col] = f2bf(acc[rt][ct][r]);
                    if (col == 0) { a_s[gr] = ps; a_d[gr] = pd; }
                }
            }
        }
    }
}

// -------- wave-per-node: softmax + aggregate(bf16 h) + bias + LN + ELU -> bf16 x --------
// Phase A stages (src, alpha[head]) pairs in a WAVE-PRIVATE LDS slab (no barriers;
// DS pipe is in-order per wave + lgkmcnt fence). Phase B: one ds_read_b64 per edge-iter.
__global__ __launch_bounds__(256) void k_aggregate_ln(
    const unsigned short* __restrict__ hb, const float* __restrict__ a_src,
    const float* __restrict__ a_dst, const int* __restrict__ row_ptr,
    const int* __restrict__ esrc, const float* __restrict__ bias,
    const float* __restrict__ gamma, const float* __restrict__ beta,
    unsigned short* __restrict__ xb) {
    __shared__ uint2 slab_all[4][64 * 5];  // [wave][j*5+head], stride-5 spreads banks
    int lane = threadIdx.x & 63;
    int w = threadIdx.x >> 6;
    uint2* slab = slab_all[w];
    int n = blockIdx.x * 4 + w;
    if (n >= NN) return;
    int start = row_ptr[n];
    int end = (n == NN - 1) ? ETOT : row_ptr[n + 1];
    int deg = end - start;

    float4 ad = ((const float4*)a_dst)[n];
    int g = lane >> 4, c16 = lane & 15, head = c16 >> 2;
    float acc[8];
#pragma unroll
    for (int k = 0; k < 8; k++) acc[k] = 0.f;

    if (deg <= 64) {
        int msrc = 0;
        float me0 = 0.f, me1 = 0.f, me2 = 0.f, me3 = 0.f;
        if (lane < deg) {
            int s = esrc[start + lane];
            msrc = s;
            float4 a = ((const float4*)a_src)[s];
            float e0 = a.x + ad.x; e0 = e0 > 0.f ? e0 : SLOPE * e0; me0 = __expf(e0);
            float e1 = a.y + ad.y; e1 = e1 > 0.f ? e1 : SLOPE * e1; me1 = __expf(e1);
            float e2 = a.z + ad.z; e2 = e2 > 0.f ? e2 : SLOPE * e2; me2 = __expf(e2);
            float e3 = a.w + ad.w; e3 = e3 > 0.f ? e3 : SLOPE * e3; me3 = __expf(e3);
        }
        float d0 = me0, d1 = me1, d2 = me2, d3 = me3;
#pragma unroll
        for (int m = 1; m < 64; m <<= 1) {
            d0 += __shfl_xor(d0, m);
            d1 += __shfl_xor(d1, m);
            d2 += __shfl_xor(d2, m);
            d3 += __shfl_xor(d3, m);
        }
        me0 *= 1.f / (d0 + 1e-16f);
        me1 *= 1.f / (d1 + 1e-16f);
        me2 *= 1.f / (d2 + 1e-16f);
        me3 *= 1.f / (d3 + 1e-16f);
        if (lane < deg) {
            slab[lane * 5 + 0] = make_uint2((unsigned)msrc, __float_as_uint(me0));
            slab[lane * 5 + 1] = make_uint2((unsigned)msrc, __float_as_uint(me1));
            slab[lane * 5 + 2] = make_uint2((unsigned)msrc, __float_as_uint(me2));
            slab[lane * 5 + 3] = make_uint2((unsigned)msrc, __float_as_uint(me3));
        }
        wave_lds_fence();
        int iters = (deg + 3) >> 2;
        for (int it = 0; it < iters; it++) {
            int j = g + (it << 2);
            if (j < deg) {
                uint2 p = slab[j * 5 + head];
                int s = (int)p.x;
                float al = __uint_as_float(p.y);
                uint4 uu = *(const uint4*)(hb + (size_t)s * 128 + c16 * 8);
                acc[0] += bf_lo(uu.x) * al; acc[1] += bf_hi(uu.x) * al;
                acc[2] += bf_lo(uu.y) * al; acc[3] += bf_hi(uu.y) * al;
                acc[4] += bf_lo(uu.z) * al; acc[5] += bf_hi(uu.z) * al;
                acc[6] += bf_lo(uu.w) * al; acc[7] += bf_hi(uu.w) * al;
            }
        }
    } else {  // cold fallback
        float d0 = 0.f, d1 = 0.f, d2 = 0.f, d3 = 0.f;
        for (int k = start + lane; k < end; k += 64) {
            int s = esrc[k];
            float4 a = ((const float4*)a_src)[s];
            float e0 = a.x + ad.x; e0 = e0 > 0.f ? e0 : SLOPE * e0; d0 += __expf(e0);
            float e1 = a.y + ad.y; e1 = e1 > 0.f ? e1 : SLOPE * e1; d1 += __expf(e1);
            float e2 = a.z + ad.z; e2 = e2 > 0.f ? e2 : SLOPE * e2; d2 += __expf(e2);
            float e3 = a.w + ad.w; e3 = e3 > 0.f ? e3 : SLOPE * e3; d3 += __expf(e3);
        }
#pragma unroll
        for (int m = 1; m < 64; m <<= 1) {
            d0 += __shfl_xor(d0, m);
            d1 += __shfl_xor(d1, m);
            d2 += __shfl_xor(d2, m);
            d3 += __shfl_xor(d3, m);
        }
        float invh = head == 0 ? 1.f / (d0 + 1e-16f) : head == 1 ? 1.f / (d1 + 1e-16f)
                   : head == 2 ? 1.f / (d2 + 1e-16f) : 1.f / (d3 + 1e-16f);
        float adh = head == 0 ? ad.x : head == 1 ? ad.y : head == 2 ? ad.z : ad.w;
        for (int j = g; j < deg; j += 4) {
            int s = esrc[start + j];
            float e = a_src[(size_t)s * 4 + head] + adh;
            e = e > 0.f ? e : SLOPE * e;
            float al = __expf(e) * invh;
            uint4 uu = *(const uint4*)(hb + (size_t)s * 128 + c16 * 8);
            acc[0] += bf_lo(uu.x) * al; acc[1] += bf_hi(uu.x) * al;
            acc[2] += bf_lo(uu.y) * al; acc[3] += bf_hi(uu.y) * al;
            acc[4] += bf_lo(uu.z) * al; acc[5] += bf_hi(uu.z) * al;
            acc[6] += bf_lo(uu.w) * al; acc[7] += bf_hi(uu.w) * al;
        }
    }

#pragma unroll
    for (int k = 0; k < 8; k++) {
        acc[k] += __shfl_xor(acc[k], 16);
        acc[k] += __shfl_xor(acc[k], 32);
    }
    if (lane < 16) {
        float y[8];
        float sum = 0.f;
        const float4* bp = (const float4*)(bias + lane * 8);
        float4 b0 = bp[0], b1 = bp[1];
#pragma unroll
        for (int k = 0; k < 8; k++) {
            float b = k < 4 ? (&b0.x)[k] : (&b1.x)[k - 4];
            y[k] = acc[k] + b;
            sum += y[k];
        }
#pragma unroll
        for (int m = 1; m < 16; m <<= 1) sum += __shfl_xor(sum, m);
        float mu = sum * (1.f / 128.f);
        float ss = 0.f;
        float d[8];
#pragma unroll
        for (int k = 0; k < 8; k++) { d[k] = y[k] - mu; ss += d[k] * d[k]; }
#pragma unroll
        for (int m = 1; m < 16; m <<= 1) ss += __shfl_xor(ss, m);
        float is = rsqrtf(ss * (1.f / 128.f) + 1e-5f);
        const float4* gp = (const float4*)(gamma + lane * 8);
        const float4* ep = (const float4*)(beta + lane * 8);
        float4 g0 = gp[0], g1 = gp[1], e0 = ep[0], e1 = ep[1];
        unsigned short o16[8];
#pragma unroll
        for (int k = 0; k < 8; k++) {
            float gm = k < 4 ? (&g0.x)[k] : (&g1.x)[k - 4];
            float bt = k < 4 ? (&e0.x)[k] : (&e1.x)[k - 4];
            float z = gm * (d[k] * is) + bt;
            o16[k] = f2bf(z > 0.f ? z : __expf(z) - 1.f);
        }
        *(uint4*)(xb + (size_t)n * 128 + lane * 8) = *(uint4*)o16;
    }
}

// -------- final layer, wave-per-node: H=1, C=32 (bf16 h), writes fp32 d_out --------
__global__ __launch_bounds__(256) void k_agg_final(
    const unsigned short* __restrict__ hb, const float* __restrict__ a_src,
    const float* __restrict__ a_dst, const int* __restrict__ row_ptr,
    const int* __restrict__ esrc, const float* __restrict__ bf,
    float* __restrict__ out) {
    __shared__ uint2 slab_all[4][64];
    int lane = threadIdx.x & 63;
    int w = threadIdx.x >> 6;
    uint2* slab = slab_all[w];
    int n = blockIdx.x * 4 + w;
    if (n >= NN) return;
    int start = row_ptr[n];
    int end = (n == NN - 1) ? ETOT : row_ptr[n + 1];
    int deg = end - start;
    float adn = a_dst[n];

    int g = lane >> 3, c8 = lane & 7;
    float acc[4] = {0.f, 0.f, 0.f, 0.f};

    if (deg <= 64) {
        int msrc = 0;
        float me = 0.f;
        if (lane < deg) {
            int s = esrc[start + lane];
            msrc = s;
            float e = a_src[s] + adn;
            e = e > 0.f ? e : SLOPE * e;
            me = __expf(e);
        }
        float d = me;
#pragma unroll
        for (int m = 1; m < 64; m <<= 1) d += __shfl_xor(d, m);
        me *= 1.f / (d + 1e-16f);
        if (lane < deg) slab[lane] = make_uint2((unsigned)msrc, __float_as_uint(me));
        wave_lds_fence();
        int iters = (deg + 7) >> 3;
        for (int it = 0; it < iters; it++) {
            int j = g + (it << 3);
            if (j < deg) {
                uint2 p = slab[j];
                int s = (int)p.x;
                float al = __uint_as_float(p.y);
                uint2 u = *(const uint2*)(hb + (size_t)s * 32 + c8 * 4);
                acc[0] += bf_lo(u.x) * al; acc[1] += bf_hi(u.x) * al;
                acc[2] += bf_lo(u.y) * al; acc[3] += bf_hi(u.y) * al;
            }
        }
    } else {
        float d = 0.f;
        for (int k = start + lane; k < end; k += 64) {
            int s = esrc[k];
            float e = a_src[s] + adn;
            e = e > 0.f ? e : SLOPE * e;
            d += __expf(e);
        }
#pragma unroll
        for (int m = 1; m < 64; m <<= 1) d += __shfl_xor(d, m);
        float inv = 1.f / (d + 1e-16f);
        for (int j = g; j < deg; j += 8) {
            int s = esrc[start + j];
            float e = a_src[s] + adn;
            e = e > 0.f ? e : SLOPE * e;
            float al = __expf(e) * inv;
            uint2 u = *(const uint2*)(hb + (size_t)s * 32 + c8 * 4);
            acc[0] += bf_lo(u.x) * al; acc[1] += bf_hi(u.x) * al;
            acc[2] += bf_lo(u.y) * al; acc[3] += bf_hi(u.y) * al;
        }
    }
#pragma unroll
    for (int k = 0; k < 4; k++) {
        acc[k] += __shfl_xor(acc[k], 8);
        acc[k] += __shfl_xor(acc[k], 16);
        acc[k] += __shfl_xor(acc[k], 32);
    }
    if (lane < 8) {
        float4 b4 = ((const float4*)bf)[lane];
        float4 o = make_float4(acc[0] + b4.x, acc[1] + b4.y, acc[2] + b4.z,
                               acc[3] + b4.w);
        ((float4*)out)[(size_t)n * 8 + lane] = o;
    }
}

// ---------------- launch ----------------
extern "C" void kernel_launch(void* const* d_in, const int* in_sizes, int n_in,
                              void* d_out, int out_size, void* d_ws,
                              size_t ws_size, hipStream_t stream) {
    const float* x  = (const float*)d_in[0];
    const int* ei   = (const int*)d_in[1];
    const float* W[3]  = {(const float*)d_in[2], (const float*)d_in[8],  (const float*)d_in[14]};
    const float* AS[3] = {(const float*)d_in[3], (const float*)d_in[9],  (const float*)d_in[15]};
    const float* AD[3] = {(const float*)d_in[4], (const float*)d_in[10], (const float*)d_in[16]};
    const float* Bb[3] = {(const float*)d_in[5], (const float*)d_in[11], (const float*)d_in[17]};
    const float* G[3]  = {(const float*)d_in[6], (const float*)d_in[12], (const float*)d_in[18]};
    const float* BE[3] = {(const float*)d_in[7], (const float*)d_in[13], (const float*)d_in[19]};
    const float* Wf  = (const float*)d_in[20];
    const float* asf = (const float*)d_in[21];
    const float* adf = (const float*)d_in[22];
    const float* bfp = (const float*)d_in[23];
    float* out = (float*)d_out;

    unsigned short* xb = (unsigned short*)d_ws;          // NN*128 bf16 (layer0 uses [NN][64])
    unsigned short* hb = xb + (size_t)NN * 128;          // NN*128 bf16
    float* a_s = (float*)(hb + (size_t)NN * 128);
    float* a_d = a_s + (size_t)NN * 4;
    int* row_ptr = (int*)(a_d + (size_t)NN * 4);
    int* esrc    = row_ptr + NN;
    int* gbh     = esrc + ETOT;
    int* ebase   = gbh + NB;
    int* gcur    = ebase + NB + 1;
    int* pbuf    = gcur + NB;                            // EE ints
    unsigned short* Wt0 = (unsigned short*)(pbuf + EE);  // 128*64
    unsigned short* Wt1 = Wt0 + 128 * 64;                // 128*128
    unsigned short* Wt2 = Wt1 + 128 * 128;               // 128*128
    unsigned short* Wtf = Wt2 + 128 * 128;               // 32*128

    // dtype prep
    k_cvt_x<<<(NN * 64 / 8 + 255) / 256, 256, 0, stream>>>(x, xb);
    k_cvt_wt<<<(64 * 128 + 255) / 256, 256, 0, stream>>>(W[0], Wt0, 64, 128);
    k_cvt_wt<<<(128 * 128 + 255) / 256, 256, 0, stream>>>(W[1], Wt1, 128, 128);
    k_cvt_wt<<<(128 * 128 + 255) / 256, 256, 0, stream>>>(W[2], Wt2, 128, 128);
    k_cvt_wt<<<(128 * 32 + 255) / 256, 256, 0, stream>>>(Wf, Wtf, 128, 32);

    // CSR build
    k_zero<<<1, 128, 0, stream>>>(gbh, NB);
    k_bhist<<<(EE + 2047) / 2048, 256, 0, stream>>>(ei, gbh);
    k_bscan<<<1, 128, 0, stream>>>(gbh, ebase, gcur);
    k_bscatter<<<(EE + CCH - 1) / CCH, 256, 0, stream>>>(ei, gcur, pbuf);
    k_bcsr<<<NB, 256, 0, stream>>>(pbuf, ebase, row_ptr, esrc);

    // layers
    const unsigned short* Wts[3] = {Wt0, Wt1, Wt2};
    int K = 64;
    int gblk = (NN + 127) / 128;
    for (int l = 0; l < 3; l++) {
        k_mfma_att<128, 4><<<gblk, 256, 0, stream>>>(xb, Wts[l], AS[l], AD[l],
                                                     hb, a_s, a_d, NN, K);
        k_aggregate_ln<<<(NN + 3) / 4, 256, 0, stream>>>(hb, a_s, a_d, row_ptr,
                                                         esrc, Bb[l], G[l], BE[l], xb);
        K = 128;
    }
    k_mfma_att<32, 1><<<gblk, 256, 0, stream>>>(xb, Wtf, asf, adf, hb, a_s, a_d,
                                                NN, 128);
    k_agg_final<<<(NN + 3) / 4, 256, 0, stream>>>(hb, a_s, a_d, row_ptr, esrc,
                                                  bfp, out);
}

// Round 9
// 560.636 us; speedup vs baseline: 2.0601x; 1.0641x over previous
//
#include <hip/hip_runtime.h>
#include <hip/hip_bf16.h>

constexpr int NN   = 100000;
constexpr int EE   = 1600000;
constexpr int ETOT = EE + NN;
constexpr float SLOPE = 0.2f;
constexpr int BSH = 10;     // nodes per bucket = 1024
constexpr int NB  = (NN + (1 << BSH) - 1) >> BSH;  // 98 buckets
constexpr int CCH = 8192;   // edges per scatter block
constexpr int DCAP = 48;    // per-node edge cap for packed path (Poisson(16)+1, ~7 sigma)

typedef __attribute__((ext_vector_type(8))) short short8;
typedef __attribute__((ext_vector_type(4))) float f32x4;

__device__ __forceinline__ float bf_lo(unsigned u) { return __uint_as_float(u << 16); }
__device__ __forceinline__ float bf_hi(unsigned u) { return __uint_as_float(u & 0xffff0000u); }
__device__ __forceinline__ unsigned short f2bf(float f) {
    __hip_bfloat16 h = __float2bfloat16(f);
    return *(unsigned short*)&h;
}
// wave-local LDS RAW ordering: DS pipe is in-order per wave; wait + compiler barrier
__device__ __forceinline__ void wave_lds_fence() {
    __asm__ volatile("s_waitcnt lgkmcnt(0)" ::: "memory");
}

// ---------------- dtype conversions ----------------
__global__ void k_cvt_x(const float* __restrict__ x, unsigned short* __restrict__ xb) {
    int i = blockIdx.x * blockDim.x + threadIdx.x;   // 8 floats per thread
    if (i >= NN * 64 / 8) return;
    const float4* xp = (const float4*)(x + (size_t)i * 8);
    float4 v0 = xp[0], v1 = xp[1];
    unsigned short o[8] = {f2bf(v0.x), f2bf(v0.y), f2bf(v0.z), f2bf(v0.w),
                           f2bf(v1.x), f2bf(v1.y), f2bf(v1.z), f2bf(v1.w)};
    *(uint4*)(xb + (size_t)i * 8) = *(uint4*)o;
}

// W [K][N] fp32 -> Wt [N][K] bf16
__global__ void k_cvt_wt(const float* __restrict__ W, unsigned short* __restrict__ Wt,
                         int K, int N) {
    int i = blockIdx.x * blockDim.x + threadIdx.x;
    if (i >= K * N) return;
    int k = i / N, n = i % N;
    Wt[(size_t)n * K + k] = f2bf(W[i]);
}

// ---------------- bucketed CSR build ----------------
__global__ void k_zero(int* p, int n) {
    int i = blockIdx.x * blockDim.x + threadIdx.x;
    if (i < n) p[i] = 0;
}

__global__ __launch_bounds__(256) void k_bhist(const int* __restrict__ ei,
                                               int* __restrict__ gbh) {
    __shared__ int h[NB];
    int t = threadIdx.x;
    if (t < NB) h[t] = 0;
    __syncthreads();
    int i = blockIdx.x * 2048 + t;
#pragma unroll
    for (int k = 0; k < 8; k++, i += 256)
        if (i < EE) atomicAdd(&h[ei[EE + i] >> BSH], 1);
    __syncthreads();
    if (t < NB && h[t]) atomicAdd(&gbh[t], h[t]);
}

__global__ void k_bscan(const int* __restrict__ gbh, int* __restrict__ ebase,
                        int* __restrict__ gcur) {
    __shared__ int sd[128];
    int t = threadIdx.x;
    int v = (t < NB) ? gbh[t] : 0;
    sd[t] = v;
    __syncthreads();
    for (int off = 1; off < 128; off <<= 1) {
        int x = (t >= off) ? sd[t - off] : 0;
        __syncthreads();
        sd[t] += x;
        __syncthreads();
    }
    int ex = sd[t] - v;
    if (t < NB) { ebase[t] = ex; gcur[t] = ex; }
    if (t == NB) ebase[NB] = EE;
}

__global__ __launch_bounds__(256) void k_bscatter(const int* __restrict__ ei,
                                                  int* __restrict__ gcur,
                                                  int* __restrict__ pbuf) {
    __shared__ int h[NB], base[NB], cur[NB];
    int t = threadIdx.x;
    if (t < NB) { h[t] = 0; cur[t] = 0; }
    __syncthreads();
    int c0 = blockIdx.x * CCH;
    int cend = c0 + CCH < EE ? c0 + CCH : EE;
    for (int i = c0 + t; i < cend; i += 256)
        atomicAdd(&h[ei[EE + i] >> BSH], 1);
    __syncthreads();
    if (t < NB && h[t] > 0) base[t] = atomicAdd(&gcur[t], h[t]);
    __syncthreads();
    for (int i = c0 + t; i < cend; i += 256) {
        int s = ei[i], d = ei[EE + i];
        int b = d >> BSH;
        int c = atomicAdd(&cur[b], 1);
        pbuf[base[b] + c] = s | ((d & ((1 << BSH) - 1)) << 17);
    }
}

__global__ __launch_bounds__(256) void k_bcsr(const int* __restrict__ pbuf,
                                              const int* __restrict__ ebase,
                                              int* __restrict__ row_ptr,
                                              int* __restrict__ esrc) {
    constexpr int BNODES = 1 << BSH;
    __shared__ int hist[BNODES];
    __shared__ int cur[BNODES];
    __shared__ int sd[256];
    int b = blockIdx.x, t = threadIdx.x;
    int node0 = b << BSH;
    int e0 = ebase[b], e1 = ebase[b + 1];
    for (int i = t; i < BNODES; i += 256) { hist[i] = 0; cur[i] = 0; }
    __syncthreads();
    for (int i = e0 + t; i < e1; i += 256)
        atomicAdd(&hist[pbuf[i] >> 17], 1);
    __syncthreads();
    int s0 = hist[4 * t], s1 = hist[4 * t + 1], s2 = hist[4 * t + 2], s3 = hist[4 * t + 3];
    int ts = s0 + s1 + s2 + s3;
    sd[t] = ts;
    __syncthreads();
    for (int off = 1; off < 256; off <<= 1) {
        int x = (t >= off) ? sd[t - off] : 0;
        __syncthreads();
        sd[t] += x;
        __syncthreads();
    }
    int ex = sd[t] - ts;
    hist[4 * t] = ex;
    hist[4 * t + 1] = ex + s0;
    hist[4 * t + 2] = ex + s0 + s1;
    hist[4 * t + 3] = ex + s0 + s1 + s2;
    __syncthreads();
    int rbase = e0 + node0;
    for (int nl = t; nl < BNODES; nl += 256) {
        int n = node0 + nl;
        if (n < NN) {
            int rp = rbase + hist[nl] + nl;
            row_ptr[n] = rp;
            esrc[rp] = n;  // self loop in slot 0
        }
    }
    __syncthreads();
    for (int i = e0 + t; i < e1; i += 256) {
        int p = pbuf[i];
        int nl = p >> 17;
        int c = atomicAdd(&cur[nl], 1);
        esrc[rbase + hist[nl] + nl + 1 + c] = p & 0x1FFFF;
    }
}

// ------- bf16 MFMA GEMM (128xBN tile, BN = full width) + fused att dots + bf16 h -------
template <int BN, int H>
__global__ __launch_bounds__(256) void k_mfma_att(
    const unsigned short* __restrict__ Ab, const unsigned short* __restrict__ Bt,
    const float* __restrict__ as_, const float* __restrict__ ad_,
    unsigned short* __restrict__ hb, float* __restrict__ a_s,
    float* __restrict__ a_d, int M, int K) {
    constexpr int NCT = BN / 16;
    constexpr int LDK = 72;  // 64-slab + 8-short pad
    __shared__ unsigned short As[128 * LDK];
    __shared__ unsigned short Bs[BN * LDK];
    int tid = threadIdx.x;
    int lane = tid & 63, w = tid >> 6;
    int q = lane >> 4, col = lane & 15;
    int rowBase = blockIdx.x * 128;

    f32x4 acc[2][NCT];
#pragma unroll
    for (int rt = 0; rt < 2; rt++)
#pragma unroll
        for (int ct = 0; ct < NCT; ct++) acc[rt][ct] = (f32x4){0.f, 0.f, 0.f, 0.f};

    int u = tid & 7;
    int r0 = tid >> 3;
    int nph = K >> 6;
    for (int ph = 0; ph < nph; ph++) {
        int kof = ph * 64 + u * 8;
#pragma unroll
        for (int rr = r0; rr < 128; rr += 32) {
            int gr = rowBase + rr;
            uint4 v = make_uint4(0, 0, 0, 0);
            if (gr < M) v = *(const uint4*)(Ab + (size_t)gr * K + kof);
            *(uint4*)(&As[rr * LDK + u * 8]) = v;
        }
#pragma unroll
        for (int br = r0; br < BN; br += 32) {
            uint4 v = *(const uint4*)(Bt + (size_t)br * K + kof);
            *(uint4*)(&Bs[br * LDK + u * 8]) = v;
        }
        __syncthreads();

        short8 af[2][2];
#pragma unroll
        for (int rt = 0; rt < 2; rt++)
#pragma unroll
            for (int kt = 0; kt < 2; kt++)
                af[rt][kt] = *(const short8*)(&As[(w * 32 + rt * 16 + col) * LDK + kt * 32 + q * 8]);
#pragma unroll
        for (int kt = 0; kt < 2; kt++)
#pragma unroll
            for (int ct = 0; ct < NCT; ct++) {
                short8 bf = *(const short8*)(&Bs[(ct * 16 + col) * LDK + kt * 32 + q * 8]);
#pragma unroll
                for (int rt = 0; rt < 2; rt++)
                    acc[rt][ct] = __builtin_amdgcn_mfma_f32_16x16x32_bf16(
                        af[rt][kt], bf, acc[rt][ct], 0, 0, 0);
            }
        __syncthreads();
    }

    float swv[NCT], dwv[NCT];
#pragma unroll
    for (int ct = 0; ct < NCT; ct++) {
        int c = ct * 16 + col;
        swv[ct] = as_[c];
        dwv[ct] = ad_[c];
    }
#pragma unroll
    for (int rt = 0; rt < 2; rt++) {
#pragma unroll
        for (int r = 0; r < 4; r++) {
            int gr = rowBase + w * 32 + rt * 16 + q * 4 + r;
            if constexpr (H == 4) {
                float ps[4] = {0, 0, 0, 0}, pd[4] = {0, 0, 0, 0};
#pragma unroll
                for (int ct = 0; ct < NCT; ct++) {
                    float v = acc[rt][ct][r];
                    ps[ct >> 1] += v * swv[ct];
                    pd[ct >> 1] += v * dwv[ct];
                }
#pragma unroll
                for (int m = 1; m < 16; m <<= 1)
#pragma unroll
                    for (int h = 0; h < 4; h++) {
                        ps[h] += __shfl_xor(ps[h], m);
                        pd[h] += __shfl_xor(pd[h], m);
                    }
                if (gr < M) {
#pragma unroll
                    for (int ct = 0; ct < NCT; ct++)
                        hb[(size_t)gr * BN + ct * 16 + col] = f2bf(acc[rt][ct][r]);
                    if (col == 0) {
                        *(float4*)(a_s + (size_t)gr * 4) = make_float4(ps[0], ps[1], ps[2], ps[3]);
                        *(float4*)(a_d + (size_t)gr * 4) = make_float4(pd[0], pd[1], pd[2], pd[3]);
                    }
                }
            } else {
                float ps = 0.f, pd = 0.f;
#pragma unroll
                for (int ct = 0; ct < NCT; ct++) {
                    float v = acc[rt][ct][r];
                    ps += v * swv[ct];
                    pd += v * dwv[ct];
                }
#pragma unroll
                for (int m = 1; m < 16; m <<= 1) {
                    ps += __shfl_xor(ps, m);
                    pd += __shfl_xor(pd, m);
                }
                if (gr < M) {
#pragma unroll
                    for (int ct = 0; ct < NCT; ct++)
                        hb[(size_t)gr * BN + ct * 16 + col] = f2bf(acc[rt][ct][r]);
                    if (col == 0) { a_s[gr] = ps; a_d[gr] = pd; }
                }
            }
        }
    }
}

// -------- 4-nodes-per-wave: softmax + aggregate(bf16 h) + bias + LN + ELU -> bf16 x --------
// 16-lane group g owns node n0+g. Phase A: lane i handles edges i,i+16,i+32 (deg<=48),
// writes (src, exp) per head to head-major wave-private LDS; 16-lane xor reductions.
// Phase B: one broadcast ds_read_b64 per edge; channels of a node live in its group
// (no cross-group reduce). LN epilogue on all 64 lanes (4 nodes at once).
__global__ __launch_bounds__(256) void k_aggregate_ln(
    const unsigned short* __restrict__ hb, const float* __restrict__ a_src,
    const float* __restrict__ a_dst, const int* __restrict__ row_ptr,
    const int* __restrict__ esrc, const float* __restrict__ bias,
    const float* __restrict__ gamma, const float* __restrict__ beta,
    unsigned short* __restrict__ xb) {
    __shared__ uint2 slab_all[4][4 * 4 * DCAP];  // [wave][node][head][j]
    int tid = threadIdx.x;
    int w = tid >> 6, lane = tid & 63;
    int g = lane >> 4, i = lane & 15;
    int myhead = i >> 2;
    uint2* slab = slab_all[w];
    int n0 = blockIdx.x * 16 + w * 4;
    int n = n0 + g;
    bool valid = n < NN;
    int start = 0, deg = 0;
    if (valid) {
        start = row_ptr[n];
        int end = (n == NN - 1) ? ETOT : row_ptr[n + 1];
        deg = end - start;
    }
    // wave-wide max degree (uniform branch selector)
    int wmax = deg;
#pragma unroll
    for (int m = 1; m < 64; m <<= 1) wmax = max(wmax, __shfl_xor(wmax, m));

    if (wmax <= DCAP) {
        float4 ad = make_float4(0.f, 0.f, 0.f, 0.f);
        if (valid) ad = ((const float4*)a_dst)[n];
        float d0 = 0.f, d1 = 0.f, d2 = 0.f, d3 = 0.f;
        uint2* nslab = slab + g * (4 * DCAP);
        for (int k = i; k < deg; k += 16) {
            int s = esrc[start + k];
            float4 a = ((const float4*)a_src)[s];
            float e0 = a.x + ad.x; e0 = fmaxf(e0, SLOPE * e0); float x0 = __expf(e0);
            float e1 = a.y + ad.y; e1 = fmaxf(e1, SLOPE * e1); float x1 = __expf(e1);
            float e2 = a.z + ad.z; e2 = fmaxf(e2, SLOPE * e2); float x2 = __expf(e2);
            float e3 = a.w + ad.w; e3 = fmaxf(e3, SLOPE * e3); float x3 = __expf(e3);
            nslab[0 * DCAP + k] = make_uint2((unsigned)s, __float_as_uint(x0));
            nslab[1 * DCAP + k] = make_uint2((unsigned)s, __float_as_uint(x1));
            nslab[2 * DCAP + k] = make_uint2((unsigned)s, __float_as_uint(x2));
            nslab[3 * DCAP + k] = make_uint2((unsigned)s, __float_as_uint(x3));
            d0 += x0; d1 += x1; d2 += x2; d3 += x3;
        }
#pragma unroll
        for (int m = 1; m < 16; m <<= 1) {  // in-group reduction
            d0 += __shfl_xor(d0, m);
            d1 += __shfl_xor(d1, m);
            d2 += __shfl_xor(d2, m);
            d3 += __shfl_xor(d3, m);
        }
        float dh = myhead == 0 ? d0 : myhead == 1 ? d1 : myhead == 2 ? d2 : d3;
        float inv = 1.f / (dh + 1e-16f);
        wave_lds_fence();

        float acc[8];
#pragma unroll
        for (int k = 0; k < 8; k++) acc[k] = 0.f;
        const uint2* myrow = nslab + myhead * DCAP;
        for (int j = 0; j < deg; j++) {  // deg uniform within group; no shuffles inside
            uint2 p = myrow[j];
            float al = __uint_as_float(p.y) * inv;
            uint4 uu = *(const uint4*)(hb + (size_t)p.x * 128 + i * 8);
            acc[0] += bf_lo(uu.x) * al; acc[1] += bf_hi(uu.x) * al;
            acc[2] += bf_lo(uu.y) * al; acc[3] += bf_hi(uu.y) * al;
            acc[4] += bf_lo(uu.z) * al; acc[5] += bf_hi(uu.z) * al;
            acc[6] += bf_lo(uu.w) * al; acc[7] += bf_hi(uu.w) * al;
        }
        if (valid) {
            float y[8];
            float sum = 0.f;
            const float4* bp = (const float4*)(bias + i * 8);
            float4 b0 = bp[0], b1 = bp[1];
#pragma unroll
            for (int k = 0; k < 8; k++) {
                float b = k < 4 ? (&b0.x)[k] : (&b1.x)[k - 4];
                y[k] = acc[k] + b;
                sum += y[k];
            }
#pragma unroll
            for (int m = 1; m < 16; m <<= 1) sum += __shfl_xor(sum, m);
            float mu = sum * (1.f / 128.f);
            float ss = 0.f;
            float d[8];
#pragma unroll
            for (int k = 0; k < 8; k++) { d[k] = y[k] - mu; ss += d[k] * d[k]; }
#pragma unroll
            for (int m = 1; m < 16; m <<= 1) ss += __shfl_xor(ss, m);
            float is = rsqrtf(ss * (1.f / 128.f) + 1e-5f);
            const float4* gp = (const float4*)(gamma + i * 8);
            const float4* ep = (const float4*)(beta + i * 8);
            float4 g0 = gp[0], g1 = gp[1], e0 = ep[0], e1 = ep[1];
            unsigned short o16[8];
#pragma unroll
            for (int k = 0; k < 8; k++) {
                float gm = k < 4 ? (&g0.x)[k] : (&g1.x)[k - 4];
                float bt = k < 4 ? (&e0.x)[k] : (&e1.x)[k - 4];
                float z = gm * (d[k] * is) + bt;
                o16[k] = f2bf(z > 0.f ? z : __expf(z) - 1.f);
            }
            *(uint4*)(xb + (size_t)n * 128 + i * 8) = *(uint4*)o16;
        }
    } else {
        // cold path (~never): process the wave's 4 nodes sequentially, full-wave,
        // R6-verified clamped-shuffle scheme.
        for (int m4 = 0; m4 < 4; m4++) {
            int nm = n0 + m4;
            if (nm >= NN) continue;
            int startm = row_ptr[nm];
            int endm = (nm == NN - 1) ? ETOT : row_ptr[nm + 1];
            int degm = endm - startm;
            float4 ad = ((const float4*)a_dst)[nm];
            int gg = lane >> 4, c16 = lane & 15, hh = c16 >> 2;
            float acc[8];
#pragma unroll
            for (int k = 0; k < 8; k++) acc[k] = 0.f;
            if (degm <= 64) {
                int msrc = 0;
                float me0 = 0.f, me1 = 0.f, me2 = 0.f, me3 = 0.f;
                if (lane < degm) {
                    int s = esrc[startm + lane];
                    msrc = s;
                    float4 a = ((const float4*)a_src)[s];
                    float e0 = a.x + ad.x; e0 = fmaxf(e0, SLOPE * e0); me0 = __expf(e0);
                    float e1 = a.y + ad.y; e1 = fmaxf(e1, SLOPE * e1); me1 = __expf(e1);
                    float e2 = a.z + ad.z; e2 = fmaxf(e2, SLOPE * e2); me2 = __expf(e2);
                    float e3 = a.w + ad.w; e3 = fmaxf(e3, SLOPE * e3); me3 = __expf(e3);
                }
                float d0 = me0, d1 = me1, d2 = me2, d3 = me3;
#pragma unroll
                for (int m = 1; m < 64; m <<= 1) {
                    d0 += __shfl_xor(d0, m);
                    d1 += __shfl_xor(d1, m);
                    d2 += __shfl_xor(d2, m);
                    d3 += __shfl_xor(d3, m);
                }
                me0 *= 1.f / (d0 + 1e-16f);
                me1 *= 1.f / (d1 + 1e-16f);
                me2 *= 1.f / (d2 + 1e-16f);
                me3 *= 1.f / (d3 + 1e-16f);
                int iters = (degm + 3) >> 2;
                for (int it = 0; it < iters; it++) {
                    int j = gg + (it << 2);
                    int jj = j < degm ? j : 0;
                    int s = __shfl(msrc, jj);
                    float a0 = __shfl(me0, jj), a1 = __shfl(me1, jj);
                    float a2 = __shfl(me2, jj), a3 = __shfl(me3, jj);
                    if (j < degm) {
                        float al = hh == 0 ? a0 : hh == 1 ? a1 : hh == 2 ? a2 : a3;
                        uint4 uu = *(const uint4*)(hb + (size_t)s * 128 + c16 * 8);
                        acc[0] += bf_lo(uu.x) * al; acc[1] += bf_hi(uu.x) * al;
                        acc[2] += bf_lo(uu.y) * al; acc[3] += bf_hi(uu.y) * al;
                        acc[4] += bf_lo(uu.z) * al; acc[5] += bf_hi(uu.z) * al;
                        acc[6] += bf_lo(uu.w) * al; acc[7] += bf_hi(uu.w) * al;
                    }
                }
            } else {
                float d0 = 0.f, d1 = 0.f, d2 = 0.f, d3 = 0.f;
                for (int k = startm + lane; k < endm; k += 64) {
                    int s = esrc[k];
                    float4 a = ((const float4*)a_src)[s];
                    float e0 = a.x + ad.x; e0 = fmaxf(e0, SLOPE * e0); d0 += __expf(e0);
                    float e1 = a.y + ad.y; e1 = fmaxf(e1, SLOPE * e1); d1 += __expf(e1);
                    float e2 = a.z + ad.z; e2 = fmaxf(e2, SLOPE * e2); d2 += __expf(e2);
                    float e3 = a.w + ad.w; e3 = fmaxf(e3, SLOPE * e3); d3 += __expf(e3);
                }
#pragma unroll
                for (int m = 1; m < 64; m <<= 1) {
                    d0 += __shfl_xor(d0, m);
                    d1 += __shfl_xor(d1, m);
                    d2 += __shfl_xor(d2, m);
                    d3 += __shfl_xor(d3, m);
                }
                float invh = hh == 0 ? 1.f / (d0 + 1e-16f) : hh == 1 ? 1.f / (d1 + 1e-16f)
                           : hh == 2 ? 1.f / (d2 + 1e-16f) : 1.f / (d3 + 1e-16f);
                float adh = hh == 0 ? ad.x : hh == 1 ? ad.y : hh == 2 ? ad.z : ad.w;
                for (int j = gg; j < degm; j += 4) {
                    int s = esrc[startm + j];
                    float e = a_src[(size_t)s * 4 + hh] + adh;
                    e = fmaxf(e, SLOPE * e);
                    float al = __expf(e) * invh;
                    uint4 uu = *(const uint4*)(hb + (size_t)s * 128 + c16 * 8);
                    acc[0] += bf_lo(uu.x) * al; acc[1] += bf_hi(uu.x) * al;
                    acc[2] += bf_lo(uu.y) * al; acc[3] += bf_hi(uu.y) * al;
                    acc[4] += bf_lo(uu.z) * al; acc[5] += bf_hi(uu.z) * al;
                    acc[6] += bf_lo(uu.w) * al; acc[7] += bf_hi(uu.w) * al;
                }
            }
#pragma unroll
            for (int k = 0; k < 8; k++) {
                acc[k] += __shfl_xor(acc[k], 16);
                acc[k] += __shfl_xor(acc[k], 32);
            }
            if (lane < 16) {
                float y[8];
                float sum = 0.f;
                const float4* bp = (const float4*)(bias + lane * 8);
                float4 b0 = bp[0], b1 = bp[1];
#pragma unroll
                for (int k = 0; k < 8; k++) {
                    float b = k < 4 ? (&b0.x)[k] : (&b1.x)[k - 4];
                    y[k] = acc[k] + b;
                    sum += y[k];
                }
#pragma unroll
                for (int m = 1; m < 16; m <<= 1) sum += __shfl_xor(sum, m);
                float mu = sum * (1.f / 128.f);
                float ss = 0.f;
                float d[8];
#pragma unroll
                for (int k = 0; k < 8; k++) { d[k] = y[k] - mu; ss += d[k] * d[k]; }
#pragma unroll
                for (int m = 1; m < 16; m <<= 1) ss += __shfl_xor(ss, m);
                float is = rsqrtf(ss * (1.f / 128.f) + 1e-5f);
                const float4* gp = (const float4*)(gamma + lane * 8);
                const float4* ep = (const float4*)(beta + lane * 8);
                float4 g0 = gp[0], g1 = gp[1], e0 = ep[0], e1 = ep[1];
                unsigned short o16[8];
#pragma unroll
                for (int k = 0; k < 8; k++) {
                    float gm = k < 4 ? (&g0.x)[k] : (&g1.x)[k - 4];
                    float bt = k < 4 ? (&e0.x)[k] : (&e1.x)[k - 4];
                    float z = gm * (d[k] * is) + bt;
                    o16[k] = f2bf(z > 0.f ? z : __expf(z) - 1.f);
                }
                *(uint4*)(xb + (size_t)nm * 128 + lane * 8) = *(uint4*)o16;
            }
        }
    }
}

// -------- final layer, wave-per-node: H=1, C=32 (bf16 h), writes fp32 d_out --------
__global__ __launch_bounds__(256) void k_agg_final(
    const unsigned short* __restrict__ hb, const float* __restrict__ a_src,
    const float* __restrict__ a_dst, const int* __restrict__ row_ptr,
    const int* __restrict__ esrc, const float* __restrict__ bf,
    float* __restrict__ out) {
    __shared__ uint2 slab_all[4][64];
    int lane = threadIdx.x & 63;
    int w = threadIdx.x >> 6;
    uint2* slab = slab_all[w];
    int n = blockIdx.x * 4 + w;
    if (n >= NN) return;
    int start = row_ptr[n];
    int end = (n == NN - 1) ? ETOT : row_ptr[n + 1];
    int deg = end - start;
    float adn = a_dst[n];

    int g = lane >> 3, c8 = lane & 7;
    float acc[4] = {0.f, 0.f, 0.f, 0.f};

    if (deg <= 64) {
        int msrc = 0;
        float me = 0.f;
        if (lane < deg) {
            int s = esrc[start + lane];
            msrc = s;
            float e = a_src[s] + adn;
            e = fmaxf(e, SLOPE * e);
            me = __expf(e);
        }
        float d = me;
#pragma unroll
        for (int m = 1; m < 64; m <<= 1) d += __shfl_xor(d, m);
        me *= 1.f / (d + 1e-16f);
        if (lane < deg) slab[lane] = make_uint2((unsigned)msrc, __float_as_uint(me));
        wave_lds_fence();
        int iters = (deg + 7) >> 3;
        for (int it = 0; it < iters; it++) {
            int j = g + (it << 3);
            if (j < deg) {
                uint2 p = slab[j];
                int s = (int)p.x;
                float al = __uint_as_float(p.y);
                uint2 u = *(const uint2*)(hb + (size_t)s * 32 + c8 * 4);
                acc[0] += bf_lo(u.x) * al; acc[1] += bf_hi(u.x) * al;
                acc[2] += bf_lo(u.y) * al; acc[3] += bf_hi(u.y) * al;
            }
        }
    } else {
        float d = 0.f;
        for (int k = start + lane; k < end; k += 64) {
            int s = esrc[k];
            float e = a_src[s] + adn;
            e = fmaxf(e, SLOPE * e);
            d += __expf(e);
        }
#pragma unroll
        for (int m = 1; m < 64; m <<= 1) d += __shfl_xor(d, m);
        float inv = 1.f / (d + 1e-16f);
        for (int j = g; j < deg; j += 8) {
            int s = esrc[start + j];
            float e = a_src[s] + adn;
            e = fmaxf(e, SLOPE * e);
            float al = __expf(e) * inv;
            uint2 u = *(const uint2*)(hb + (size_t)s * 32 + c8 * 4);
            acc[0] += bf_lo(u.x) * al; acc[1] += bf_hi(u.x) * al;
            acc[2] += bf_lo(u.y) * al; acc[3] += bf_hi(u.y) * al;
        }
    }
#pragma unroll
    for (int k = 0; k < 4; k++) {
        acc[k] += __shfl_xor(acc[k], 8);
        acc[k] += __shfl_xor(acc[k], 16);
        acc[k] += __shfl_xor(acc[k], 32);
    }
    if (lane < 8) {
        float4 b4 = ((const float4*)bf)[lane];
        float4 o = make_float4(acc[0] + b4.x, acc[1] + b4.y, acc[2] + b4.z,
                               acc[3] + b4.w);
        ((float4*)out)[(size_t)n * 8 + lane] = o;
    }
}

// ---------------- launch ----------------
extern "C" void kernel_launch(void* const* d_in, const int* in_sizes, int n_in,
                              void* d_out, int out_size, void* d_ws,
                              size_t ws_size, hipStream_t stream) {
    const float* x  = (const float*)d_in[0];
    const int* ei   = (const int*)d_in[1];
    const float* W[3]  = {(const float*)d_in[2], (const float*)d_in[8],  (const float*)d_in[14]};
    const float* AS[3] = {(const float*)d_in[3], (const float*)d_in[9],  (const float*)d_in[15]};
    const float* AD[3] = {(const float*)d_in[4], (const float*)d_in[10], (const float*)d_in[16]};
    const float* Bb[3] = {(const float*)d_in[5], (const float*)d_in[11], (const float*)d_in[17]};
    const float* G[3]  = {(const float*)d_in[6], (const float*)d_in[12], (const float*)d_in[18]};
    const float* BE[3] = {(const float*)d_in[7], (const float*)d_in[13], (const float*)d_in[19]};
    const float* Wf  = (const float*)d_in[20];
    const float* asf = (const float*)d_in[21];
    const float* adf = (const float*)d_in[22];
    const float* bfp = (const float*)d_in[23];
    float* out = (float*)d_out;

    unsigned short* xb = (unsigned short*)d_ws;          // NN*128 bf16 (layer0 uses [NN][64])
    unsigned short* hb = xb + (size_t)NN * 128;          // NN*128 bf16
    float* a_s = (float*)(hb + (size_t)NN * 128);
    float* a_d = a_s + (size_t)NN * 4;
    int* row_ptr = (int*)(a_d + (size_t)NN * 4);
    int* esrc    = row_ptr + NN;
    int* gbh     = esrc + ETOT;
    int* ebase   = gbh + NB;
    int* gcur    = ebase + NB + 1;
    int* pbuf    = gcur + NB;                            // EE ints
    unsigned short* Wt0 = (unsigned short*)(pbuf + EE);  // 128*64
    unsigned short* Wt1 = Wt0 + 128 * 64;                // 128*128
    unsigned short* Wt2 = Wt1 + 128 * 128;               // 128*128
    unsigned short* Wtf = Wt2 + 128 * 128;               // 32*128

    // dtype prep
    k_cvt_x<<<(NN * 64 / 8 + 255) / 256, 256, 0, stream>>>(x, xb);
    k_cvt_wt<<<(64 * 128 + 255) / 256, 256, 0, stream>>>(W[0], Wt0, 64, 128);
    k_cvt_wt<<<(128 * 128 + 255) / 256, 256, 0, stream>>>(W[1], Wt1, 128, 128);
    k_cvt_wt<<<(128 * 128 + 255) / 256, 256, 0, stream>>>(W[2], Wt2, 128, 128);
    k_cvt_wt<<<(128 * 32 + 255) / 256, 256, 0, stream>>>(Wf, Wtf, 128, 32);

    // CSR build
    k_zero<<<1, 128, 0, stream>>>(gbh, NB);
    k_bhist<<<(EE + 2047) / 2048, 256, 0, stream>>>(ei, gbh);
    k_bscan<<<1, 128, 0, stream>>>(gbh, ebase, gcur);
    k_bscatter<<<(EE + CCH - 1) / CCH, 256, 0, stream>>>(ei, gcur, pbuf);
    k_bcsr<<<NB, 256, 0, stream>>>(pbuf, ebase, row_ptr, esrc);

    // layers
    const unsigned short* Wts[3] = {Wt0, Wt1, Wt2};
    int K = 64;
    int gblk = (NN + 127) / 128;
    for (int l = 0; l < 3; l++) {
        k_mfma_att<128, 4><<<gblk, 256, 0, stream>>>(xb, Wts[l], AS[l], AD[l],
                                                     hb, a_s, a_d, NN, K);
        k_aggregate_ln<<<(NN + 15) / 16, 256, 0, stream>>>(hb, a_s, a_d, row_ptr,
                                                           esrc, Bb[l], G[l], BE[l], xb);
        K = 128;
    }
    k_mfma_att<32, 1><<<gblk, 256, 0, stream>>>(xb, Wtf, asf, adf, hb, a_s, a_d,
                                                NN, 128);
    k_agg_final<<<(NN + 3) / 4, 256, 0, stream>>>(hb, a_s, a_d, row_ptr, esrc,
                                                  bfp, out);
}

// Round 10
// 554.765 us; speedup vs baseline: 2.0819x; 1.0106x over previous
//
#include <hip/hip_runtime.h>
#include <hip/hip_bf16.h>

constexpr int NN   = 100000;
constexpr int EE   = 1600000;
constexpr int ETOT = EE + NN;
constexpr float SLOPE = 0.2f;
constexpr int BSH = 10;     // nodes per bucket = 1024
constexpr int NB  = (NN + (1 << BSH) - 1) >> BSH;  // 98 buckets
constexpr int CCH = 8192;   // edges per scatter block
constexpr int DCAP  = 36;   // per-node edge cap for packed path (P(Poisson(16)+1>36)~2e-7)
constexpr int DCAPP = 37;   // padded stride: head stride 74dw%32=10, node stride 296dw%32=8
                            // -> phase-B read banks 8g+10h+2j all-distinct (conflict-free)

typedef __attribute__((ext_vector_type(8))) short short8;
typedef __attribute__((ext_vector_type(4))) float f32x4;

__device__ __forceinline__ float bf_lo(unsigned u) { return __uint_as_float(u << 16); }
__device__ __forceinline__ float bf_hi(unsigned u) { return __uint_as_float(u & 0xffff0000u); }
__device__ __forceinline__ unsigned short f2bf(float f) {
    __hip_bfloat16 h = __float2bfloat16(f);
    return *(unsigned short*)&h;
}
// wave-local LDS RAW ordering: DS pipe is in-order per wave; wait + compiler barrier
__device__ __forceinline__ void wave_lds_fence() {
    __asm__ volatile("s_waitcnt lgkmcnt(0)" ::: "memory");
}

// ---------------- dtype conversions ----------------
__global__ void k_cvt_x(const float* __restrict__ x, unsigned short* __restrict__ xb) {
    int i = blockIdx.x * blockDim.x + threadIdx.x;   // 8 floats per thread
    if (i >= NN * 64 / 8) return;
    const float4* xp = (const float4*)(x + (size_t)i * 8);
    float4 v0 = xp[0], v1 = xp[1];
    unsigned short o[8] = {f2bf(v0.x), f2bf(v0.y), f2bf(v0.z), f2bf(v0.w),
                           f2bf(v1.x), f2bf(v1.y), f2bf(v1.z), f2bf(v1.w)};
    *(uint4*)(xb + (size_t)i * 8) = *(uint4*)o;
}

// W [K][N] fp32 -> Wt [N][K] bf16
__global__ void k_cvt_wt(const float* __restrict__ W, unsigned short* __restrict__ Wt,
                         int K, int N) {
    int i = blockIdx.x * blockDim.x + threadIdx.x;
    if (i >= K * N) return;
    int k = i / N, n = i % N;
    Wt[(size_t)n * K + k] = f2bf(W[i]);
}

// ---------------- bucketed CSR build ----------------
__global__ void k_zero(int* p, int n) {
    int i = blockIdx.x * blockDim.x + threadIdx.x;
    if (i < n) p[i] = 0;
}

__global__ __launch_bounds__(256) void k_bhist(const int* __restrict__ ei,
                                               int* __restrict__ gbh) {
    __shared__ int h[NB];
    int t = threadIdx.x;
    if (t < NB) h[t] = 0;
    __syncthreads();
    int i = blockIdx.x * 2048 + t;
#pragma unroll
    for (int k = 0; k < 8; k++, i += 256)
        if (i < EE) atomicAdd(&h[ei[EE + i] >> BSH], 1);
    __syncthreads();
    if (t < NB && h[t]) atomicAdd(&gbh[t], h[t]);
}

__global__ void k_bscan(const int* __restrict__ gbh, int* __restrict__ ebase,
                        int* __restrict__ gcur) {
    __shared__ int sd[128];
    int t = threadIdx.x;
    int v = (t < NB) ? gbh[t] : 0;
    sd[t] = v;
    __syncthreads();
    for (int off = 1; off < 128; off <<= 1) {
        int x = (t >= off) ? sd[t - off] : 0;
        __syncthreads();
        sd[t] += x;
        __syncthreads();
    }
    int ex = sd[t] - v;
    if (t < NB) { ebase[t] = ex; gcur[t] = ex; }
    if (t == NB) ebase[NB] = EE;
}

__global__ __launch_bounds__(256) void k_bscatter(const int* __restrict__ ei,
                                                  int* __restrict__ gcur,
                                                  int* __restrict__ pbuf) {
    __shared__ int h[NB], base[NB], cur[NB];
    int t = threadIdx.x;
    if (t < NB) { h[t] = 0; cur[t] = 0; }
    __syncthreads();
    int c0 = blockIdx.x * CCH;
    int cend = c0 + CCH < EE ? c0 + CCH : EE;
    for (int i = c0 + t; i < cend; i += 256)
        atomicAdd(&h[ei[EE + i] >> BSH], 1);
    __syncthreads();
    if (t < NB && h[t] > 0) base[t] = atomicAdd(&gcur[t], h[t]);
    __syncthreads();
    for (int i = c0 + t; i < cend; i += 256) {
        int s = ei[i], d = ei[EE + i];
        int b = d >> BSH;
        int c = atomicAdd(&cur[b], 1);
        pbuf[base[b] + c] = s | ((d & ((1 << BSH) - 1)) << 17);
    }
}

__global__ __launch_bounds__(256) void k_bcsr(const int* __restrict__ pbuf,
                                              const int* __restrict__ ebase,
                                              int* __restrict__ row_ptr,
                                              int* __restrict__ esrc) {
    constexpr int BNODES = 1 << BSH;
    __shared__ int hist[BNODES];
    __shared__ int cur[BNODES];
    __shared__ int sd[256];
    int b = blockIdx.x, t = threadIdx.x;
    int node0 = b << BSH;
    int e0 = ebase[b], e1 = ebase[b + 1];
    for (int i = t; i < BNODES; i += 256) { hist[i] = 0; cur[i] = 0; }
    __syncthreads();
    for (int i = e0 + t; i < e1; i += 256)
        atomicAdd(&hist[pbuf[i] >> 17], 1);
    __syncthreads();
    int s0 = hist[4 * t], s1 = hist[4 * t + 1], s2 = hist[4 * t + 2], s3 = hist[4 * t + 3];
    int ts = s0 + s1 + s2 + s3;
    sd[t] = ts;
    __syncthreads();
    for (int off = 1; off < 256; off <<= 1) {
        int x = (t >= off) ? sd[t - off] : 0;
        __syncthreads();
        sd[t] += x;
        __syncthreads();
    }
    int ex = sd[t] - ts;
    hist[4 * t] = ex;
    hist[4 * t + 1] = ex + s0;
    hist[4 * t + 2] = ex + s0 + s1;
    hist[4 * t + 3] = ex + s0 + s1 + s2;
    __syncthreads();
    int rbase = e0 + node0;
    for (int nl = t; nl < BNODES; nl += 256) {
        int n = node0 + nl;
        if (n < NN) {
            int rp = rbase + hist[nl] + nl;
            row_ptr[n] = rp;
            esrc[rp] = n;  // self loop in slot 0
        }
    }
    __syncthreads();
    for (int i = e0 + t; i < e1; i += 256) {
        int p = pbuf[i];
        int nl = p >> 17;
        int c = atomicAdd(&cur[nl], 1);
        esrc[rbase + hist[nl] + nl + 1 + c] = p & 0x1FFFF;
    }
}

// ------- bf16 MFMA GEMM (128xBN tile, BN = full width) + fused att dots + bf16 h -------
template <int BN, int H>
__global__ __launch_bounds__(256) void k_mfma_att(
    const unsigned short* __restrict__ Ab, const unsigned short* __restrict__ Bt,
    const float* __restrict__ as_, const float* __restrict__ ad_,
    unsigned short* __restrict__ hb, float* __restrict__ a_s,
    float* __restrict__ a_d, int M, int K) {
    constexpr int NCT = BN / 16;
    constexpr int LDK = 72;  // 64-slab + 8-short pad
    __shared__ unsigned short As[128 * LDK];
    __shared__ unsigned short Bs[BN * LDK];
    int tid = threadIdx.x;
    int lane = tid & 63, w = tid >> 6;
    int q = lane >> 4, col = lane & 15;
    int rowBase = blockIdx.x * 128;

    f32x4 acc[2][NCT];
#pragma unroll
    for (int rt = 0; rt < 2; rt++)
#pragma unroll
        for (int ct = 0; ct < NCT; ct++) acc[rt][ct] = (f32x4){0.f, 0.f, 0.f, 0.f};

    int u = tid & 7;
    int r0 = tid >> 3;
    int nph = K >> 6;
    for (int ph = 0; ph < nph; ph++) {
        int kof = ph * 64 + u * 8;
#pragma unroll
        for (int rr = r0; rr < 128; rr += 32) {
            int gr = rowBase + rr;
            uint4 v = make_uint4(0, 0, 0, 0);
            if (gr < M) v = *(const uint4*)(Ab + (size_t)gr * K + kof);
            *(uint4*)(&As[rr * LDK + u * 8]) = v;
        }
#pragma unroll
        for (int br = r0; br < BN; br += 32) {
            uint4 v = *(const uint4*)(Bt + (size_t)br * K + kof);
            *(uint4*)(&Bs[br * LDK + u * 8]) = v;
        }
        __syncthreads();

        short8 af[2][2];
#pragma unroll
        for (int rt = 0; rt < 2; rt++)
#pragma unroll
            for (int kt = 0; kt < 2; kt++)
                af[rt][kt] = *(const short8*)(&As[(w * 32 + rt * 16 + col) * LDK + kt * 32 + q * 8]);
#pragma unroll
        for (int kt = 0; kt < 2; kt++)
#pragma unroll
            for (int ct = 0; ct < NCT; ct++) {
                short8 bf = *(const short8*)(&Bs[(ct * 16 + col) * LDK + kt * 32 + q * 8]);
#pragma unroll
                for (int rt = 0; rt < 2; rt++)
                    acc[rt][ct] = __builtin_amdgcn_mfma_f32_16x16x32_bf16(
                        af[rt][kt], bf, acc[rt][ct], 0, 0, 0);
            }
        __syncthreads();
    }

    float swv[NCT], dwv[NCT];
#pragma unroll
    for (int ct = 0; ct < NCT; ct++) {
        int c = ct * 16 + col;
        swv[ct] = as_[c];
        dwv[ct] = ad_[c];
    }
#pragma unroll
    for (int rt = 0; rt < 2; rt++) {
#pragma unroll
        for (int r = 0; r < 4; r++) {
            int gr = rowBase + w * 32 + rt * 16 + q * 4 + r;
            if constexpr (H == 4) {
                float ps[4] = {0, 0, 0, 0}, pd[4] = {0, 0, 0, 0};
#pragma unroll
                for (int ct = 0; ct < NCT; ct++) {
                    float v = acc[rt][ct][r];
                    ps[ct >> 1] += v * swv[ct];
                    pd[ct >> 1] += v * dwv[ct];
                }
#pragma unroll
                for (int m = 1; m < 16; m <<= 1)
#pragma unroll
                    for (int h = 0; h < 4; h++) {
                        ps[h] += __shfl_xor(ps[h], m);
                        pd[h] += __shfl_xor(pd[h], m);
                    }
                if (gr < M) {
#pragma unroll
                    for (int ct = 0; ct < NCT; ct++)
                        hb[(size_t)gr * BN + ct * 16 + col] = f2bf(acc[rt][ct][r]);
                    if (col == 0) {
                        *(float4*)(a_s + (size_t)gr * 4) = make_float4(ps[0], ps[1], ps[2], ps[3]);
                        *(float4*)(a_d + (size_t)gr * 4) = make_float4(pd[0], pd[1], pd[2], pd[3]);
                    }
                }
            } else {
                float ps = 0.f, pd = 0.f;
#pragma unroll
                for (int ct = 0; ct < NCT; ct++) {
                    float v = acc[rt][ct][r];
                    ps += v * swv[ct];
                    pd += v * dwv[ct];
                }
#pragma unroll
                for (int m = 1; m < 16; m <<= 1) {
                    ps += __shfl_xor(ps, m);
                    pd += __shfl_xor(pd, m);
                }
                if (gr < M) {
#pragma unroll
                    for (int ct = 0; ct < NCT; ct++)
                        hb[(size_t)gr * BN + ct * 16 + col] = f2bf(acc[rt][ct][r]);
                    if (col == 0) { a_s[gr] = ps; a_d[gr] = pd; }
                }
            }
        }
    }
}

// -------- 4-nodes-per-wave: softmax + aggregate(bf16 h) + bias + LN + ELU -> bf16 x --------
// 16-lane group g owns node n0+g. Slab layout [node][head][j] with padded strides
// (DCAPP=37) making phase-B ds_read_b64 conflict-free (banks 8g+10h+2j distinct)
// and phase-A writes 2-way (free). 18.9 KB LDS -> 8 blocks/CU (100% occ cap).
__global__ __launch_bounds__(256) void k_aggregate_ln(
    const unsigned short* __restrict__ hb, const float* __restrict__ a_src,
    const float* __restrict__ a_dst, const int* __restrict__ row_ptr,
    const int* __restrict__ esrc, const float* __restrict__ bias,
    const float* __restrict__ gamma, const float* __restrict__ beta,
    unsigned short* __restrict__ xb) {
    __shared__ uint2 slab_all[4][4 * 4 * DCAPP];  // [wave][node][head][j]
    int tid = threadIdx.x;
    int w = tid >> 6, lane = tid & 63;
    int g = lane >> 4, i = lane & 15;
    int myhead = i >> 2;
    uint2* slab = slab_all[w];
    int n0 = blockIdx.x * 16 + w * 4;
    int n = n0 + g;
    bool valid = n < NN;
    int start = 0, deg = 0;
    if (valid) {
        start = row_ptr[n];
        int end = (n == NN - 1) ? ETOT : row_ptr[n + 1];
        deg = end - start;
    }
    // wave-wide max degree (uniform branch selector)
    int wmax = deg;
#pragma unroll
    for (int m = 1; m < 64; m <<= 1) wmax = max(wmax, __shfl_xor(wmax, m));

    if (wmax <= DCAP) {
        float4 ad = make_float4(0.f, 0.f, 0.f, 0.f);
        if (valid) ad = ((const float4*)a_dst)[n];
        float d0 = 0.f, d1 = 0.f, d2 = 0.f, d3 = 0.f;
        uint2* nslab = slab + g * (4 * DCAPP);
        for (int k = i; k < deg; k += 16) {
            int s = esrc[start + k];
            float4 a = ((const float4*)a_src)[s];
            float e0 = a.x + ad.x; e0 = fmaxf(e0, SLOPE * e0); float x0 = __expf(e0);
            float e1 = a.y + ad.y; e1 = fmaxf(e1, SLOPE * e1); float x1 = __expf(e1);
            float e2 = a.z + ad.z; e2 = fmaxf(e2, SLOPE * e2); float x2 = __expf(e2);
            float e3 = a.w + ad.w; e3 = fmaxf(e3, SLOPE * e3); float x3 = __expf(e3);
            nslab[0 * DCAPP + k] = make_uint2((unsigned)s, __float_as_uint(x0));
            nslab[1 * DCAPP + k] = make_uint2((unsigned)s, __float_as_uint(x1));
            nslab[2 * DCAPP + k] = make_uint2((unsigned)s, __float_as_uint(x2));
            nslab[3 * DCAPP + k] = make_uint2((unsigned)s, __float_as_uint(x3));
            d0 += x0; d1 += x1; d2 += x2; d3 += x3;
        }
#pragma unroll
        for (int m = 1; m < 16; m <<= 1) {  // in-group reduction
            d0 += __shfl_xor(d0, m);
            d1 += __shfl_xor(d1, m);
            d2 += __shfl_xor(d2, m);
            d3 += __shfl_xor(d3, m);
        }
        float dh = myhead == 0 ? d0 : myhead == 1 ? d1 : myhead == 2 ? d2 : d3;
        float inv = 1.f / (dh + 1e-16f);
        wave_lds_fence();

        float acc[8];
#pragma unroll
        for (int k = 0; k < 8; k++) acc[k] = 0.f;
        const uint2* myrow = nslab + myhead * DCAPP;
        for (int j = 0; j < deg; j++) {  // deg uniform within group; j uniform per iter
            uint2 p = myrow[j];
            float al = __uint_as_float(p.y) * inv;
            uint4 uu = *(const uint4*)(hb + (size_t)p.x * 128 + i * 8);
            acc[0] += bf_lo(uu.x) * al; acc[1] += bf_hi(uu.x) * al;
            acc[2] += bf_lo(uu.y) * al; acc[3] += bf_hi(uu.y) * al;
            acc[4] += bf_lo(uu.z) * al; acc[5] += bf_hi(uu.z) * al;
            acc[6] += bf_lo(uu.w) * al; acc[7] += bf_hi(uu.w) * al;
        }
        if (valid) {
            float y[8];
            float sum = 0.f;
            const float4* bp = (const float4*)(bias + i * 8);
            float4 b0 = bp[0], b1 = bp[1];
#pragma unroll
            for (int k = 0; k < 8; k++) {
                float b = k < 4 ? (&b0.x)[k] : (&b1.x)[k - 4];
                y[k] = acc[k] + b;
                sum += y[k];
            }
#pragma unroll
            for (int m = 1; m < 16; m <<= 1) sum += __shfl_xor(sum, m);
            float mu = sum * (1.f / 128.f);
            float ss = 0.f;
            float d[8];
#pragma unroll
            for (int k = 0; k < 8; k++) { d[k] = y[k] - mu; ss += d[k] * d[k]; }
#pragma unroll
            for (int m = 1; m < 16; m <<= 1) ss += __shfl_xor(ss, m);
            float is = rsqrtf(ss * (1.f / 128.f) + 1e-5f);
            const float4* gp = (const float4*)(gamma + i * 8);
            const float4* ep = (const float4*)(beta + i * 8);
            float4 g0 = gp[0], g1 = gp[1], e0 = ep[0], e1 = ep[1];
            unsigned short o16[8];
#pragma unroll
            for (int k = 0; k < 8; k++) {
                float gm = k < 4 ? (&g0.x)[k] : (&g1.x)[k - 4];
                float bt = k < 4 ? (&e0.x)[k] : (&e1.x)[k - 4];
                float z = gm * (d[k] * is) + bt;
                o16[k] = f2bf(z > 0.f ? z : __expf(z) - 1.f);
            }
            *(uint4*)(xb + (size_t)n * 128 + i * 8) = *(uint4*)o16;
        }
    } else {
        // cold path (~never): process the wave's 4 nodes sequentially, full-wave,
        // R6-verified clamped-shuffle scheme.
        for (int m4 = 0; m4 < 4; m4++) {
            int nm = n0 + m4;
            if (nm >= NN) continue;
            int startm = row_ptr[nm];
            int endm = (nm == NN - 1) ? ETOT : row_ptr[nm + 1];
            int degm = endm - startm;
            float4 ad = ((const float4*)a_dst)[nm];
            int gg = lane >> 4, c16 = lane & 15, hh = c16 >> 2;
            float acc[8];
#pragma unroll
            for (int k = 0; k < 8; k++) acc[k] = 0.f;
            if (degm <= 64) {
                int msrc = 0;
                float me0 = 0.f, me1 = 0.f, me2 = 0.f, me3 = 0.f;
                if (lane < degm) {
                    int s = esrc[startm + lane];
                    msrc = s;
                    float4 a = ((const float4*)a_src)[s];
                    float e0 = a.x + ad.x; e0 = fmaxf(e0, SLOPE * e0); me0 = __expf(e0);
                    float e1 = a.y + ad.y; e1 = fmaxf(e1, SLOPE * e1); me1 = __expf(e1);
                    float e2 = a.z + ad.z; e2 = fmaxf(e2, SLOPE * e2); me2 = __expf(e2);
                    float e3 = a.w + ad.w; e3 = fmaxf(e3, SLOPE * e3); me3 = __expf(e3);
                }
                float d0 = me0, d1 = me1, d2 = me2, d3 = me3;
#pragma unroll
                for (int m = 1; m < 64; m <<= 1) {
                    d0 += __shfl_xor(d0, m);
                    d1 += __shfl_xor(d1, m);
                    d2 += __shfl_xor(d2, m);
                    d3 += __shfl_xor(d3, m);
                }
                me0 *= 1.f / (d0 + 1e-16f);
                me1 *= 1.f / (d1 + 1e-16f);
                me2 *= 1.f / (d2 + 1e-16f);
                me3 *= 1.f / (d3 + 1e-16f);
                int iters = (degm + 3) >> 2;
                for (int it = 0; it < iters; it++) {
                    int j = gg + (it << 2);
                    int jj = j < degm ? j : 0;
                    int s = __shfl(msrc, jj);
                    float a0 = __shfl(me0, jj), a1 = __shfl(me1, jj);
                    float a2 = __shfl(me2, jj), a3 = __shfl(me3, jj);
                    if (j < degm) {
                        float al = hh == 0 ? a0 : hh == 1 ? a1 : hh == 2 ? a2 : a3;
                        uint4 uu = *(const uint4*)(hb + (size_t)s * 128 + c16 * 8);
                        acc[0] += bf_lo(uu.x) * al; acc[1] += bf_hi(uu.x) * al;
                        acc[2] += bf_lo(uu.y) * al; acc[3] += bf_hi(uu.y) * al;
                        acc[4] += bf_lo(uu.z) * al; acc[5] += bf_hi(uu.z) * al;
                        acc[6] += bf_lo(uu.w) * al; acc[7] += bf_hi(uu.w) * al;
                    }
                }
            } else {
                float d0 = 0.f, d1 = 0.f, d2 = 0.f, d3 = 0.f;
                for (int k = startm + lane; k < endm; k += 64) {
                    int s = esrc[k];
                    float4 a = ((const float4*)a_src)[s];
                    float e0 = a.x + ad.x; e0 = fmaxf(e0, SLOPE * e0); d0 += __expf(e0);
                    float e1 = a.y + ad.y; e1 = fmaxf(e1, SLOPE * e1); d1 += __expf(e1);
                    float e2 = a.z + ad.z; e2 = fmaxf(e2, SLOPE * e2); d2 += __expf(e2);
                    float e3 = a.w + ad.w; e3 = fmaxf(e3, SLOPE * e3); d3 += __expf(e3);
                }
#pragma unroll
                for (int m = 1; m < 64; m <<= 1) {
                    d0 += __shfl_xor(d0, m);
                    d1 += __shfl_xor(d1, m);
                    d2 += __shfl_xor(d2, m);
                    d3 += __shfl_xor(d3, m);
                }
                float invh = hh == 0 ? 1.f / (d0 + 1e-16f) : hh == 1 ? 1.f / (d1 + 1e-16f)
                           : hh == 2 ? 1.f / (d2 + 1e-16f) : 1.f / (d3 + 1e-16f);
                float adh = hh == 0 ? ad.x : hh == 1 ? ad.y : hh == 2 ? ad.z : ad.w;
                for (int j = gg; j < degm; j += 4) {
                    int s = esrc[startm + j];
                    float e = a_src[(size_t)s * 4 + hh] + adh;
                    e = fmaxf(e, SLOPE * e);
                    float al = __expf(e) * invh;
                    uint4 uu = *(const uint4*)(hb + (size_t)s * 128 + c16 * 8);
                    acc[0] += bf_lo(uu.x) * al; acc[1] += bf_hi(uu.x) * al;
                    acc[2] += bf_lo(uu.y) * al; acc[3] += bf_hi(uu.y) * al;
                    acc[4] += bf_lo(uu.z) * al; acc[5] += bf_hi(uu.z) * al;
                    acc[6] += bf_lo(uu.w) * al; acc[7] += bf_hi(uu.w) * al;
                }
            }
#pragma unroll
            for (int k = 0; k < 8; k++) {
                acc[k] += __shfl_xor(acc[k], 16);
                acc[k] += __shfl_xor(acc[k], 32);
            }
            if (lane < 16) {
                float y[8];
                float sum = 0.f;
                const float4* bp = (const float4*)(bias + lane * 8);
                float4 b0 = bp[0], b1 = bp[1];
#pragma unroll
                for (int k = 0; k < 8; k++) {
                    float b = k < 4 ? (&b0.x)[k] : (&b1.x)[k - 4];
                    y[k] = acc[k] + b;
                    sum += y[k];
                }
#pragma unroll
                for (int m = 1; m < 16; m <<= 1) sum += __shfl_xor(sum, m);
                float mu = sum * (1.f / 128.f);
                float ss = 0.f;
                float d[8];
#pragma unroll
                for (int k = 0; k < 8; k++) { d[k] = y[k] - mu; ss += d[k] * d[k]; }
#pragma unroll
                for (int m = 1; m < 16; m <<= 1) ss += __shfl_xor(ss, m);
                float is = rsqrtf(ss * (1.f / 128.f) + 1e-5f);
                const float4* gp = (const float4*)(gamma + lane * 8);
                const float4* ep = (const float4*)(beta + lane * 8);
                float4 g0 = gp[0], g1 = gp[1], e0 = ep[0], e1 = ep[1];
                unsigned short o16[8];
#pragma unroll
                for (int k = 0; k < 8; k++) {
                    float gm = k < 4 ? (&g0.x)[k] : (&g1.x)[k - 4];
                    float bt = k < 4 ? (&e0.x)[k] : (&e1.x)[k - 4];
                    float z = gm * (d[k] * is) + bt;
                    o16[k] = f2bf(z > 0.f ? z : __expf(z) - 1.f);
                }
                *(uint4*)(xb + (size_t)nm * 128 + lane * 8) = *(uint4*)o16;
            }
        }
    }
}

// -------- final layer, wave-per-node: H=1, C=32 (bf16 h), writes fp32 d_out --------
__global__ __launch_bounds__(256) void k_agg_final(
    const unsigned short* __restrict__ hb, const float* __restrict__ a_src,
    const float* __restrict__ a_dst, const int* __restrict__ row_ptr,
    const int* __restrict__ esrc, const float* __restrict__ bf,
    float* __restrict__ out) {
    __shared__ uint2 slab_all[4][64];
    int lane = threadIdx.x & 63;
    int w = threadIdx.x >> 6;
    uint2* slab = slab_all[w];
    int n = blockIdx.x * 4 + w;
    if (n >= NN) return;
    int start = row_ptr[n];
    int end = (n == NN - 1) ? ETOT : row_ptr[n + 1];
    int deg = end - start;
    float adn = a_dst[n];

    int g = lane >> 3, c8 = lane & 7;
    float acc[4] = {0.f, 0.f, 0.f, 0.f};

    if (deg <= 64) {
        int msrc = 0;
        float me = 0.f;
        if (lane < deg) {
            int s = esrc[start + lane];
            msrc = s;
            float e = a_src[s] + adn;
            e = fmaxf(e, SLOPE * e);
            me = __expf(e);
        }
        float d = me;
#pragma unroll
        for (int m = 1; m < 64; m <<= 1) d += __shfl_xor(d, m);
        me *= 1.f / (d + 1e-16f);
        if (lane < deg) slab[lane] = make_uint2((unsigned)msrc, __float_as_uint(me));
        wave_lds_fence();
        int iters = (deg + 7) >> 3;
        for (int it = 0; it < iters; it++) {
            int j = g + (it << 3);
            if (j < deg) {
                uint2 p = slab[j];
                int s = (int)p.x;
                float al = __uint_as_float(p.y);
                uint2 u = *(const uint2*)(hb + (size_t)s * 32 + c8 * 4);
                acc[0] += bf_lo(u.x) * al; acc[1] += bf_hi(u.x) * al;
                acc[2] += bf_lo(u.y) * al; acc[3] += bf_hi(u.y) * al;
            }
        }
    } else {
        float d = 0.f;
        for (int k = start + lane; k < end; k += 64) {
            int s = esrc[k];
            float e = a_src[s] + adn;
            e = fmaxf(e, SLOPE * e);
            d += __expf(e);
        }
#pragma unroll
        for (int m = 1; m < 64; m <<= 1) d += __shfl_xor(d, m);
        float inv = 1.f / (d + 1e-16f);
        for (int j = g; j < deg; j += 8) {
            int s = esrc[start + j];
            float e = a_src[s] + adn;
            e = fmaxf(e, SLOPE * e);
            float al = __expf(e) * inv;
            uint2 u = *(const uint2*)(hb + (size_t)s * 32 + c8 * 4);
            acc[0] += bf_lo(u.x) * al; acc[1] += bf_hi(u.x) * al;
            acc[2] += bf_lo(u.y) * al; acc[3] += bf_hi(u.y) * al;
        }
    }
#pragma unroll
    for (int k = 0; k < 4; k++) {
        acc[k] += __shfl_xor(acc[k], 8);
        acc[k] += __shfl_xor(acc[k], 16);
        acc[k] += __shfl_xor(acc[k], 32);
    }
    if (lane < 8) {
        float4 b4 = ((const float4*)bf)[lane];
        float4 o = make_float4(acc[0] + b4.x, acc[1] + b4.y, acc[2] + b4.z,
                               acc[3] + b4.w);
        ((float4*)out)[(size_t)n * 8 + lane] = o;
    }
}

// ---------------- launch ----------------
extern "C" void kernel_launch(void* const* d_in, const int* in_sizes, int n_in,
                              void* d_out, int out_size, void* d_ws,
                              size_t ws_size, hipStream_t stream) {
    const float* x  = (const float*)d_in[0];
    const int* ei   = (const int*)d_in[1];
    const float* W[3]  = {(const float*)d_in[2], (const float*)d_in[8],  (const float*)d_in[14]};
    const float* AS[3] = {(const float*)d_in[3], (const float*)d_in[9],  (const float*)d_in[15]};
    const float* AD[3] = {(const float*)d_in[4], (const float*)d_in[10], (const float*)d_in[16]};
    const float* Bb[3] = {(const float*)d_in[5], (const float*)d_in[11], (const float*)d_in[17]};
    const float* G[3]  = {(const float*)d_in[6], (const float*)d_in[12], (const float*)d_in[18]};
    const float* BE[3] = {(const float*)d_in[7], (const float*)d_in[13], (const float*)d_in[19]};
    const float* Wf  = (const float*)d_in[20];
    const float* asf = (const float*)d_in[21];
    const float* adf = (const float*)d_in[22];
    const float* bfp = (const float*)d_in[23];
    float* out = (float*)d_out;

    unsigned short* xb = (unsigned short*)d_ws;          // NN*128 bf16 (layer0 uses [NN][64])
    unsigned short* hb = xb + (size_t)NN * 128;          // NN*128 bf16
    float* a_s = (float*)(hb + (size_t)NN * 128);
    float* a_d = a_s + (size_t)NN * 4;
    int* row_ptr = (int*)(a_d + (size_t)NN * 4);
    int* esrc    = row_ptr + NN;
    int* gbh     = esrc + ETOT;
    int* ebase   = gbh + NB;
    int* gcur    = ebase + NB + 1;
    int* pbuf    = gcur + NB;                            // EE ints
    unsigned short* Wt0 = (unsigned short*)(pbuf + EE);  // 128*64
    unsigned short* Wt1 = Wt0 + 128 * 64;                // 128*128
    unsigned short* Wt2 = Wt1 + 128 * 128;               // 128*128
    unsigned short* Wtf = Wt2 + 128 * 128;               // 32*128

    // dtype prep
    k_cvt_x<<<(NN * 64 / 8 + 255) / 256, 256, 0, stream>>>(x, xb);
    k_cvt_wt<<<(64 * 128 + 255) / 256, 256, 0, stream>>>(W[0], Wt0, 64, 128);
    k_cvt_wt<<<(128 * 128 + 255) / 256, 256, 0, stream>>>(W[1], Wt1, 128, 128);
    k_cvt_wt<<<(128 * 128 + 255) / 256, 256, 0, stream>>>(W[2], Wt2, 128, 128);
    k_cvt_wt<<<(128 * 32 + 255) / 256, 256, 0, stream>>>(Wf, Wtf, 128, 32);

    // CSR build
    k_zero<<<1, 128, 0, stream>>>(gbh, NB);
    k_bhist<<<(EE + 2047) / 2048, 256, 0, stream>>>(ei, gbh);
    k_bscan<<<1, 128, 0, stream>>>(gbh, ebase, gcur);
    k_bscatter<<<(EE + CCH - 1) / CCH, 256, 0, stream>>>(ei, gcur, pbuf);
    k_bcsr<<<NB, 256, 0, stream>>>(pbuf, ebase, row_ptr, esrc);

    // layers
    const unsigned short* Wts[3] = {Wt0, Wt1, Wt2};
    int K = 64;
    int gblk = (NN + 127) / 128;
    for (int l = 0; l < 3; l++) {
        k_mfma_att<128, 4><<<gblk, 256, 0, stream>>>(xb, Wts[l], AS[l], AD[l],
                                                     hb, a_s, a_d, NN, K);
        k_aggregate_ln<<<(NN + 15) / 16, 256, 0, stream>>>(hb, a_s, a_d, row_ptr,
                                                           esrc, Bb[l], G[l], BE[l], xb);
        K = 128;
    }
    k_mfma_att<32, 1><<<gblk, 256, 0, stream>>>(xb, Wtf, asf, adf, hb, a_s, a_d,
                                                NN, 128);
    k_agg_final<<<(NN + 3) / 4, 256, 0, stream>>>(hb, a_s, a_d, row_ptr, esrc,
                                                  bfp, out);
}

// Round 11
// 547.448 us; speedup vs baseline: 2.1097x; 1.0134x over previous
//
#include <hip/hip_runtime.h>
#include <hip/hip_bf16.h>

constexpr int NN   = 100000;
constexpr int EE   = 1600000;
constexpr int ETOT = EE + NN;
constexpr float SLOPE = 0.2f;
constexpr int BSH = 10;     // nodes per bucket = 1024
constexpr int NB  = (NN + (1 << BSH) - 1) >> BSH;  // 98 buckets
constexpr int CCH = 8192;   // edges per scatter block
constexpr int DCAP  = 36;   // per-node edge cap for packed path (P(Poisson(16)+1>36)~2e-7)
constexpr int DCAPP = 37;   // padded stride -> phase-B reads conflict-free (see R10)

typedef __attribute__((ext_vector_type(8))) short short8;
typedef __attribute__((ext_vector_type(4))) float f32x4;

__device__ __forceinline__ float bf_lo(unsigned u) { return __uint_as_float(u << 16); }
__device__ __forceinline__ float bf_hi(unsigned u) { return __uint_as_float(u & 0xffff0000u); }
__device__ __forceinline__ unsigned short f2bf(float f) {
    __hip_bfloat16 h = __float2bfloat16(f);
    return *(unsigned short*)&h;
}
// wave-local LDS RAW ordering: DS pipe is in-order per wave; wait + compiler barrier
__device__ __forceinline__ void wave_lds_fence() {
    __asm__ volatile("s_waitcnt lgkmcnt(0)" ::: "memory");
}
__device__ __forceinline__ void fma8(float* acc, uint4 u, float al) {
    acc[0] += bf_lo(u.x) * al; acc[1] += bf_hi(u.x) * al;
    acc[2] += bf_lo(u.y) * al; acc[3] += bf_hi(u.y) * al;
    acc[4] += bf_lo(u.z) * al; acc[5] += bf_hi(u.z) * al;
    acc[6] += bf_lo(u.w) * al; acc[7] += bf_hi(u.w) * al;
}
__device__ __forceinline__ void fma4(float* acc, uint2 u, float al) {
    acc[0] += bf_lo(u.x) * al; acc[1] += bf_hi(u.x) * al;
    acc[2] += bf_lo(u.y) * al; acc[3] += bf_hi(u.y) * al;
}

// ---------------- dtype conversions ----------------
__global__ void k_cvt_x(const float* __restrict__ x, unsigned short* __restrict__ xb) {
    int i = blockIdx.x * blockDim.x + threadIdx.x;   // 8 floats per thread
    if (i >= NN * 64 / 8) return;
    const float4* xp = (const float4*)(x + (size_t)i * 8);
    float4 v0 = xp[0], v1 = xp[1];
    unsigned short o[8] = {f2bf(v0.x), f2bf(v0.y), f2bf(v0.z), f2bf(v0.w),
                           f2bf(v1.x), f2bf(v1.y), f2bf(v1.z), f2bf(v1.w)};
    *(uint4*)(xb + (size_t)i * 8) = *(uint4*)o;
}

// W [K][N] fp32 -> Wt [N][K] bf16
__global__ void k_cvt_wt(const float* __restrict__ W, unsigned short* __restrict__ Wt,
                         int K, int N) {
    int i = blockIdx.x * blockDim.x + threadIdx.x;
    if (i >= K * N) return;
    int k = i / N, n = i % N;
    Wt[(size_t)n * K + k] = f2bf(W[i]);
}

// ---------------- bucketed CSR build ----------------
__global__ void k_zero(int* p, int n) {
    int i = blockIdx.x * blockDim.x + threadIdx.x;
    if (i < n) p[i] = 0;
}

__global__ __launch_bounds__(256) void k_bhist(const int* __restrict__ ei,
                                               int* __restrict__ gbh) {
    __shared__ int h[NB];
    int t = threadIdx.x;
    if (t < NB) h[t] = 0;
    __syncthreads();
    int i = blockIdx.x * 2048 + t;
#pragma unroll
    for (int k = 0; k < 8; k++, i += 256)
        if (i < EE) atomicAdd(&h[ei[EE + i] >> BSH], 1);
    __syncthreads();
    if (t < NB && h[t]) atomicAdd(&gbh[t], h[t]);
}

__global__ void k_bscan(const int* __restrict__ gbh, int* __restrict__ ebase,
                        int* __restrict__ gcur) {
    __shared__ int sd[128];
    int t = threadIdx.x;
    int v = (t < NB) ? gbh[t] : 0;
    sd[t] = v;
    __syncthreads();
    for (int off = 1; off < 128; off <<= 1) {
        int x = (t >= off) ? sd[t - off] : 0;
        __syncthreads();
        sd[t] += x;
        __syncthreads();
    }
    int ex = sd[t] - v;
    if (t < NB) { ebase[t] = ex; gcur[t] = ex; }
    if (t == NB) ebase[NB] = EE;
}

__global__ __launch_bounds__(256) void k_bscatter(const int* __restrict__ ei,
                                                  int* __restrict__ gcur,
                                                  int* __restrict__ pbuf) {
    __shared__ int h[NB], base[NB], cur[NB];
    int t = threadIdx.x;
    if (t < NB) { h[t] = 0; cur[t] = 0; }
    __syncthreads();
    int c0 = blockIdx.x * CCH;
    int cend = c0 + CCH < EE ? c0 + CCH : EE;
    for (int i = c0 + t; i < cend; i += 256)
        atomicAdd(&h[ei[EE + i] >> BSH], 1);
    __syncthreads();
    if (t < NB && h[t] > 0) base[t] = atomicAdd(&gcur[t], h[t]);
    __syncthreads();
    for (int i = c0 + t; i < cend; i += 256) {
        int s = ei[i], d = ei[EE + i];
        int b = d >> BSH;
        int c = atomicAdd(&cur[b], 1);
        pbuf[base[b] + c] = s | ((d & ((1 << BSH) - 1)) << 17);
    }
}

__global__ __launch_bounds__(256) void k_bcsr(const int* __restrict__ pbuf,
                                              const int* __restrict__ ebase,
                                              int* __restrict__ row_ptr,
                                              int* __restrict__ esrc) {
    constexpr int BNODES = 1 << BSH;
    __shared__ int hist[BNODES];
    __shared__ int cur[BNODES];
    __shared__ int sd[256];
    int b = blockIdx.x, t = threadIdx.x;
    int node0 = b << BSH;
    int e0 = ebase[b], e1 = ebase[b + 1];
    for (int i = t; i < BNODES; i += 256) { hist[i] = 0; cur[i] = 0; }
    __syncthreads();
    for (int i = e0 + t; i < e1; i += 256)
        atomicAdd(&hist[pbuf[i] >> 17], 1);
    __syncthreads();
    int s0 = hist[4 * t], s1 = hist[4 * t + 1], s2 = hist[4 * t + 2], s3 = hist[4 * t + 3];
    int ts = s0 + s1 + s2 + s3;
    sd[t] = ts;
    __syncthreads();
    for (int off = 1; off < 256; off <<= 1) {
        int x = (t >= off) ? sd[t - off] : 0;
        __syncthreads();
        sd[t] += x;
        __syncthreads();
    }
    int ex = sd[t] - ts;
    hist[4 * t] = ex;
    hist[4 * t + 1] = ex + s0;
    hist[4 * t + 2] = ex + s0 + s1;
    hist[4 * t + 3] = ex + s0 + s1 + s2;
    __syncthreads();
    int rbase = e0 + node0;
    for (int nl = t; nl < BNODES; nl += 256) {
        int n = node0 + nl;
        if (n < NN) {
            int rp = rbase + hist[nl] + nl;
            row_ptr[n] = rp;
            esrc[rp] = n;  // self loop in slot 0
        }
    }
    __syncthreads();
    for (int i = e0 + t; i < e1; i += 256) {
        int p = pbuf[i];
        int nl = p >> 17;
        int c = atomicAdd(&cur[nl], 1);
        esrc[rbase + hist[nl] + nl + 1 + c] = p & 0x1FFFF;
    }
}

// ------- bf16 MFMA GEMM (128xBN tile, BN = full width) + fused att dots + bf16 h -------
template <int BN, int H>
__global__ __launch_bounds__(256) void k_mfma_att(
    const unsigned short* __restrict__ Ab, const unsigned short* __restrict__ Bt,
    const float* __restrict__ as_, const float* __restrict__ ad_,
    unsigned short* __restrict__ hb, float* __restrict__ a_s,
    float* __restrict__ a_d, int M, int K) {
    constexpr int NCT = BN / 16;
    constexpr int LDK = 72;  // 64-slab + 8-short pad
    __shared__ unsigned short As[128 * LDK];
    __shared__ unsigned short Bs[BN * LDK];
    int tid = threadIdx.x;
    int lane = tid & 63, w = tid >> 6;
    int q = lane >> 4, col = lane & 15;
    int rowBase = blockIdx.x * 128;

    f32x4 acc[2][NCT];
#pragma unroll
    for (int rt = 0; rt < 2; rt++)
#pragma unroll
        for (int ct = 0; ct < NCT; ct++) acc[rt][ct] = (f32x4){0.f, 0.f, 0.f, 0.f};

    int u = tid & 7;
    int r0 = tid >> 3;
    int nph = K >> 6;
    for (int ph = 0; ph < nph; ph++) {
        int kof = ph * 64 + u * 8;
#pragma unroll
        for (int rr = r0; rr < 128; rr += 32) {
            int gr = rowBase + rr;
            uint4 v = make_uint4(0, 0, 0, 0);
            if (gr < M) v = *(const uint4*)(Ab + (size_t)gr * K + kof);
            *(uint4*)(&As[rr * LDK + u * 8]) = v;
        }
#pragma unroll
        for (int br = r0; br < BN; br += 32) {
            uint4 v = *(const uint4*)(Bt + (size_t)br * K + kof);
            *(uint4*)(&Bs[br * LDK + u * 8]) = v;
        }
        __syncthreads();

        short8 af[2][2];
#pragma unroll
        for (int rt = 0; rt < 2; rt++)
#pragma unroll
            for (int kt = 0; kt < 2; kt++)
                af[rt][kt] = *(const short8*)(&As[(w * 32 + rt * 16 + col) * LDK + kt * 32 + q * 8]);
#pragma unroll
        for (int kt = 0; kt < 2; kt++)
#pragma unroll
            for (int ct = 0; ct < NCT; ct++) {
                short8 bf = *(const short8*)(&Bs[(ct * 16 + col) * LDK + kt * 32 + q * 8]);
#pragma unroll
                for (int rt = 0; rt < 2; rt++)
                    acc[rt][ct] = __builtin_amdgcn_mfma_f32_16x16x32_bf16(
                        af[rt][kt], bf, acc[rt][ct], 0, 0, 0);
            }
        __syncthreads();
    }

    float swv[NCT], dwv[NCT];
#pragma unroll
    for (int ct = 0; ct < NCT; ct++) {
        int c = ct * 16 + col;
        swv[ct] = as_[c];
        dwv[ct] = ad_[c];
    }
#pragma unroll
    for (int rt = 0; rt < 2; rt++) {
#pragma unroll
        for (int r = 0; r < 4; r++) {
            int gr = rowBase + w * 32 + rt * 16 + q * 4 + r;
            if constexpr (H == 4) {
                float ps[4] = {0, 0, 0, 0}, pd[4] = {0, 0, 0, 0};
#pragma unroll
                for (int ct = 0; ct < NCT; ct++) {
                    float v = acc[rt][ct][r];
                    ps[ct >> 1] += v * swv[ct];
                    pd[ct >> 1] += v * dwv[ct];
                }
#pragma unroll
                for (int m = 1; m < 16; m <<= 1)
#pragma unroll
                    for (int h = 0; h < 4; h++) {
                        ps[h] += __shfl_xor(ps[h], m);
                        pd[h] += __shfl_xor(pd[h], m);
                    }
                if (gr < M) {
#pragma unroll
                    for (int ct = 0; ct < NCT; ct++)
                        hb[(size_t)gr * BN + ct * 16 + col] = f2bf(acc[rt][ct][r]);
                    if (col == 0) {
                        *(float4*)(a_s + (size_t)gr * 4) = make_float4(ps[0], ps[1], ps[2], ps[3]);
                        *(float4*)(a_d + (size_t)gr * 4) = make_float4(pd[0], pd[1], pd[2], pd[3]);
                    }
                }
            } else {
                float ps = 0.f, pd = 0.f;
#pragma unroll
                for (int ct = 0; ct < NCT; ct++) {
                    float v = acc[rt][ct][r];
                    ps += v * swv[ct];
                    pd += v * dwv[ct];
                }
#pragma unroll
                for (int m = 1; m < 16; m <<= 1) {
                    ps += __shfl_xor(ps, m);
                    pd += __shfl_xor(pd, m);
                }
                if (gr < M) {
#pragma unroll
                    for (int ct = 0; ct < NCT; ct++)
                        hb[(size_t)gr * BN + ct * 16 + col] = f2bf(acc[rt][ct][r]);
                    if (col == 0) { a_s[gr] = ps; a_d[gr] = pd; }
                }
            }
        }
    }
}

// -------- 4-nodes-per-wave: softmax + aggregate(bf16 h) + bias + LN + ELU -> bf16 x --------
// 16-lane group g owns node n0+g. Slab [node][head][j], DCAPP=37 padding (conflict-free).
// Phase B: 4-wide load batching (4 global_load_dwordx4 in flight per lane) + softmax
// division hoisted out of the loop (Σα·h = inv·Σexp·h).
__global__ __launch_bounds__(256) void k_aggregate_ln(
    const unsigned short* __restrict__ hb, const float* __restrict__ a_src,
    const float* __restrict__ a_dst, const int* __restrict__ row_ptr,
    const int* __restrict__ esrc, const float* __restrict__ bias,
    const float* __restrict__ gamma, const float* __restrict__ beta,
    unsigned short* __restrict__ xb) {
    __shared__ uint2 slab_all[4][4 * 4 * DCAPP];  // [wave][node][head][j]
    int tid = threadIdx.x;
    int w = tid >> 6, lane = tid & 63;
    int g = lane >> 4, i = lane & 15;
    int myhead = i >> 2;
    uint2* slab = slab_all[w];
    int n0 = blockIdx.x * 16 + w * 4;
    int n = n0 + g;
    bool valid = n < NN;
    int start = 0, deg = 0;
    if (valid) {
        start = row_ptr[n];
        int end = (n == NN - 1) ? ETOT : row_ptr[n + 1];
        deg = end - start;
    }
    // wave-wide max degree (uniform branch selector)
    int wmax = deg;
#pragma unroll
    for (int m = 1; m < 64; m <<= 1) wmax = max(wmax, __shfl_xor(wmax, m));

    if (wmax <= DCAP) {
        float4 ad = make_float4(0.f, 0.f, 0.f, 0.f);
        if (valid) ad = ((const float4*)a_dst)[n];
        float d0 = 0.f, d1 = 0.f, d2 = 0.f, d3 = 0.f;
        uint2* nslab = slab + g * (4 * DCAPP);
        for (int k = i; k < deg; k += 16) {
            int s = esrc[start + k];
            float4 a = ((const float4*)a_src)[s];
            float e0 = a.x + ad.x; e0 = fmaxf(e0, SLOPE * e0); float x0 = __expf(e0);
            float e1 = a.y + ad.y; e1 = fmaxf(e1, SLOPE * e1); float x1 = __expf(e1);
            float e2 = a.z + ad.z; e2 = fmaxf(e2, SLOPE * e2); float x2 = __expf(e2);
            float e3 = a.w + ad.w; e3 = fmaxf(e3, SLOPE * e3); float x3 = __expf(e3);
            nslab[0 * DCAPP + k] = make_uint2((unsigned)s, __float_as_uint(x0));
            nslab[1 * DCAPP + k] = make_uint2((unsigned)s, __float_as_uint(x1));
            nslab[2 * DCAPP + k] = make_uint2((unsigned)s, __float_as_uint(x2));
            nslab[3 * DCAPP + k] = make_uint2((unsigned)s, __float_as_uint(x3));
            d0 += x0; d1 += x1; d2 += x2; d3 += x3;
        }
#pragma unroll
        for (int m = 1; m < 16; m <<= 1) {  // in-group reduction
            d0 += __shfl_xor(d0, m);
            d1 += __shfl_xor(d1, m);
            d2 += __shfl_xor(d2, m);
            d3 += __shfl_xor(d3, m);
        }
        float dh = myhead == 0 ? d0 : myhead == 1 ? d1 : myhead == 2 ? d2 : d3;
        float inv = 1.f / (dh + 1e-16f);
        wave_lds_fence();

        float acc[8];
#pragma unroll
        for (int k = 0; k < 8; k++) acc[k] = 0.f;
        const uint2* myrow = nslab + myhead * DCAPP;
        const unsigned short* hbase = hb + i * 8;
        int j = 0;
        for (; j + 4 <= deg; j += 4) {  // 4 independent gathers in flight
            uint2 p0 = myrow[j], p1 = myrow[j + 1], p2 = myrow[j + 2], p3 = myrow[j + 3];
            uint4 u0 = *(const uint4*)(hbase + (size_t)p0.x * 128);
            uint4 u1 = *(const uint4*)(hbase + (size_t)p1.x * 128);
            uint4 u2 = *(const uint4*)(hbase + (size_t)p2.x * 128);
            uint4 u3 = *(const uint4*)(hbase + (size_t)p3.x * 128);
            fma8(acc, u0, __uint_as_float(p0.y));
            fma8(acc, u1, __uint_as_float(p1.y));
            fma8(acc, u2, __uint_as_float(p2.y));
            fma8(acc, u3, __uint_as_float(p3.y));
        }
        for (; j < deg; j++) {
            uint2 p = myrow[j];
            uint4 uu = *(const uint4*)(hbase + (size_t)p.x * 128);
            fma8(acc, uu, __uint_as_float(p.y));
        }
#pragma unroll
        for (int k = 0; k < 8; k++) acc[k] *= inv;  // softmax denom applied once

        if (valid) {
            float y[8];
            float sum = 0.f;
            const float4* bp = (const float4*)(bias + i * 8);
            float4 b0 = bp[0], b1 = bp[1];
#pragma unroll
            for (int k = 0; k < 8; k++) {
                float b = k < 4 ? (&b0.x)[k] : (&b1.x)[k - 4];
                y[k] = acc[k] + b;
                sum += y[k];
            }
#pragma unroll
            for (int m = 1; m < 16; m <<= 1) sum += __shfl_xor(sum, m);
            float mu = sum * (1.f / 128.f);
            float ss = 0.f;
            float d[8];
#pragma unroll
            for (int k = 0; k < 8; k++) { d[k] = y[k] - mu; ss += d[k] * d[k]; }
#pragma unroll
            for (int m = 1; m < 16; m <<= 1) ss += __shfl_xor(ss, m);
            float is = rsqrtf(ss * (1.f / 128.f) + 1e-5f);
            const float4* gp = (const float4*)(gamma + i * 8);
            const float4* ep = (const float4*)(beta + i * 8);
            float4 g0 = gp[0], g1 = gp[1], e0 = ep[0], e1 = ep[1];
            unsigned short o16[8];
#pragma unroll
            for (int k = 0; k < 8; k++) {
                float gm = k < 4 ? (&g0.x)[k] : (&g1.x)[k - 4];
                float bt = k < 4 ? (&e0.x)[k] : (&e1.x)[k - 4];
                float z = gm * (d[k] * is) + bt;
                o16[k] = f2bf(z > 0.f ? z : __expf(z) - 1.f);
            }
            *(uint4*)(xb + (size_t)n * 128 + i * 8) = *(uint4*)o16;
        }
    } else {
        // cold path (~never): process the wave's 4 nodes sequentially, full-wave,
        // R6-verified clamped-shuffle scheme.
        for (int m4 = 0; m4 < 4; m4++) {
            int nm = n0 + m4;
            if (nm >= NN) continue;
            int startm = row_ptr[nm];
            int endm = (nm == NN - 1) ? ETOT : row_ptr[nm + 1];
            int degm = endm - startm;
            float4 ad = ((const float4*)a_dst)[nm];
            int gg = lane >> 4, c16 = lane & 15, hh = c16 >> 2;
            float acc[8];
#pragma unroll
            for (int k = 0; k < 8; k++) acc[k] = 0.f;
            if (degm <= 64) {
                int msrc = 0;
                float me0 = 0.f, me1 = 0.f, me2 = 0.f, me3 = 0.f;
                if (lane < degm) {
                    int s = esrc[startm + lane];
                    msrc = s;
                    float4 a = ((const float4*)a_src)[s];
                    float e0 = a.x + ad.x; e0 = fmaxf(e0, SLOPE * e0); me0 = __expf(e0);
                    float e1 = a.y + ad.y; e1 = fmaxf(e1, SLOPE * e1); me1 = __expf(e1);
                    float e2 = a.z + ad.z; e2 = fmaxf(e2, SLOPE * e2); me2 = __expf(e2);
                    float e3 = a.w + ad.w; e3 = fmaxf(e3, SLOPE * e3); me3 = __expf(e3);
                }
                float d0 = me0, d1 = me1, d2 = me2, d3 = me3;
#pragma unroll
                for (int m = 1; m < 64; m <<= 1) {
                    d0 += __shfl_xor(d0, m);
                    d1 += __shfl_xor(d1, m);
                    d2 += __shfl_xor(d2, m);
                    d3 += __shfl_xor(d3, m);
                }
                me0 *= 1.f / (d0 + 1e-16f);
                me1 *= 1.f / (d1 + 1e-16f);
                me2 *= 1.f / (d2 + 1e-16f);
                me3 *= 1.f / (d3 + 1e-16f);
                int iters = (degm + 3) >> 2;
                for (int it = 0; it < iters; it++) {
                    int j = gg + (it << 2);
                    int jj = j < degm ? j : 0;
                    int s = __shfl(msrc, jj);
                    float a0 = __shfl(me0, jj), a1 = __shfl(me1, jj);
                    float a2 = __shfl(me2, jj), a3 = __shfl(me3, jj);
                    if (j < degm) {
                        float al = hh == 0 ? a0 : hh == 1 ? a1 : hh == 2 ? a2 : a3;
                        uint4 uu = *(const uint4*)(hb + (size_t)s * 128 + c16 * 8);
                        fma8(acc, uu, al);
                    }
                }
            } else {
                float d0 = 0.f, d1 = 0.f, d2 = 0.f, d3 = 0.f;
                for (int k = startm + lane; k < endm; k += 64) {
                    int s = esrc[k];
                    float4 a = ((const float4*)a_src)[s];
                    float e0 = a.x + ad.x; e0 = fmaxf(e0, SLOPE * e0); d0 += __expf(e0);
                    float e1 = a.y + ad.y; e1 = fmaxf(e1, SLOPE * e1); d1 += __expf(e1);
                    float e2 = a.z + ad.z; e2 = fmaxf(e2, SLOPE * e2); d2 += __expf(e2);
                    float e3 = a.w + ad.w; e3 = fmaxf(e3, SLOPE * e3); d3 += __expf(e3);
                }
#pragma unroll
                for (int m = 1; m < 64; m <<= 1) {
                    d0 += __shfl_xor(d0, m);
                    d1 += __shfl_xor(d1, m);
                    d2 += __shfl_xor(d2, m);
                    d3 += __shfl_xor(d3, m);
                }
                float invh = hh == 0 ? 1.f / (d0 + 1e-16f) : hh == 1 ? 1.f / (d1 + 1e-16f)
                           : hh == 2 ? 1.f / (d2 + 1e-16f) : 1.f / (d3 + 1e-16f);
                float adh = hh == 0 ? ad.x : hh == 1 ? ad.y : hh == 2 ? ad.z : ad.w;
                for (int j = gg; j < degm; j += 4) {
                    int s = esrc[startm + j];
                    float e = a_src[(size_t)s * 4 + hh] + adh;
                    e = fmaxf(e, SLOPE * e);
                    float al = __expf(e) * invh;
                    uint4 uu = *(const uint4*)(hb + (size_t)s * 128 + c16 * 8);
                    fma8(acc, uu, al);
                }
            }
#pragma unroll
            for (int k = 0; k < 8; k++) {
                acc[k] += __shfl_xor(acc[k], 16);
                acc[k] += __shfl_xor(acc[k], 32);
            }
            if (lane < 16) {
                float y[8];
                float sum = 0.f;
                const float4* bp = (const float4*)(bias + lane * 8);
                float4 b0 = bp[0], b1 = bp[1];
#pragma unroll
                for (int k = 0; k < 8; k++) {
                    float b = k < 4 ? (&b0.x)[k] : (&b1.x)[k - 4];
                    y[k] = acc[k] + b;
                    sum += y[k];
                }
#pragma unroll
                for (int m = 1; m < 16; m <<= 1) sum += __shfl_xor(sum, m);
                float mu = sum * (1.f / 128.f);
                float ss = 0.f;
                float d[8];
#pragma unroll
                for (int k = 0; k < 8; k++) { d[k] = y[k] - mu; ss += d[k] * d[k]; }
#pragma unroll
                for (int m = 1; m < 16; m <<= 1) ss += __shfl_xor(ss, m);
                float is = rsqrtf(ss * (1.f / 128.f) + 1e-5f);
                const float4* gp = (const float4*)(gamma + lane * 8);
                const float4* ep = (const float4*)(beta + lane * 8);
                float4 g0 = gp[0], g1 = gp[1], e0 = ep[0], e1 = ep[1];
                unsigned short o16[8];
#pragma unroll
                for (int k = 0; k < 8; k++) {
                    float gm = k < 4 ? (&g0.x)[k] : (&g1.x)[k - 4];
                    float bt = k < 4 ? (&e0.x)[k] : (&e1.x)[k - 4];
                    float z = gm * (d[k] * is) + bt;
                    o16[k] = f2bf(z > 0.f ? z : __expf(z) - 1.f);
                }
                *(uint4*)(xb + (size_t)nm * 128 + lane * 8) = *(uint4*)o16;
            }
        }
    }
}

// -------- final layer, wave-per-node: H=1, C=32 (bf16 h), writes fp32 d_out --------
__global__ __launch_bounds__(256) void k_agg_final(
    const unsigned short* __restrict__ hb, const float* __restrict__ a_src,
    const float* __restrict__ a_dst, const int* __restrict__ row_ptr,
    const int* __restrict__ esrc, const float* __restrict__ bf,
    float* __restrict__ out) {
    __shared__ uint2 slab_all[4][64];
    int lane = threadIdx.x & 63;
    int w = threadIdx.x >> 6;
    uint2* slab = slab_all[w];
    int n = blockIdx.x * 4 + w;
    if (n >= NN) return;
    int start = row_ptr[n];
    int end = (n == NN - 1) ? ETOT : row_ptr[n + 1];
    int deg = end - start;
    float adn = a_dst[n];

    int g = lane >> 3, c8 = lane & 7;
    float acc[4] = {0.f, 0.f, 0.f, 0.f};
    float inv = 1.f;

    if (deg <= 64) {
        int msrc = 0;
        float me = 0.f;
        if (lane < deg) {
            int s = esrc[start + lane];
            msrc = s;
            float e = a_src[s] + adn;
            e = fmaxf(e, SLOPE * e);
            me = __expf(e);
        }
        float d = me;
#pragma unroll
        for (int m = 1; m < 64; m <<= 1) d += __shfl_xor(d, m);
        inv = 1.f / (d + 1e-16f);
        if (lane < deg) slab[lane] = make_uint2((unsigned)msrc, __float_as_uint(me));
        wave_lds_fence();
        const unsigned short* hbase = hb + c8 * 4;
        int j = g;
        for (; j + 8 < deg; j += 16) {  // 2 gathers in flight
            uint2 p0 = slab[j], p1 = slab[j + 8];
            uint2 u0 = *(const uint2*)(hbase + (size_t)p0.x * 32);
            uint2 u1 = *(const uint2*)(hbase + (size_t)p1.x * 32);
            fma4(acc, u0, __uint_as_float(p0.y));
            fma4(acc, u1, __uint_as_float(p1.y));
        }
        if (j < deg) {
            uint2 p = slab[j];
            uint2 u = *(const uint2*)(hbase + (size_t)p.x * 32);
            fma4(acc, u, __uint_as_float(p.y));
        }
#pragma unroll
        for (int k = 0; k < 4; k++) acc[k] *= inv;
    } else {
        float d = 0.f;
        for (int k = start + lane; k < end; k += 64) {
            int s = esrc[k];
            float e = a_src[s] + adn;
            e = fmaxf(e, SLOPE * e);
            d += __expf(e);
        }
#pragma unroll
        for (int m = 1; m < 64; m <<= 1) d += __shfl_xor(d, m);
        inv = 1.f / (d + 1e-16f);
        for (int j = g; j < deg; j += 8) {
            int s = esrc[start + j];
            float e = a_src[s] + adn;
            e = fmaxf(e, SLOPE * e);
            float al = __expf(e) * inv;
            uint2 u = *(const uint2*)(hb + (size_t)s * 32 + c8 * 4);
            fma4(acc, u, al);
        }
    }
#pragma unroll
    for (int k = 0; k < 4; k++) {
        acc[k] += __shfl_xor(acc[k], 8);
        acc[k] += __shfl_xor(acc[k], 16);
        acc[k] += __shfl_xor(acc[k], 32);
    }
    if (lane < 8) {
        float4 b4 = ((const float4*)bf)[lane];
        float4 o = make_float4(acc[0] + b4.x, acc[1] + b4.y, acc[2] + b4.z,
                               acc[3] + b4.w);
        ((float4*)out)[(size_t)n * 8 + lane] = o;
    }
}

// ---------------- launch ----------------
extern "C" void kernel_launch(void* const* d_in, const int* in_sizes, int n_in,
                              void* d_out, int out_size, void* d_ws,
                              size_t ws_size, hipStream_t stream) {
    const float* x  = (const float*)d_in[0];
    const int* ei   = (const int*)d_in[1];
    const float* W[3]  = {(const float*)d_in[2], (const float*)d_in[8],  (const float*)d_in[14]};
    const float* AS[3] = {(const float*)d_in[3], (const float*)d_in[9],  (const float*)d_in[15]};
    const float* AD[3] = {(const float*)d_in[4], (const float*)d_in[10], (const float*)d_in[16]};
    const float* Bb[3] = {(const float*)d_in[5], (const float*)d_in[11], (const float*)d_in[17]};
    const float* G[3]  = {(const float*)d_in[6], (const float*)d_in[12], (const float*)d_in[18]};
    const float* BE[3] = {(const float*)d_in[7], (const float*)d_in[13], (const float*)d_in[19]};
    const float* Wf  = (const float*)d_in[20];
    const float* asf = (const float*)d_in[21];
    const float* adf = (const float*)d_in[22];
    const float* bfp = (const float*)d_in[23];
    float* out = (float*)d_out;

    unsigned short* xb = (unsigned short*)d_ws;          // NN*128 bf16 (layer0 uses [NN][64])
    unsigned short* hb = xb + (size_t)NN * 128;          // NN*128 bf16
    float* a_s = (float*)(hb + (size_t)NN * 128);
    float* a_d = a_s + (size_t)NN * 4;
    int* row_ptr = (int*)(a_d + (size_t)NN * 4);
    int* esrc    = row_ptr + NN;
    int* gbh     = esrc + ETOT;
    int* ebase   = gbh + NB;
    int* gcur    = ebase + NB + 1;
    int* pbuf    = gcur + NB;                            // EE ints
    unsigned short* Wt0 = (unsigned short*)(pbuf + EE);  // 128*64
    unsigned short* Wt1 = Wt0 + 128 * 64;                // 128*128
    unsigned short* Wt2 = Wt1 + 128 * 128;               // 128*128
    unsigned short* Wtf = Wt2 + 128 * 128;               // 32*128

    // dtype prep
    k_cvt_x<<<(NN * 64 / 8 + 255) / 256, 256, 0, stream>>>(x, xb);
    k_cvt_wt<<<(64 * 128 + 255) / 256, 256, 0, stream>>>(W[0], Wt0, 64, 128);
    k_cvt_wt<<<(128 * 128 + 255) / 256, 256, 0, stream>>>(W[1], Wt1, 128, 128);
    k_cvt_wt<<<(128 * 128 + 255) / 256, 256, 0, stream>>>(W[2], Wt2, 128, 128);
    k_cvt_wt<<<(128 * 32 + 255) / 256, 256, 0, stream>>>(Wf, Wtf, 128, 32);

    // CSR build
    k_zero<<<1, 128, 0, stream>>>(gbh, NB);
    k_bhist<<<(EE + 2047) / 2048, 256, 0, stream>>>(ei, gbh);
    k_bscan<<<1, 128, 0, stream>>>(gbh, ebase, gcur);
    k_bscatter<<<(EE + CCH - 1) / CCH, 256, 0, stream>>>(ei, gcur, pbuf);
    k_bcsr<<<NB, 256, 0, stream>>>(pbuf, ebase, row_ptr, esrc);

    // layers
    const unsigned short* Wts[3] = {Wt0, Wt1, Wt2};
    int K = 64;
    int gblk = (NN + 127) / 128;
    for (int l = 0; l < 3; l++) {
        k_mfma_att<128, 4><<<gblk, 256, 0, stream>>>(xb, Wts[l], AS[l], AD[l],
                                                     hb, a_s, a_d, NN, K);
        k_aggregate_ln<<<(NN + 15) / 16, 256, 0, stream>>>(hb, a_s, a_d, row_ptr,
                                                           esrc, Bb[l], G[l], BE[l], xb);
        K = 128;
    }
    k_mfma_att<32, 1><<<gblk, 256, 0, stream>>>(xb, Wtf, asf, adf, hb, a_s, a_d,
                                                NN, 128);
    k_agg_final<<<(NN + 3) / 4, 256, 0, stream>>>(hb, a_s, a_d, row_ptr, esrc,
                                                  bfp, out);
}